// Round 2
// baseline (2024.132 us; speedup 1.0000x reference)
//
#include <hip/hip_runtime.h>
#include <math.h>

constexpr int NN   = 50000;   // nodes
constexpr int NE   = 400000;  // edges
constexpr int INC  = 128;     // in channels
constexpr int HIDC = 64;      // hidden per head
constexpr int NH   = 4;       // heads
constexpr int D1   = 256;     // NH*HIDC
constexpr int NOUT = 10;      // classes
constexpr int NG   = 64;      // graphs

// ---------- generic fill ----------
__global__ void fill_k(float* __restrict__ p, float v, int n) {
  int i = blockIdx.x * 256 + threadIdx.x;
  if (i < n) p[i] = v;
}

// ---------- GEMM: Y[M,Ncols] = X[M,K] @ W[K,Ncols] + bias ----------
// BM=BN=64, BK=16, 256 threads, 4x4 microtile. K % 16 == 0, Ncols % 64 == 0.
__global__ __launch_bounds__(256) void gemm_bias(const float* __restrict__ X,
    const float* __restrict__ W, const float* __restrict__ bias,
    float* __restrict__ Y, int M, int K, int Ncols) {
  __shared__ float Xs[16][68];
  __shared__ float Ws[16][64];
  const int t  = threadIdx.x;
  const int m0 = blockIdx.y * 64;
  const int n0 = blockIdx.x * 64;
  const int tr = t >> 4;        // 0..15
  const int tc = t & 15;        // 0..15
  float acc[4][4] = {};
  for (int k0 = 0; k0 < K; k0 += 16) {
    { // X tile: 64 rows x 16 k
      int row = t >> 2;
      int kc  = (t & 3) * 4;
      int gm  = m0 + row;
      float4 v = make_float4(0.f, 0.f, 0.f, 0.f);
      if (gm < M) v = *(const float4*)(X + (size_t)gm * K + k0 + kc);
      Xs[kc + 0][row] = v.x; Xs[kc + 1][row] = v.y;
      Xs[kc + 2][row] = v.z; Xs[kc + 3][row] = v.w;
    }
    { // W tile: 16 k x 64 n
      int row = t >> 4;
      int nc  = (t & 15) * 4;
      float4 v = *(const float4*)(W + (size_t)(k0 + row) * Ncols + n0 + nc);
      Ws[row][nc + 0] = v.x; Ws[row][nc + 1] = v.y;
      Ws[row][nc + 2] = v.z; Ws[row][nc + 3] = v.w;
    }
    __syncthreads();
#pragma unroll
    for (int kk = 0; kk < 16; kk++) {
      float xr[4], wr[4];
#pragma unroll
      for (int i = 0; i < 4; i++) xr[i] = Xs[kk][tr * 4 + i];
#pragma unroll
      for (int j = 0; j < 4; j++) wr[j] = Ws[kk][tc * 4 + j];
#pragma unroll
      for (int i = 0; i < 4; i++)
#pragma unroll
        for (int j = 0; j < 4; j++) acc[i][j] += xr[i] * wr[j];
    }
    __syncthreads();
  }
#pragma unroll
  for (int i = 0; i < 4; i++) {
    int gm = m0 + tr * 4 + i;
    if (gm >= M) continue;
#pragma unroll
    for (int j = 0; j < 4; j++) {
      int gn = n0 + tc * 4 + j;
      Y[(size_t)gm * Ncols + gn] = acc[i][j] + bias[gn];
    }
  }
}

// ---------- float atomic max (CAS loop) ----------
__device__ __forceinline__ void atomicMaxFloat(float* addr, float val) {
  int* ia = (int*)addr;
  int old = __hip_atomic_load(ia, __ATOMIC_RELAXED, __HIP_MEMORY_SCOPE_AGENT);
  while (__int_as_float(old) < val) {
    int assumed = old;
    old = atomicCAS(ia, assumed, __float_as_int(val));
    if (old == assumed) break;
  }
}

// ---------- per-edge attention logits + scatter max ----------
// 16 threads per (edge,head) pair; block = 256 -> 16 pairs.
__global__ __launch_bounds__(256) void edge_logits(
    const int* __restrict__ src, const int* __restrict__ dst,
    const float* __restrict__ Q, const float* __restrict__ Km,
    float* __restrict__ alpha, float* __restrict__ amax) {
  const int t    = threadIdx.x;
  const int grp  = t >> 4;
  const int lane = t & 15;
  const int pair = blockIdx.x * 16 + grp;     // e*NH + h
  if (pair >= NE * NH) return;
  const int e = pair >> 2;
  const int h = pair & 3;
  const int s = src[e], d = dst[e];
  const float4 qv = *(const float4*)(Q  + (size_t)d * D1 + h * HIDC + lane * 4);
  const float4 kv = *(const float4*)(Km + (size_t)s * D1 + h * HIDC + lane * 4);
  float dot = qv.x * kv.x + qv.y * kv.y + qv.z * kv.z + qv.w * kv.w;
#pragma unroll
  for (int off = 8; off >= 1; off >>= 1) dot += __shfl_xor(dot, off, 16);
  if (lane == 0) {
    float a = dot * 0.125f;   // / sqrt(64)
    alpha[pair] = a;
    atomicMaxFloat(&amax[(size_t)d * NH + h], a);
  }
}

// ---------- exp(alpha - max) + scatter-sum denom ----------
__global__ void edge_exp(const int* __restrict__ dst, float* __restrict__ alpha,
                         const float* __restrict__ amax, float* __restrict__ denom) {
  int i = blockIdx.x * 256 + threadIdx.x;   // pair index
  if (i >= NE * NH) return;
  int e = i >> 2, h = i & 3;
  int d = dst[e];
  float ex = __expf(alpha[i] - amax[(size_t)d * NH + h]);
  alpha[i] = ex;
  atomicAdd(&denom[(size_t)d * NH + h], ex);
}

// ---------- weighted scatter aggregation: out[dst] += w * V[src] ----------
// one block (256 threads = all channels) per edge
__global__ __launch_bounds__(256) void aggregate(
    const int* __restrict__ src, const int* __restrict__ dst,
    const float* __restrict__ ex, const float* __restrict__ denom,
    const float* __restrict__ V, float* __restrict__ out) {
  const int e = blockIdx.x;
  const int c = threadIdx.x;      // 0..255
  const int h = c >> 6;
  const int s = src[e], d = dst[e];
  const float w = ex[(size_t)e * NH + h] / (denom[(size_t)d * NH + h] + 1e-16f);
  atomicAdd(&out[(size_t)d * D1 + c], w * V[(size_t)s * D1 + c]);
}

// ---------- ELU in place ----------
__global__ void elu_k(float* __restrict__ x, int n) {
  int i = blockIdx.x * 256 + threadIdx.x;
  if (i < n) {
    float v = x[i];
    x[i] = v > 0.f ? v : expm1f(v);
  }
}

// ---------- sorted-batch mean-pool partial sums ----------
// block handles 64 consecutive nodes; thread = channel; run-length atomics
__global__ __launch_bounds__(256) void pool_k(const float* __restrict__ h,
    const int* __restrict__ batch, float* __restrict__ sums) {
  const int c = threadIdx.x;
  const int n0 = blockIdx.x * 64;
  const int n1 = min(n0 + 64, NN);
  float run = 0.f;
  int curg = -1;
  for (int n = n0; n < n1; n++) {
    int g = batch[n];
    if (g != curg) {
      if (curg >= 0) atomicAdd(&sums[(size_t)curg * D1 + c], run);
      run = 0.f; curg = g;
    }
    run += h[(size_t)n * D1 + c];
  }
  if (curg >= 0) atomicAdd(&sums[(size_t)curg * D1 + c], run);
}

__global__ void count_k(const int* __restrict__ batch, float* __restrict__ cnt) {
  int i = blockIdx.x * 256 + threadIdx.x;
  if (i < NN) atomicAdd(&cnt[batch[i]], 1.0f);
}

// ---------- classifier + log_softmax ----------
__global__ __launch_bounds__(640) void head_k(const float* __restrict__ sums,
    const float* __restrict__ cnt, const float* __restrict__ Wl,
    const float* __restrict__ bl, float* __restrict__ out) {
  __shared__ float logits[NG][NOUT];
  const int t = threadIdx.x;
  if (t < NG * NOUT) {
    int g = t / NOUT, o = t % NOUT;
    float inv = 1.0f / fmaxf(cnt[g], 1.0f);
    float acc = 0.f;
    for (int k = 0; k < D1; k++) acc += sums[(size_t)g * D1 + k] * Wl[k * NOUT + o];
    logits[g][o] = acc * inv + bl[o];
  }
  __syncthreads();
  if (t < NG) {
    float mx = -INFINITY;
#pragma unroll
    for (int o = 0; o < NOUT; o++) mx = fmaxf(mx, logits[t][o]);
    float s = 0.f;
#pragma unroll
    for (int o = 0; o < NOUT; o++) s += __expf(logits[t][o] - mx);
    float lse = mx + logf(s);
#pragma unroll
    for (int o = 0; o < NOUT; o++) out[t * NOUT + o] = logits[t][o] - lse;
  }
}

// ---------------------------------------------------------------------------
extern "C" void kernel_launch(void* const* d_in, const int* in_sizes, int n_in,
                              void* d_out, int out_size, void* d_ws, size_t ws_size,
                              hipStream_t stream) {
  const float* x   = (const float*)d_in[0];
  const int* ei    = (const int*)d_in[1];
  const int* batch = (const int*)d_in[2];
  const float* Wq1 = (const float*)d_in[3];  const float* bq1 = (const float*)d_in[4];
  const float* Wk1 = (const float*)d_in[5];  const float* bk1 = (const float*)d_in[6];
  const float* Wv1 = (const float*)d_in[7];  const float* bv1 = (const float*)d_in[8];
  const float* Ws1 = (const float*)d_in[9];  const float* bs1 = (const float*)d_in[10];
  const float* Wq2 = (const float*)d_in[11]; const float* bq2 = (const float*)d_in[12];
  const float* Wk2 = (const float*)d_in[13]; const float* bk2 = (const float*)d_in[14];
  const float* Wv2 = (const float*)d_in[15]; const float* bv2 = (const float*)d_in[16];
  const float* Ws2 = (const float*)d_in[17]; const float* bs2 = (const float*)d_in[18];
  const float* Wl  = (const float*)d_in[19]; const float* bl  = (const float*)d_in[20];

  const int* srcIdx = ei;          // edge_index[0] (source j)
  const int* dstIdx = ei + NE;     // edge_index[1] (target i)

  // Workspace layout: 3 node-sized fp32 buffers (live-range reused) + small.
  float* ws    = (float*)d_ws;
  const size_t SZ_NODE = (size_t)NN * D1;      // 12.8M floats
  float* A     = ws;                            // Q (both layers), V (layer 2)
  float* B     = ws + SZ_NODE;                  // K1, then H1 (skip+agg)
  float* C     = ws + 2 * SZ_NODE;              // V1, K2, then H2 (skip+agg)
  float* alpha = ws + 3 * SZ_NODE;              // NE*NH
  float* amax  = alpha + (size_t)NE * NH;       // NN*NH
  float* denom = amax + (size_t)NN * NH;        // NN*NH
  float* sums  = denom + (size_t)NN * NH;       // NG*D1
  float* cnt   = sums + (size_t)NG * D1;        // NG (contiguous after sums)

  const dim3 gemmGrid(D1 / 64, (NN + 63) / 64);
  const int pairBlocks = (NE * NH + 15) / 16;
  const int pairThreadBlocks = (NE * NH + 255) / 256;
  const int nhBlocks = (NN * NH + 255) / 256;
  const int eluBlocks = (NN * D1 + 255) / 256;

  // ======== Layer 1 ========  (x -> H1 in B)
  fill_k<<<nhBlocks, 256, 0, stream>>>(amax, -INFINITY, NN * NH);
  fill_k<<<nhBlocks, 256, 0, stream>>>(denom, 0.f, NN * NH);
  gemm_bias<<<gemmGrid, 256, 0, stream>>>(x, Wq1, bq1, A, NN, INC, D1);   // Q
  gemm_bias<<<gemmGrid, 256, 0, stream>>>(x, Wk1, bk1, B, NN, INC, D1);   // K
  gemm_bias<<<gemmGrid, 256, 0, stream>>>(x, Wv1, bv1, C, NN, INC, D1);   // V
  edge_logits<<<pairBlocks, 256, 0, stream>>>(srcIdx, dstIdx, A, B, alpha, amax);
  edge_exp<<<pairThreadBlocks, 256, 0, stream>>>(dstIdx, alpha, amax, denom);
  gemm_bias<<<gemmGrid, 256, 0, stream>>>(x, Ws1, bs1, B, NN, INC, D1);   // skip -> B (K dead)
  aggregate<<<NE, 256, 0, stream>>>(srcIdx, dstIdx, alpha, denom, C, B);  // B += attn·V
  elu_k<<<eluBlocks, 256, 0, stream>>>(B, NN * D1);                       // H1 = B

  // ======== Layer 2 ========  (B -> H2 in C)
  fill_k<<<nhBlocks, 256, 0, stream>>>(amax, -INFINITY, NN * NH);
  fill_k<<<nhBlocks, 256, 0, stream>>>(denom, 0.f, NN * NH);
  gemm_bias<<<gemmGrid, 256, 0, stream>>>(B, Wq2, bq2, A, NN, D1, D1);    // Q
  gemm_bias<<<gemmGrid, 256, 0, stream>>>(B, Wk2, bk2, C, NN, D1, D1);    // K (V1 dead)
  edge_logits<<<pairBlocks, 256, 0, stream>>>(srcIdx, dstIdx, A, C, alpha, amax);
  edge_exp<<<pairThreadBlocks, 256, 0, stream>>>(dstIdx, alpha, amax, denom);
  gemm_bias<<<gemmGrid, 256, 0, stream>>>(B, Wv2, bv2, A, NN, D1, D1);    // V -> A (Q dead)
  gemm_bias<<<gemmGrid, 256, 0, stream>>>(B, Ws2, bs2, C, NN, D1, D1);    // skip -> C (K dead)
  aggregate<<<NE, 256, 0, stream>>>(srcIdx, dstIdx, alpha, denom, A, C);  // C += attn·V
  elu_k<<<eluBlocks, 256, 0, stream>>>(C, NN * D1);                       // H2 = C

  // ======== Pool + head ========
  fill_k<<<(NG * D1 + NG + 255) / 256, 256, 0, stream>>>(sums, 0.f, NG * D1 + NG);
  pool_k<<<(NN + 63) / 64, 256, 0, stream>>>(C, batch, sums);
  count_k<<<(NN + 255) / 256, 256, 0, stream>>>(batch, cnt);
  head_k<<<1, 640, 0, stream>>>(sums, cnt, Wl, bl, (float*)d_out);
}

// Round 3
// 1657.323 us; speedup vs baseline: 1.2213x; 1.2213x over previous
//
#include <hip/hip_runtime.h>
#include <math.h>

constexpr int NN   = 50000;   // nodes
constexpr int NE   = 400000;  // edges
constexpr int INC  = 128;     // in channels
constexpr int HIDC = 64;      // hidden per head
constexpr int NH   = 4;       // heads
constexpr int D1   = 256;     // NH*HIDC
constexpr int NOUT = 10;      // classes
constexpr int NG   = 64;      // graphs

typedef __attribute__((ext_vector_type(8))) short bf16x8;   // MFMA A/B frag (4 VGPRs)
typedef __attribute__((ext_vector_type(4))) float f32x4;    // MFMA C/D frag

// ---------- bf16 pack (RNE) ----------
__device__ __forceinline__ short f2b(float f) {
  union { float f; unsigned int i; } v; v.f = f;
  unsigned int x = v.i;
  return (short)((x + 0x7FFFu + ((x >> 16) & 1u)) >> 16);
}

// ---------- generic fill ----------
__global__ void fill_k(float* __restrict__ p, float v, int n) {
  int i = blockIdx.x * 256 + threadIdx.x;
  if (i < n) p[i] = v;
}

// ---------- fp32 -> bf16 convert (4 elems/thread) ----------
__global__ void cvt_bf16_k(const float* __restrict__ in, short* __restrict__ out, int n) {
  int i = (blockIdx.x * 256 + threadIdx.x) * 4;
  if (i >= n) return;
  float4 v = *(const float4*)(in + i);
  short4 o; o.x = f2b(v.x); o.y = f2b(v.y); o.z = f2b(v.z); o.w = f2b(v.w);
  *(short4*)(out + i) = o;
}

// ---------- ELU + bf16 convert (4 elems/thread) ----------
__global__ void elu_cvt_k(const float* __restrict__ in, short* __restrict__ out, int n) {
  int i = (blockIdx.x * 256 + threadIdx.x) * 4;
  if (i >= n) return;
  float4 v = *(const float4*)(in + i);
  v.x = v.x > 0.f ? v.x : expm1f(v.x);
  v.y = v.y > 0.f ? v.y : expm1f(v.y);
  v.z = v.z > 0.f ? v.z : expm1f(v.z);
  v.w = v.w > 0.f ? v.w : expm1f(v.w);
  short4 o; o.x = f2b(v.x); o.y = f2b(v.y); o.z = f2b(v.z); o.w = f2b(v.w);
  *(short4*)(out + i) = o;
}

// ---------- W[K][N] fp32 -> Wt[N][K] bf16 (coalesced writes) ----------
__global__ void wt_cvt_k(const float* __restrict__ W, short* __restrict__ Wt,
                         int kbits, int N) {
  int i = blockIdx.x * 256 + threadIdx.x;     // over N*K, output-major
  int K = 1 << kbits;
  if (i >= N * K) return;
  int n = i >> kbits, k = i & (K - 1);
  Wt[i] = f2b(W[(size_t)k * N + n]);
}

// ---------- MFMA GEMM: Y[M,256] = Xb[M,K](bf16) @ Wt[256,K](bf16)^T + bias ----
// BM=BN=128, BK=32. 256 threads = 4 waves, each wave 64x64 via 4x4 MFMAs.
// LDS rows padded to 56 bf16 (112 B): 16B-aligned, 2-way banks (free).
constexpr int LDP = 56;
__global__ __launch_bounds__(256) void gemm_mfma(
    const short* __restrict__ Xb, const short* __restrict__ Wt,
    const float* __restrict__ bias, float* __restrict__ Y, int M, int K) {
  __shared__ short As[128 * LDP];
  __shared__ short Bs[128 * LDP];
  const int t    = threadIdx.x;
  const int m0   = blockIdx.y * 128;
  const int n0   = blockIdx.x * 128;
  const int lane = t & 63;
  const int wv   = t >> 6;          // wave 0..3
  const int wm   = (wv >> 1) * 64;  // wave m offset
  const int wn   = (wv & 1) * 64;   // wave n offset
  const int quad = lane >> 4;
  const int l16  = lane & 15;

  f32x4 acc[4][4] = {};
  for (int k0 = 0; k0 < K; k0 += 32) {
    // stage A: 128 rows x 32 bf16; 512 16B-chunks over 256 threads x2
#pragma unroll
    for (int it = 0; it < 2; ++it) {
      int c   = t + it * 256;
      int row = c >> 2, seg = c & 3;
      int gm  = m0 + row;
      int4 v  = make_int4(0, 0, 0, 0);
      if (gm < M) v = *(const int4*)(Xb + (size_t)gm * K + k0 + seg * 8);
      *(int4*)(&As[row * LDP + seg * 8]) = v;
      // stage B: Wt rows n0+row (always < 256)
      int4 w = *(const int4*)(Wt + (size_t)(n0 + row) * K + k0 + seg * 8);
      *(int4*)(&Bs[row * LDP + seg * 8]) = w;
    }
    __syncthreads();
    bf16x8 a[4], b[4];
#pragma unroll
    for (int mi = 0; mi < 4; mi++)
      a[mi] = *(const bf16x8*)(&As[(wm + mi * 16 + l16) * LDP + quad * 8]);
#pragma unroll
    for (int nj = 0; nj < 4; nj++)
      b[nj] = *(const bf16x8*)(&Bs[(wn + nj * 16 + l16) * LDP + quad * 8]);
#pragma unroll
    for (int mi = 0; mi < 4; mi++)
#pragma unroll
      for (int nj = 0; nj < 4; nj++)
        acc[mi][nj] = __builtin_amdgcn_mfma_f32_16x16x32_bf16(a[mi], b[nj], acc[mi][nj], 0, 0, 0);
    __syncthreads();
  }
  // epilogue: D row = m (quad*4+reg), col = n (lane&15)
#pragma unroll
  for (int mi = 0; mi < 4; mi++) {
#pragma unroll
    for (int r = 0; r < 4; r++) {
      int gm = m0 + wm + mi * 16 + quad * 4 + r;
      if (gm >= M) continue;
#pragma unroll
      for (int nj = 0; nj < 4; nj++) {
        int gn = n0 + wn + nj * 16 + l16;
        Y[(size_t)gm * D1 + gn] = acc[mi][nj][r] + bias[gn];
      }
    }
  }
}

// ---------- float atomic max (CAS loop) ----------
__device__ __forceinline__ void atomicMaxFloat(float* addr, float val) {
  int* ia = (int*)addr;
  int old = __hip_atomic_load(ia, __ATOMIC_RELAXED, __HIP_MEMORY_SCOPE_AGENT);
  while (__int_as_float(old) < val) {
    int assumed = old;
    old = atomicCAS(ia, assumed, __float_as_int(val));
    if (old == assumed) break;
  }
}

// ---------- per-edge attention logits + scatter max ----------
__global__ __launch_bounds__(256) void edge_logits(
    const int* __restrict__ src, const int* __restrict__ dst,
    const float* __restrict__ Q, const float* __restrict__ Km,
    float* __restrict__ alpha, float* __restrict__ amax) {
  const int t    = threadIdx.x;
  const int grp  = t >> 4;
  const int lane = t & 15;
  const int pair = blockIdx.x * 16 + grp;     // e*NH + h
  if (pair >= NE * NH) return;
  const int e = pair >> 2;
  const int h = pair & 3;
  const int s = src[e], d = dst[e];
  const float4 qv = *(const float4*)(Q  + (size_t)d * D1 + h * HIDC + lane * 4);
  const float4 kv = *(const float4*)(Km + (size_t)s * D1 + h * HIDC + lane * 4);
  float dot = qv.x * kv.x + qv.y * kv.y + qv.z * kv.z + qv.w * kv.w;
#pragma unroll
  for (int off = 8; off >= 1; off >>= 1) dot += __shfl_xor(dot, off, 16);
  if (lane == 0) {
    float a = dot * 0.125f;   // / sqrt(64)
    alpha[pair] = a;
    atomicMaxFloat(&amax[(size_t)d * NH + h], a);
  }
}

// ---------- exp(alpha - max) + scatter-sum denom ----------
__global__ void edge_exp(const int* __restrict__ dst, float* __restrict__ alpha,
                         const float* __restrict__ amax, float* __restrict__ denom) {
  int i = blockIdx.x * 256 + threadIdx.x;   // pair index
  if (i >= NE * NH) return;
  int e = i >> 2, h = i & 3;
  int d = dst[e];
  float ex = __expf(alpha[i] - amax[(size_t)d * NH + h]);
  alpha[i] = ex;
  atomicAdd(&denom[(size_t)d * NH + h], ex);
}

// ---------- weighted scatter aggregation: out[dst] += w * V[src] ----------
__global__ __launch_bounds__(256) void aggregate(
    const int* __restrict__ src, const int* __restrict__ dst,
    const float* __restrict__ ex, const float* __restrict__ denom,
    const float* __restrict__ V, float* __restrict__ out) {
  const int e = blockIdx.x;
  const int c = threadIdx.x;      // 0..255
  const int h = c >> 6;
  const int s = src[e], d = dst[e];
  const float w = ex[(size_t)e * NH + h] / (denom[(size_t)d * NH + h] + 1e-16f);
  atomicAdd(&out[(size_t)d * D1 + c], w * V[(size_t)s * D1 + c]);
}

// ---------- ELU in place (fp32) ----------
__global__ void elu_k(float* __restrict__ x, int n) {
  int i = blockIdx.x * 256 + threadIdx.x;
  if (i < n) {
    float v = x[i];
    x[i] = v > 0.f ? v : expm1f(v);
  }
}

// ---------- sorted-batch mean-pool partial sums ----------
__global__ __launch_bounds__(256) void pool_k(const float* __restrict__ h,
    const int* __restrict__ batch, float* __restrict__ sums) {
  const int c = threadIdx.x;
  const int n0 = blockIdx.x * 64;
  const int n1 = min(n0 + 64, NN);
  float run = 0.f;
  int curg = -1;
  for (int n = n0; n < n1; n++) {
    int g = batch[n];
    if (g != curg) {
      if (curg >= 0) atomicAdd(&sums[(size_t)curg * D1 + c], run);
      run = 0.f; curg = g;
    }
    run += h[(size_t)n * D1 + c];
  }
  if (curg >= 0) atomicAdd(&sums[(size_t)curg * D1 + c], run);
}

__global__ void count_k(const int* __restrict__ batch, float* __restrict__ cnt) {
  int i = blockIdx.x * 256 + threadIdx.x;
  if (i < NN) atomicAdd(&cnt[batch[i]], 1.0f);
}

// ---------- classifier + log_softmax ----------
__global__ __launch_bounds__(640) void head_k(const float* __restrict__ sums,
    const float* __restrict__ cnt, const float* __restrict__ Wl,
    const float* __restrict__ bl, float* __restrict__ out) {
  __shared__ float logits[NG][NOUT];
  const int t = threadIdx.x;
  if (t < NG * NOUT) {
    int g = t / NOUT, o = t % NOUT;
    float inv = 1.0f / fmaxf(cnt[g], 1.0f);
    float acc = 0.f;
    for (int k = 0; k < D1; k++) acc += sums[(size_t)g * D1 + k] * Wl[k * NOUT + o];
    logits[g][o] = acc * inv + bl[o];
  }
  __syncthreads();
  if (t < NG) {
    float mx = -INFINITY;
#pragma unroll
    for (int o = 0; o < NOUT; o++) mx = fmaxf(mx, logits[t][o]);
    float s = 0.f;
#pragma unroll
    for (int o = 0; o < NOUT; o++) s += __expf(logits[t][o] - mx);
    float lse = mx + logf(s);
#pragma unroll
    for (int o = 0; o < NOUT; o++) out[t * NOUT + o] = logits[t][o] - lse;
  }
}

// ---------------------------------------------------------------------------
extern "C" void kernel_launch(void* const* d_in, const int* in_sizes, int n_in,
                              void* d_out, int out_size, void* d_ws, size_t ws_size,
                              hipStream_t stream) {
  const float* x   = (const float*)d_in[0];
  const int* ei    = (const int*)d_in[1];
  const int* batch = (const int*)d_in[2];
  const float* Wq1 = (const float*)d_in[3];  const float* bq1 = (const float*)d_in[4];
  const float* Wk1 = (const float*)d_in[5];  const float* bk1 = (const float*)d_in[6];
  const float* Wv1 = (const float*)d_in[7];  const float* bv1 = (const float*)d_in[8];
  const float* Ws1 = (const float*)d_in[9];  const float* bs1 = (const float*)d_in[10];
  const float* Wq2 = (const float*)d_in[11]; const float* bq2 = (const float*)d_in[12];
  const float* Wk2 = (const float*)d_in[13]; const float* bk2 = (const float*)d_in[14];
  const float* Wv2 = (const float*)d_in[15]; const float* bv2 = (const float*)d_in[16];
  const float* Ws2 = (const float*)d_in[17]; const float* bs2 = (const float*)d_in[18];
  const float* Wl  = (const float*)d_in[19]; const float* bl  = (const float*)d_in[20];

  const int* srcIdx = ei;          // edge_index[0] (source j)
  const int* dstIdx = ei + NE;     // edge_index[1] (target i)

  // Workspace: 3 node-sized fp32 buffers (live-range reused) + small + bf16.
  float* ws    = (float*)d_ws;
  const size_t SZ_NODE = (size_t)NN * D1;      // 12.8M floats
  float* A     = ws;                            // Q (both layers), V2
  float* B     = ws + SZ_NODE;                  // K1, then H1 (skip+agg)
  float* C     = ws + 2 * SZ_NODE;              // V1, K2, then H2 (skip+agg)
  float* alpha = ws + 3 * SZ_NODE;              // NE*NH
  float* amax  = alpha + (size_t)NE * NH;       // NN*NH
  float* denom = amax + (size_t)NN * NH;        // NN*NH
  float* sums  = denom + (size_t)NN * NH;       // NG*D1
  float* cnt   = sums + (size_t)NG * D1;        // NG
  // bf16 region
  short* sb   = (short*)(cnt + NG);
  short* Xb   = sb;                              // NN*INC
  short* H1b  = Xb + (size_t)NN * INC;           // NN*D1
  short* Wt1q = H1b + SZ_NODE;                   // 4x (D1*INC)
  short* Wt1k = Wt1q + (size_t)D1 * INC;
  short* Wt1v = Wt1k + (size_t)D1 * INC;
  short* Wt1s = Wt1v + (size_t)D1 * INC;
  short* Wt2q = Wt1s + (size_t)D1 * INC;         // 4x (D1*D1)
  short* Wt2k = Wt2q + (size_t)D1 * D1;
  short* Wt2v = Wt2k + (size_t)D1 * D1;
  short* Wt2s = Wt2v + (size_t)D1 * D1;

  const dim3 gemmGrid(2, (NN + 127) / 128);     // N=256 -> 2 col tiles
  const int pairBlocks = (NE * NH + 15) / 16;
  const int pairThreadBlocks = (NE * NH + 255) / 256;
  const int nhBlocks = (NN * NH + 255) / 256;
  const int eluBlocks = (NN * D1 + 255) / 256;
  const int wt1Blocks = (D1 * INC + 255) / 256;
  const int wt2Blocks = (D1 * D1 + 255) / 256;

  // ======== Converts (once) ========
  cvt_bf16_k<<<(NN * INC / 4 + 255) / 256, 256, 0, stream>>>(x, Xb, NN * INC);
  wt_cvt_k<<<wt1Blocks, 256, 0, stream>>>(Wq1, Wt1q, 7, D1);
  wt_cvt_k<<<wt1Blocks, 256, 0, stream>>>(Wk1, Wt1k, 7, D1);
  wt_cvt_k<<<wt1Blocks, 256, 0, stream>>>(Wv1, Wt1v, 7, D1);
  wt_cvt_k<<<wt1Blocks, 256, 0, stream>>>(Ws1, Wt1s, 7, D1);
  wt_cvt_k<<<wt2Blocks, 256, 0, stream>>>(Wq2, Wt2q, 8, D1);
  wt_cvt_k<<<wt2Blocks, 256, 0, stream>>>(Wk2, Wt2k, 8, D1);
  wt_cvt_k<<<wt2Blocks, 256, 0, stream>>>(Wv2, Wt2v, 8, D1);
  wt_cvt_k<<<wt2Blocks, 256, 0, stream>>>(Ws2, Wt2s, 8, D1);

  // ======== Layer 1 ========  (Xb -> H1 in B)
  fill_k<<<nhBlocks, 256, 0, stream>>>(amax, -INFINITY, NN * NH);
  fill_k<<<nhBlocks, 256, 0, stream>>>(denom, 0.f, NN * NH);
  gemm_mfma<<<gemmGrid, 256, 0, stream>>>(Xb, Wt1q, bq1, A, NN, INC);   // Q
  gemm_mfma<<<gemmGrid, 256, 0, stream>>>(Xb, Wt1k, bk1, B, NN, INC);   // K
  gemm_mfma<<<gemmGrid, 256, 0, stream>>>(Xb, Wt1v, bv1, C, NN, INC);   // V
  edge_logits<<<pairBlocks, 256, 0, stream>>>(srcIdx, dstIdx, A, B, alpha, amax);
  edge_exp<<<pairThreadBlocks, 256, 0, stream>>>(dstIdx, alpha, amax, denom);
  gemm_mfma<<<gemmGrid, 256, 0, stream>>>(Xb, Wt1s, bs1, B, NN, INC);   // skip -> B
  aggregate<<<NE, 256, 0, stream>>>(srcIdx, dstIdx, alpha, denom, C, B); // B += attn.V
  elu_cvt_k<<<(NN * D1 / 4 + 255) / 256, 256, 0, stream>>>(B, H1b, NN * D1);

  // ======== Layer 2 ========  (H1b -> H2 in C)
  fill_k<<<nhBlocks, 256, 0, stream>>>(amax, -INFINITY, NN * NH);
  fill_k<<<nhBlocks, 256, 0, stream>>>(denom, 0.f, NN * NH);
  gemm_mfma<<<gemmGrid, 256, 0, stream>>>(H1b, Wt2q, bq2, A, NN, D1);   // Q
  gemm_mfma<<<gemmGrid, 256, 0, stream>>>(H1b, Wt2k, bk2, C, NN, D1);   // K
  edge_logits<<<pairBlocks, 256, 0, stream>>>(srcIdx, dstIdx, A, C, alpha, amax);
  edge_exp<<<pairThreadBlocks, 256, 0, stream>>>(dstIdx, alpha, amax, denom);
  gemm_mfma<<<gemmGrid, 256, 0, stream>>>(H1b, Wt2v, bv2, A, NN, D1);   // V -> A
  gemm_mfma<<<gemmGrid, 256, 0, stream>>>(H1b, Wt2s, bs2, C, NN, D1);   // skip -> C
  aggregate<<<NE, 256, 0, stream>>>(srcIdx, dstIdx, alpha, denom, A, C); // C += attn.V
  elu_k<<<eluBlocks, 256, 0, stream>>>(C, NN * D1);                      // H2 = C

  // ======== Pool + head ========
  fill_k<<<(NG * D1 + NG + 255) / 256, 256, 0, stream>>>(sums, 0.f, NG * D1 + NG);
  pool_k<<<(NN + 63) / 64, 256, 0, stream>>>(C, batch, sums);
  count_k<<<(NN + 255) / 256, 256, 0, stream>>>(batch, cnt);
  head_k<<<1, 640, 0, stream>>>(sums, cnt, Wl, bl, (float*)d_out);
}

// Round 4
// 1040.255 us; speedup vs baseline: 1.9458x; 1.5932x over previous
//
#include <hip/hip_runtime.h>
#include <math.h>

constexpr int NN   = 50000;   // nodes
constexpr int NE   = 400000;  // edges
constexpr int INC  = 128;     // in channels
constexpr int NH   = 4;       // heads
constexpr int D1   = 256;     // NH*HIDC
constexpr int NOUT = 10;      // classes
constexpr int NG   = 64;      // graphs
constexpr int NB_SCAN = (NN + 255) / 256;   // 196 scan blocks

typedef __attribute__((ext_vector_type(8))) short bf16x8;   // MFMA A/B frag
typedef __attribute__((ext_vector_type(4))) float f32x4;    // MFMA C/D frag

// ---------- bf16 pack (RNE) ----------
__device__ __forceinline__ short f2b(float f) {
  union { float f; unsigned int i; } v; v.f = f;
  unsigned int x = v.i;
  return (short)((x + 0x7FFFu + ((x >> 16) & 1u)) >> 16);
}

// ---------- fills ----------
__global__ void fill_k(float* __restrict__ p, float v, int n) {
  int i = blockIdx.x * 256 + threadIdx.x;
  if (i < n) p[i] = v;
}
__global__ void fill_i(int* __restrict__ p, int v, int n) {
  int i = blockIdx.x * 256 + threadIdx.x;
  if (i < n) p[i] = v;
}

// ---------- fp32 -> bf16 convert ----------
__global__ void cvt_bf16_k(const float* __restrict__ in, short* __restrict__ out, int n) {
  int i = (blockIdx.x * 256 + threadIdx.x) * 4;
  if (i >= n) return;
  float4 v = *(const float4*)(in + i);
  short4 o; o.x = f2b(v.x); o.y = f2b(v.y); o.z = f2b(v.z); o.w = f2b(v.w);
  *(short4*)(out + i) = o;
}

// ---------- W[K][N] fp32 -> Wt[N][K] bf16 ----------
__global__ void wt_cvt_k(const float* __restrict__ W, short* __restrict__ Wt,
                         int kbits, int N) {
  int i = blockIdx.x * 256 + threadIdx.x;
  int K = 1 << kbits;
  if (i >= N * K) return;
  int n = i >> kbits, k = i & (K - 1);
  Wt[i] = f2b(W[(size_t)k * N + n]);
}

// ---------- CSR build ----------
__global__ void deg_count(const int* __restrict__ dst, int* __restrict__ deg) {
  int e = blockIdx.x * 256 + threadIdx.x;
  if (e < NE) atomicAdd(&deg[dst[e]], 1);
}
// block partial sums
__global__ __launch_bounds__(256) void scan1(const int* __restrict__ deg,
                                             int* __restrict__ partial) {
  __shared__ int sh[256];
  int t = threadIdx.x, i = blockIdx.x * 256 + t;
  sh[t] = (i < NN) ? deg[i] : 0;
  __syncthreads();
  for (int off = 128; off > 0; off >>= 1) {
    if (t < off) sh[t] += sh[t + off];
    __syncthreads();
  }
  if (t == 0) partial[blockIdx.x] = sh[0];
}
// single-block exclusive scan of partials (nb <= 256)
__global__ __launch_bounds__(256) void scan2(int* __restrict__ partial, int nb) {
  __shared__ int sh[256];
  int t = threadIdx.x;
  int v = (t < nb) ? partial[t] : 0;
  sh[t] = v;
  __syncthreads();
  for (int off = 1; off < 256; off <<= 1) {
    int o = (t >= off) ? sh[t - off] : 0;
    __syncthreads();
    sh[t] += o;
    __syncthreads();
  }
  if (t < nb) partial[t] = sh[t] - v;   // exclusive
}
// per-block exclusive scan + offset -> rowstart & cursor
__global__ __launch_bounds__(256) void scan3(const int* __restrict__ deg,
    const int* __restrict__ partial, int* __restrict__ rowstart,
    int* __restrict__ cursor) {
  __shared__ int sh[256];
  int t = threadIdx.x, i = blockIdx.x * 256 + t;
  int v = (i < NN) ? deg[i] : 0;
  sh[t] = v;
  __syncthreads();
  for (int off = 1; off < 256; off <<= 1) {
    int o = (t >= off) ? sh[t - off] : 0;
    __syncthreads();
    sh[t] += o;
    __syncthreads();
  }
  int excl = sh[t] - v + partial[blockIdx.x];
  if (i <= NN) rowstart[i] = excl;      // rowstart[NN] == NE (all-zero tail)
  if (i < NN)  cursor[i]   = excl;
}
__global__ void scatter_k(const int* __restrict__ src, const int* __restrict__ dst,
    int* __restrict__ cursor, int* __restrict__ esrc, int* __restrict__ edst) {
  int e = blockIdx.x * 256 + threadIdx.x;
  if (e >= NE) return;
  int d = dst[e];
  int pos = atomicAdd(&cursor[d], 1);
  esrc[pos] = src[e];
  edst[pos] = d;
}

// ---------- MFMA GEMM: Y[M,256] = Xb[M,K](bf16) @ Wt[256,K]^T + bias ----------
constexpr int LDP = 56;
template <typename TOUT>
__device__ __forceinline__ void st1(TOUT* p, float v);
template <> __device__ __forceinline__ void st1<float>(float* p, float v) { *p = v; }
template <> __device__ __forceinline__ void st1<short>(short* p, float v) { *p = f2b(v); }

template <typename TOUT>
__global__ __launch_bounds__(256) void gemm_mfma(
    const short* __restrict__ Xb, const short* __restrict__ Wt,
    const float* __restrict__ bias, TOUT* __restrict__ Y, int M, int K) {
  __shared__ short As[128 * LDP];
  __shared__ short Bs[128 * LDP];
  const int t    = threadIdx.x;
  const int m0   = blockIdx.y * 128;
  const int n0   = blockIdx.x * 128;
  const int lane = t & 63;
  const int wv   = t >> 6;
  const int wm   = (wv >> 1) * 64;
  const int wn   = (wv & 1) * 64;
  const int quad = lane >> 4;
  const int l16  = lane & 15;

  f32x4 acc[4][4] = {};
  for (int k0 = 0; k0 < K; k0 += 32) {
#pragma unroll
    for (int it = 0; it < 2; ++it) {
      int c   = t + it * 256;
      int row = c >> 2, seg = c & 3;
      int gm  = m0 + row;
      int4 v  = make_int4(0, 0, 0, 0);
      if (gm < M) v = *(const int4*)(Xb + (size_t)gm * K + k0 + seg * 8);
      *(int4*)(&As[row * LDP + seg * 8]) = v;
      int4 w = *(const int4*)(Wt + (size_t)(n0 + row) * K + k0 + seg * 8);
      *(int4*)(&Bs[row * LDP + seg * 8]) = w;
    }
    __syncthreads();
    bf16x8 a[4], b[4];
#pragma unroll
    for (int mi = 0; mi < 4; mi++)
      a[mi] = *(const bf16x8*)(&As[(wm + mi * 16 + l16) * LDP + quad * 8]);
#pragma unroll
    for (int nj = 0; nj < 4; nj++)
      b[nj] = *(const bf16x8*)(&Bs[(wn + nj * 16 + l16) * LDP + quad * 8]);
#pragma unroll
    for (int mi = 0; mi < 4; mi++)
#pragma unroll
      for (int nj = 0; nj < 4; nj++)
        acc[mi][nj] = __builtin_amdgcn_mfma_f32_16x16x32_bf16(a[mi], b[nj], acc[mi][nj], 0, 0, 0);
    __syncthreads();
  }
#pragma unroll
  for (int mi = 0; mi < 4; mi++) {
#pragma unroll
    for (int r = 0; r < 4; r++) {
      int gm = m0 + wm + mi * 16 + quad * 4 + r;
      if (gm >= M) continue;
#pragma unroll
      for (int nj = 0; nj < 4; nj++) {
        int gn = n0 + wn + nj * 16 + l16;
        st1<TOUT>(Y + (size_t)gm * D1 + gn, acc[mi][nj][r] + bias[gn]);
      }
    }
  }
}

// ---------- per-edge attention logits (CSR order) ----------
// 16 threads per (pos,head); block 256 = 16 pairs.
__global__ __launch_bounds__(256) void edge_logits(
    const int* __restrict__ esrc, const int* __restrict__ edst,
    const float* __restrict__ Q, const float* __restrict__ Km,
    float* __restrict__ alpha) {
  const int t    = threadIdx.x;
  const int lane = t & 15;
  const int pair = blockIdx.x * 16 + (t >> 4);   // pos*NH + h
  if (pair >= NE * NH) return;
  const int pos = pair >> 2;
  const int h   = pair & 3;
  const int s = esrc[pos], d = edst[pos];
  const float4 qv = *(const float4*)(Q  + (size_t)d * D1 + h * 64 + lane * 4);
  const float4 kv = *(const float4*)(Km + (size_t)s * D1 + h * 64 + lane * 4);
  float dot = qv.x * kv.x + qv.y * kv.y + qv.z * kv.z + qv.w * kv.w;
#pragma unroll
  for (int off = 8; off >= 1; off >>= 1) dot += __shfl_xor(dot, off, 16);
  if (lane == 0) alpha[pair] = dot * 0.125f;    // / sqrt(64)
}

// ---------- fused node softmax + aggregate + skip + ELU (+cast) ----------
// wave per node; thread handles 4 channels (float4). block 256 = 4 nodes.
template <typename TOUT>
__global__ __launch_bounds__(256) void node_agg(
    const int* __restrict__ rowstart, const int* __restrict__ esrc,
    const float* __restrict__ alpha, const float* __restrict__ V,
    const float* __restrict__ skip, TOUT* __restrict__ out) {
  const int nid = blockIdx.x * 4 + (threadIdx.x >> 6);
  if (nid >= NN) return;
  const int t  = threadIdx.x & 63;
  const int h  = t >> 4;          // head for my 4 channels
  const int c0 = t * 4;
  const int r0 = rowstart[nid], r1 = rowstart[nid + 1];
  float mh = -INFINITY;
  for (int r = r0; r < r1; r++) mh = fmaxf(mh, alpha[r * 4 + h]);
  float4 acc = make_float4(0.f, 0.f, 0.f, 0.f);
  float denom = 0.f;
  for (int r = r0; r < r1; r++) {
    float ex = __expf(alpha[r * 4 + h] - mh);
    denom += ex;
    const float4 v = *(const float4*)(V + (size_t)esrc[r] * D1 + c0);
    acc.x += ex * v.x; acc.y += ex * v.y; acc.z += ex * v.z; acc.w += ex * v.w;
  }
  const float inv = 1.0f / (denom + 1e-16f);
  const float4 sk = *(const float4*)(skip + (size_t)nid * D1 + c0);
  float o0 = acc.x * inv + sk.x;
  float o1 = acc.y * inv + sk.y;
  float o2 = acc.z * inv + sk.z;
  float o3 = acc.w * inv + sk.w;
  o0 = o0 > 0.f ? o0 : expm1f(o0);
  o1 = o1 > 0.f ? o1 : expm1f(o1);
  o2 = o2 > 0.f ? o2 : expm1f(o2);
  o3 = o3 > 0.f ? o3 : expm1f(o3);
  TOUT* p = out + (size_t)nid * D1 + c0;
  st1<TOUT>(p + 0, o0); st1<TOUT>(p + 1, o1);
  st1<TOUT>(p + 2, o2); st1<TOUT>(p + 3, o3);
}

// ---------- sorted-batch mean-pool partial sums ----------
__global__ __launch_bounds__(256) void pool_k(const float* __restrict__ h,
    const int* __restrict__ batch, float* __restrict__ sums) {
  const int c = threadIdx.x;
  const int n0 = blockIdx.x * 64;
  const int n1 = min(n0 + 64, NN);
  float run = 0.f;
  int curg = -1;
  for (int n = n0; n < n1; n++) {
    int g = batch[n];
    if (g != curg) {
      if (curg >= 0) atomicAdd(&sums[(size_t)curg * D1 + c], run);
      run = 0.f; curg = g;
    }
    run += h[(size_t)n * D1 + c];
  }
  if (curg >= 0) atomicAdd(&sums[(size_t)curg * D1 + c], run);
}

__global__ void count_k(const int* __restrict__ batch, float* __restrict__ cnt) {
  int i = blockIdx.x * 256 + threadIdx.x;
  if (i < NN) atomicAdd(&cnt[batch[i]], 1.0f);
}

// ---------- classifier + log_softmax ----------
__global__ __launch_bounds__(640) void head_k(const float* __restrict__ sums,
    const float* __restrict__ cnt, const float* __restrict__ Wl,
    const float* __restrict__ bl, float* __restrict__ out) {
  __shared__ float logits[NG][NOUT];
  const int t = threadIdx.x;
  if (t < NG * NOUT) {
    int g = t / NOUT, o = t % NOUT;
    float inv = 1.0f / fmaxf(cnt[g], 1.0f);
    float acc = 0.f;
    for (int k = 0; k < D1; k++) acc += sums[(size_t)g * D1 + k] * Wl[k * NOUT + o];
    logits[g][o] = acc * inv + bl[o];
  }
  __syncthreads();
  if (t < NG) {
    float mx = -INFINITY;
#pragma unroll
    for (int o = 0; o < NOUT; o++) mx = fmaxf(mx, logits[t][o]);
    float s = 0.f;
#pragma unroll
    for (int o = 0; o < NOUT; o++) s += __expf(logits[t][o] - mx);
    float lse = mx + logf(s);
#pragma unroll
    for (int o = 0; o < NOUT; o++) out[t * NOUT + o] = logits[t][o] - lse;
  }
}

// ---------------------------------------------------------------------------
extern "C" void kernel_launch(void* const* d_in, const int* in_sizes, int n_in,
                              void* d_out, int out_size, void* d_ws, size_t ws_size,
                              hipStream_t stream) {
  const float* x   = (const float*)d_in[0];
  const int* ei    = (const int*)d_in[1];
  const int* batch = (const int*)d_in[2];
  const float* Wq1 = (const float*)d_in[3];  const float* bq1 = (const float*)d_in[4];
  const float* Wk1 = (const float*)d_in[5];  const float* bk1 = (const float*)d_in[6];
  const float* Wv1 = (const float*)d_in[7];  const float* bv1 = (const float*)d_in[8];
  const float* Ws1 = (const float*)d_in[9];  const float* bs1 = (const float*)d_in[10];
  const float* Wq2 = (const float*)d_in[11]; const float* bq2 = (const float*)d_in[12];
  const float* Wk2 = (const float*)d_in[13]; const float* bk2 = (const float*)d_in[14];
  const float* Wv2 = (const float*)d_in[15]; const float* bv2 = (const float*)d_in[16];
  const float* Ws2 = (const float*)d_in[17]; const float* bs2 = (const float*)d_in[18];
  const float* Wl  = (const float*)d_in[19]; const float* bl  = (const float*)d_in[20];

  const int* srcIdx = ei;          // edge_index[0] (source j)
  const int* dstIdx = ei + NE;     // edge_index[1] (target i)

  // -------- workspace layout --------
  float* ws = (float*)d_ws;
  const size_t SZ_NODE = (size_t)NN * D1;       // 12.8M floats
  float* Qf    = ws;                             // 51.2 MB
  float* Kf    = ws + SZ_NODE;
  float* Vf    = ws + 2 * SZ_NODE;
  float* SKf   = ws + 3 * SZ_NODE;               // skip; layer-2 out in place
  float* alpha = ws + 4 * SZ_NODE;               // NE*NH (CSR order)
  float* sums  = alpha + (size_t)NE * NH;        // NG*D1
  float* cnt   = sums + (size_t)NG * D1;         // NG
  // bf16 region
  short* Xb   = (short*)(cnt + NG);              // NN*INC
  short* H1b  = Xb + (size_t)NN * INC;           // NN*D1
  short* Wt1q = H1b + SZ_NODE;
  short* Wt1k = Wt1q + (size_t)D1 * INC;
  short* Wt1v = Wt1k + (size_t)D1 * INC;
  short* Wt1s = Wt1v + (size_t)D1 * INC;
  short* Wt2q = Wt1s + (size_t)D1 * INC;
  short* Wt2k = Wt2q + (size_t)D1 * D1;
  short* Wt2v = Wt2k + (size_t)D1 * D1;
  short* Wt2s = Wt2v + (size_t)D1 * D1;
  // int region (CSR)
  int* ip      = (int*)(Wt2s + (size_t)D1 * D1);
  int* deg     = ip;                 // NN
  int* partial = deg + NN;           // 256
  int* rowstart= partial + 256;      // NN+1
  int* cursor  = rowstart + NN + 1;  // NN
  int* esrc    = cursor + NN;        // NE
  int* edst    = esrc + NE;          // NE

  const dim3 gemmGrid(2, (NN + 127) / 128);
  const int pairBlocks = (NE * NH + 15) / 16;
  const int edgeBlocks = (NE + 255) / 256;
  const int nodeBlocks = (NN + 255) / 256;
  const int wt1Blocks  = (D1 * INC + 255) / 256;
  const int wt2Blocks  = (D1 * D1 + 255) / 256;
  const int aggBlocks  = (NN + 3) / 4;

  // ======== Converts (once) ========
  cvt_bf16_k<<<(NN * INC / 4 + 255) / 256, 256, 0, stream>>>(x, Xb, NN * INC);
  wt_cvt_k<<<wt1Blocks, 256, 0, stream>>>(Wq1, Wt1q, 7, D1);
  wt_cvt_k<<<wt1Blocks, 256, 0, stream>>>(Wk1, Wt1k, 7, D1);
  wt_cvt_k<<<wt1Blocks, 256, 0, stream>>>(Wv1, Wt1v, 7, D1);
  wt_cvt_k<<<wt1Blocks, 256, 0, stream>>>(Ws1, Wt1s, 7, D1);
  wt_cvt_k<<<wt2Blocks, 256, 0, stream>>>(Wq2, Wt2q, 8, D1);
  wt_cvt_k<<<wt2Blocks, 256, 0, stream>>>(Wk2, Wt2k, 8, D1);
  wt_cvt_k<<<wt2Blocks, 256, 0, stream>>>(Wv2, Wt2v, 8, D1);
  wt_cvt_k<<<wt2Blocks, 256, 0, stream>>>(Ws2, Wt2s, 8, D1);

  // ======== CSR build (once, reused by both layers) ========
  fill_i<<<nodeBlocks, 256, 0, stream>>>(deg, 0, NN);
  deg_count<<<edgeBlocks, 256, 0, stream>>>(dstIdx, deg);
  scan1<<<NB_SCAN, 256, 0, stream>>>(deg, partial);
  scan2<<<1, 256, 0, stream>>>(partial, NB_SCAN);
  scan3<<<NB_SCAN, 256, 0, stream>>>(deg, partial, rowstart, cursor);
  scatter_k<<<edgeBlocks, 256, 0, stream>>>(srcIdx, dstIdx, cursor, esrc, edst);

  // ======== Layer 1 ========  (Xb -> H1b)
  gemm_mfma<float><<<gemmGrid, 256, 0, stream>>>(Xb, Wt1q, bq1, Qf, NN, INC);
  gemm_mfma<float><<<gemmGrid, 256, 0, stream>>>(Xb, Wt1k, bk1, Kf, NN, INC);
  gemm_mfma<float><<<gemmGrid, 256, 0, stream>>>(Xb, Wt1v, bv1, Vf, NN, INC);
  gemm_mfma<float><<<gemmGrid, 256, 0, stream>>>(Xb, Wt1s, bs1, SKf, NN, INC);
  edge_logits<<<pairBlocks, 256, 0, stream>>>(esrc, edst, Qf, Kf, alpha);
  node_agg<short><<<aggBlocks, 256, 0, stream>>>(rowstart, esrc, alpha, Vf, SKf, H1b);

  // ======== Layer 2 ========  (H1b -> H2 in SKf, in place)
  gemm_mfma<float><<<gemmGrid, 256, 0, stream>>>(H1b, Wt2q, bq2, Qf, NN, D1);
  gemm_mfma<float><<<gemmGrid, 256, 0, stream>>>(H1b, Wt2k, bk2, Kf, NN, D1);
  edge_logits<<<pairBlocks, 256, 0, stream>>>(esrc, edst, Qf, Kf, alpha);
  gemm_mfma<float><<<gemmGrid, 256, 0, stream>>>(H1b, Wt2v, bv2, Vf, NN, D1);
  gemm_mfma<float><<<gemmGrid, 256, 0, stream>>>(H1b, Wt2s, bs2, SKf, NN, D1);
  node_agg<float><<<aggBlocks, 256, 0, stream>>>(rowstart, esrc, alpha, Vf, SKf, SKf);

  // ======== Pool + head ========
  fill_k<<<(NG * D1 + NG + 255) / 256, 256, 0, stream>>>(sums, 0.f, NG * D1 + NG);
  pool_k<<<(NN + 63) / 64, 256, 0, stream>>>(SKf, batch, sums);
  count_k<<<(NN + 255) / 256, 256, 0, stream>>>(batch, cnt);
  head_k<<<1, 640, 0, stream>>>(sums, cnt, Wl, bl, (float*)d_out);
}

// Round 5
// 923.673 us; speedup vs baseline: 2.1914x; 1.1262x over previous
//
#include <hip/hip_runtime.h>
#include <math.h>

constexpr int NN   = 50000;   // nodes
constexpr int NE   = 400000;  // edges
constexpr int INC  = 128;     // in channels
constexpr int NH   = 4;       // heads
constexpr int D1   = 256;     // NH*HIDC
constexpr int NOUT = 10;      // classes
constexpr int NG   = 64;      // graphs
constexpr int NB_SCAN = (NN + 255) / 256;   // 196 scan blocks

typedef __attribute__((ext_vector_type(8))) short bf16x8;   // MFMA A/B frag
typedef __attribute__((ext_vector_type(4))) float f32x4;    // MFMA C/D frag

// ---------- bf16 pack (RNE) ----------
__device__ __forceinline__ short f2b(float f) {
  union { float f; unsigned int i; } v; v.f = f;
  unsigned int x = v.i;
  return (short)((x + 0x7FFFu + ((x >> 16) & 1u)) >> 16);
}

// ---------- fills ----------
__global__ void fill_i(int* __restrict__ p, int v, int n) {
  int i = blockIdx.x * 256 + threadIdx.x;
  if (i < n) p[i] = v;
}

// ---------- fp32 -> bf16 convert ----------
__global__ void cvt_bf16_k(const float* __restrict__ in, short* __restrict__ out, int n) {
  int i = (blockIdx.x * 256 + threadIdx.x) * 4;
  if (i >= n) return;
  float4 v = *(const float4*)(in + i);
  short4 o; o.x = f2b(v.x); o.y = f2b(v.y); o.z = f2b(v.z); o.w = f2b(v.w);
  *(short4*)(out + i) = o;
}

// ---------- W[K][N] fp32 -> Wt[N][K] bf16 ----------
__global__ void wt_cvt_k(const float* __restrict__ W, short* __restrict__ Wt,
                         int kbits, int N) {
  int i = blockIdx.x * 256 + threadIdx.x;
  int K = 1 << kbits;
  if (i >= N * K) return;
  int n = i >> kbits, k = i & (K - 1);
  Wt[i] = f2b(W[(size_t)k * N + n]);
}

// ---------- CSR build ----------
__global__ void deg_count(const int* __restrict__ dst, int* __restrict__ deg) {
  int e = blockIdx.x * 256 + threadIdx.x;
  if (e < NE) atomicAdd(&deg[dst[e]], 1);
}
__global__ __launch_bounds__(256) void scan1(const int* __restrict__ deg,
                                             int* __restrict__ partial) {
  __shared__ int sh[256];
  int t = threadIdx.x, i = blockIdx.x * 256 + t;
  sh[t] = (i < NN) ? deg[i] : 0;
  __syncthreads();
  for (int off = 128; off > 0; off >>= 1) {
    if (t < off) sh[t] += sh[t + off];
    __syncthreads();
  }
  if (t == 0) partial[blockIdx.x] = sh[0];
}
__global__ __launch_bounds__(256) void scan2(int* __restrict__ partial, int nb) {
  __shared__ int sh[256];
  int t = threadIdx.x;
  int v = (t < nb) ? partial[t] : 0;
  sh[t] = v;
  __syncthreads();
  for (int off = 1; off < 256; off <<= 1) {
    int o = (t >= off) ? sh[t - off] : 0;
    __syncthreads();
    sh[t] += o;
    __syncthreads();
  }
  if (t < nb) partial[t] = sh[t] - v;   // exclusive
}
__global__ __launch_bounds__(256) void scan3(const int* __restrict__ deg,
    const int* __restrict__ partial, int* __restrict__ rowstart,
    int* __restrict__ cursor) {
  __shared__ int sh[256];
  int t = threadIdx.x, i = blockIdx.x * 256 + t;
  int v = (i < NN) ? deg[i] : 0;
  sh[t] = v;
  __syncthreads();
  for (int off = 1; off < 256; off <<= 1) {
    int o = (t >= off) ? sh[t - off] : 0;
    __syncthreads();
    sh[t] += o;
    __syncthreads();
  }
  int excl = sh[t] - v + partial[blockIdx.x];
  if (i <= NN) rowstart[i] = excl;
  if (i < NN)  cursor[i]   = excl;
}
__global__ void scatter_k(const int* __restrict__ src, const int* __restrict__ dst,
    int* __restrict__ cursor, int* __restrict__ esrc, int* __restrict__ edst) {
  int e = blockIdx.x * 256 + threadIdx.x;
  if (e >= NE) return;
  int d = dst[e];
  int pos = atomicAdd(&cursor[d], 1);
  esrc[pos] = src[e];
  edst[pos] = d;
}

// ---------- MFMA GEMM: Y[M,256] = Xb[M,K](bf16) @ Wt[256,K]^T + bias ----------
constexpr int LDP = 56;
template <typename TOUT>
__device__ __forceinline__ void st1(TOUT* p, float v);
template <> __device__ __forceinline__ void st1<float>(float* p, float v) { *p = v; }
template <> __device__ __forceinline__ void st1<short>(short* p, float v) { *p = f2b(v); }

template <typename TOUT>
__global__ __launch_bounds__(256) void gemm_mfma(
    const short* __restrict__ Xb, const short* __restrict__ Wt,
    const float* __restrict__ bias, TOUT* __restrict__ Y, int M, int K) {
  __shared__ short As[128 * LDP];
  __shared__ short Bs[128 * LDP];
  const int t    = threadIdx.x;
  const int m0   = blockIdx.y * 128;
  const int n0   = blockIdx.x * 128;
  const int lane = t & 63;
  const int wv   = t >> 6;
  const int wm   = (wv >> 1) * 64;
  const int wn   = (wv & 1) * 64;
  const int quad = lane >> 4;
  const int l16  = lane & 15;

  f32x4 acc[4][4] = {};
  for (int k0 = 0; k0 < K; k0 += 32) {
#pragma unroll
    for (int it = 0; it < 2; ++it) {
      int c   = t + it * 256;
      int row = c >> 2, seg = c & 3;
      int gm  = m0 + row;
      int4 v  = make_int4(0, 0, 0, 0);
      if (gm < M) v = *(const int4*)(Xb + (size_t)gm * K + k0 + seg * 8);
      *(int4*)(&As[row * LDP + seg * 8]) = v;
      int4 w = *(const int4*)(Wt + (size_t)(n0 + row) * K + k0 + seg * 8);
      *(int4*)(&Bs[row * LDP + seg * 8]) = w;
    }
    __syncthreads();
    bf16x8 a[4], b[4];
#pragma unroll
    for (int mi = 0; mi < 4; mi++)
      a[mi] = *(const bf16x8*)(&As[(wm + mi * 16 + l16) * LDP + quad * 8]);
#pragma unroll
    for (int nj = 0; nj < 4; nj++)
      b[nj] = *(const bf16x8*)(&Bs[(wn + nj * 16 + l16) * LDP + quad * 8]);
#pragma unroll
    for (int mi = 0; mi < 4; mi++)
#pragma unroll
      for (int nj = 0; nj < 4; nj++)
        acc[mi][nj] = __builtin_amdgcn_mfma_f32_16x16x32_bf16(a[mi], b[nj], acc[mi][nj], 0, 0, 0);
    __syncthreads();
  }
#pragma unroll
  for (int mi = 0; mi < 4; mi++) {
#pragma unroll
    for (int r = 0; r < 4; r++) {
      int gm = m0 + wm + mi * 16 + quad * 4 + r;
      if (gm >= M) continue;
#pragma unroll
      for (int nj = 0; nj < 4; nj++) {
        int gn = n0 + wn + nj * 16 + l16;
        st1<TOUT>(Y + (size_t)gm * D1 + gn, acc[mi][nj][r] + bias[gn]);
      }
    }
  }
}

// ---------- per-edge attention logits (CSR order) ----------
__global__ __launch_bounds__(256) void edge_logits(
    const int* __restrict__ esrc, const int* __restrict__ edst,
    const float* __restrict__ Q, const float* __restrict__ Km,
    float* __restrict__ alpha) {
  const int t    = threadIdx.x;
  const int lane = t & 15;
  const int pair = blockIdx.x * 16 + (t >> 4);   // pos*NH + h
  if (pair >= NE * NH) return;
  const int pos = pair >> 2;
  const int h   = pair & 3;
  const int s = esrc[pos], d = edst[pos];
  const float4 qv = *(const float4*)(Q  + (size_t)d * D1 + h * 64 + lane * 4);
  const float4 kv = *(const float4*)(Km + (size_t)s * D1 + h * 64 + lane * 4);
  float dot = qv.x * kv.x + qv.y * kv.y + qv.z * kv.z + qv.w * kv.w;
#pragma unroll
  for (int off = 8; off >= 1; off >>= 1) dot += __shfl_xor(dot, off, 16);
  if (lane == 0) alpha[pair] = dot * 0.125f;    // / sqrt(64)
}

// ---------- fused node softmax + aggregate + skip + ELU (+cast) ----------
template <typename TOUT>
__global__ __launch_bounds__(256) void node_agg(
    const int* __restrict__ rowstart, const int* __restrict__ esrc,
    const float* __restrict__ alpha, const float* __restrict__ V,
    const float* __restrict__ skip, TOUT* __restrict__ out) {
  const int nid = blockIdx.x * 4 + (threadIdx.x >> 6);
  if (nid >= NN) return;
  const int t  = threadIdx.x & 63;
  const int h  = t >> 4;          // head for my 4 channels
  const int c0 = t * 4;
  const int r0 = rowstart[nid], r1 = rowstart[nid + 1];
  float mh = -INFINITY;
  for (int r = r0; r < r1; r++) mh = fmaxf(mh, alpha[r * 4 + h]);
  float4 acc = make_float4(0.f, 0.f, 0.f, 0.f);
  float denom = 0.f;
  for (int r = r0; r < r1; r++) {
    float ex = __expf(alpha[r * 4 + h] - mh);
    denom += ex;
    const float4 v = *(const float4*)(V + (size_t)esrc[r] * D1 + c0);
    acc.x += ex * v.x; acc.y += ex * v.y; acc.z += ex * v.z; acc.w += ex * v.w;
  }
  const float inv = 1.0f / (denom + 1e-16f);
  const float4 sk = *(const float4*)(skip + (size_t)nid * D1 + c0);
  float o0 = acc.x * inv + sk.x;
  float o1 = acc.y * inv + sk.y;
  float o2 = acc.z * inv + sk.z;
  float o3 = acc.w * inv + sk.w;
  o0 = o0 > 0.f ? o0 : expm1f(o0);
  o1 = o1 > 0.f ? o1 : expm1f(o1);
  o2 = o2 > 0.f ? o2 : expm1f(o2);
  o3 = o3 > 0.f ? o3 : expm1f(o3);
  TOUT* p = out + (size_t)nid * D1 + c0;
  st1<TOUT>(p + 0, o0); st1<TOUT>(p + 1, o1);
  st1<TOUT>(p + 2, o2); st1<TOUT>(p + 3, o3);
}

// ---------- graph boundaries via binary search (batch is sorted) ----------
__global__ void bounds_k(const int* __restrict__ batch, int* __restrict__ gb) {
  int g = threadIdx.x;            // 0..NG
  if (g > NG) return;
  int lo = 0, hi = NN;
  while (lo < hi) {               // lower_bound(batch, g)
    int mid = (lo + hi) >> 1;
    if (batch[mid] < g) lo = mid + 1; else hi = mid;
  }
  gb[g] = lo;
}

// ---------- per-graph mean pool (block per graph, no atomics) ----------
__global__ __launch_bounds__(256) void graph_pool(const float* __restrict__ h,
    const int* __restrict__ gb, float* __restrict__ pooled) {
  const int g = blockIdx.x;
  const int c = threadIdx.x;
  const int b0 = gb[g], b1 = gb[g + 1];
  float s = 0.f;
  for (int n = b0; n < b1; n++) s += h[(size_t)n * D1 + c];
  pooled[(size_t)g * D1 + c] = s / fmaxf((float)(b1 - b0), 1.0f);
}

// ---------- classifier + log_softmax ----------
__global__ __launch_bounds__(640) void head_k(const float* __restrict__ pooled,
    const float* __restrict__ Wl, const float* __restrict__ bl,
    float* __restrict__ out) {
  __shared__ float logits[NG][NOUT];
  const int t = threadIdx.x;
  if (t < NG * NOUT) {
    int g = t / NOUT, o = t % NOUT;
    float acc = 0.f;
    for (int k = 0; k < D1; k++) acc += pooled[(size_t)g * D1 + k] * Wl[k * NOUT + o];
    logits[g][o] = acc + bl[o];
  }
  __syncthreads();
  if (t < NG) {
    float mx = -INFINITY;
#pragma unroll
    for (int o = 0; o < NOUT; o++) mx = fmaxf(mx, logits[t][o]);
    float s = 0.f;
#pragma unroll
    for (int o = 0; o < NOUT; o++) s += __expf(logits[t][o] - mx);
    float lse = mx + logf(s);
#pragma unroll
    for (int o = 0; o < NOUT; o++) out[t * NOUT + o] = logits[t][o] - lse;
  }
}

// ---------------------------------------------------------------------------
extern "C" void kernel_launch(void* const* d_in, const int* in_sizes, int n_in,
                              void* d_out, int out_size, void* d_ws, size_t ws_size,
                              hipStream_t stream) {
  const float* x   = (const float*)d_in[0];
  const int* ei    = (const int*)d_in[1];
  const int* batch = (const int*)d_in[2];
  const float* Wq1 = (const float*)d_in[3];  const float* bq1 = (const float*)d_in[4];
  const float* Wk1 = (const float*)d_in[5];  const float* bk1 = (const float*)d_in[6];
  const float* Wv1 = (const float*)d_in[7];  const float* bv1 = (const float*)d_in[8];
  const float* Ws1 = (const float*)d_in[9];  const float* bs1 = (const float*)d_in[10];
  const float* Wq2 = (const float*)d_in[11]; const float* bq2 = (const float*)d_in[12];
  const float* Wk2 = (const float*)d_in[13]; const float* bk2 = (const float*)d_in[14];
  const float* Wv2 = (const float*)d_in[15]; const float* bv2 = (const float*)d_in[16];
  const float* Ws2 = (const float*)d_in[17]; const float* bs2 = (const float*)d_in[18];
  const float* Wl  = (const float*)d_in[19]; const float* bl  = (const float*)d_in[20];

  const int* srcIdx = ei;          // edge_index[0] (source j)
  const int* dstIdx = ei + NE;     // edge_index[1] (target i)

  // -------- workspace layout --------
  float* ws = (float*)d_ws;
  const size_t SZ_NODE = (size_t)NN * D1;       // 12.8M floats
  float* Qf     = ws;                            // 51.2 MB
  float* Kf     = ws + SZ_NODE;
  float* Vf     = ws + 2 * SZ_NODE;
  float* SKf    = ws + 3 * SZ_NODE;              // skip; layer-2 out in place
  float* alpha  = ws + 4 * SZ_NODE;              // NE*NH (CSR order)
  float* pooled = alpha + (size_t)NE * NH;       // NG*D1
  // bf16 region
  short* Xb   = (short*)(pooled + (size_t)NG * D1);  // NN*INC
  short* H1b  = Xb + (size_t)NN * INC;           // NN*D1
  short* Wt1q = H1b + SZ_NODE;
  short* Wt1k = Wt1q + (size_t)D1 * INC;
  short* Wt1v = Wt1k + (size_t)D1 * INC;
  short* Wt1s = Wt1v + (size_t)D1 * INC;
  short* Wt2q = Wt1s + (size_t)D1 * INC;
  short* Wt2k = Wt2q + (size_t)D1 * D1;
  short* Wt2v = Wt2k + (size_t)D1 * D1;
  short* Wt2s = Wt2v + (size_t)D1 * D1;
  // int region (CSR + graph bounds)
  int* ip      = (int*)(Wt2s + (size_t)D1 * D1);
  int* deg     = ip;                 // NN
  int* partial = deg + NN;           // 256
  int* rowstart= partial + 256;      // NN+1
  int* cursor  = rowstart + NN + 1;  // NN
  int* esrc    = cursor + NN;        // NE
  int* edst    = esrc + NE;          // NE
  int* gb      = edst + NE;          // NG+1

  const dim3 gemmGrid(2, (NN + 127) / 128);
  const int pairBlocks = (NE * NH + 15) / 16;
  const int edgeBlocks = (NE + 255) / 256;
  const int nodeBlocks = (NN + 255) / 256;
  const int wt1Blocks  = (D1 * INC + 255) / 256;
  const int wt2Blocks  = (D1 * D1 + 255) / 256;
  const int aggBlocks  = (NN + 3) / 4;

  // ======== Converts (once) ========
  cvt_bf16_k<<<(NN * INC / 4 + 255) / 256, 256, 0, stream>>>(x, Xb, NN * INC);
  wt_cvt_k<<<wt1Blocks, 256, 0, stream>>>(Wq1, Wt1q, 7, D1);
  wt_cvt_k<<<wt1Blocks, 256, 0, stream>>>(Wk1, Wt1k, 7, D1);
  wt_cvt_k<<<wt1Blocks, 256, 0, stream>>>(Wv1, Wt1v, 7, D1);
  wt_cvt_k<<<wt1Blocks, 256, 0, stream>>>(Ws1, Wt1s, 7, D1);
  wt_cvt_k<<<wt2Blocks, 256, 0, stream>>>(Wq2, Wt2q, 8, D1);
  wt_cvt_k<<<wt2Blocks, 256, 0, stream>>>(Wk2, Wt2k, 8, D1);
  wt_cvt_k<<<wt2Blocks, 256, 0, stream>>>(Wv2, Wt2v, 8, D1);
  wt_cvt_k<<<wt2Blocks, 256, 0, stream>>>(Ws2, Wt2s, 8, D1);

  // ======== CSR build + graph bounds (once) ========
  fill_i<<<nodeBlocks, 256, 0, stream>>>(deg, 0, NN);
  deg_count<<<edgeBlocks, 256, 0, stream>>>(dstIdx, deg);
  scan1<<<NB_SCAN, 256, 0, stream>>>(deg, partial);
  scan2<<<1, 256, 0, stream>>>(partial, NB_SCAN);
  scan3<<<NB_SCAN, 256, 0, stream>>>(deg, partial, rowstart, cursor);
  scatter_k<<<edgeBlocks, 256, 0, stream>>>(srcIdx, dstIdx, cursor, esrc, edst);
  bounds_k<<<1, 128, 0, stream>>>(batch, gb);

  // ======== Layer 1 ========  (Xb -> H1b)
  gemm_mfma<float><<<gemmGrid, 256, 0, stream>>>(Xb, Wt1q, bq1, Qf, NN, INC);
  gemm_mfma<float><<<gemmGrid, 256, 0, stream>>>(Xb, Wt1k, bk1, Kf, NN, INC);
  gemm_mfma<float><<<gemmGrid, 256, 0, stream>>>(Xb, Wt1v, bv1, Vf, NN, INC);
  gemm_mfma<float><<<gemmGrid, 256, 0, stream>>>(Xb, Wt1s, bs1, SKf, NN, INC);
  edge_logits<<<pairBlocks, 256, 0, stream>>>(esrc, edst, Qf, Kf, alpha);
  node_agg<short><<<aggBlocks, 256, 0, stream>>>(rowstart, esrc, alpha, Vf, SKf, H1b);

  // ======== Layer 2 ========  (H1b -> H2 in SKf, in place)
  gemm_mfma<float><<<gemmGrid, 256, 0, stream>>>(H1b, Wt2q, bq2, Qf, NN, D1);
  gemm_mfma<float><<<gemmGrid, 256, 0, stream>>>(H1b, Wt2k, bk2, Kf, NN, D1);
  edge_logits<<<pairBlocks, 256, 0, stream>>>(esrc, edst, Qf, Kf, alpha);
  gemm_mfma<float><<<gemmGrid, 256, 0, stream>>>(H1b, Wt2v, bv2, Vf, NN, D1);
  gemm_mfma<float><<<gemmGrid, 256, 0, stream>>>(H1b, Wt2s, bs2, SKf, NN, D1);
  node_agg<float><<<aggBlocks, 256, 0, stream>>>(rowstart, esrc, alpha, Vf, SKf, SKf);

  // ======== Pool + head ========
  graph_pool<<<NG, 256, 0, stream>>>(SKf, gb, pooled);
  head_k<<<1, 640, 0, stream>>>(pooled, Wl, bl, (float*)d_out);
}

// Round 6
// 744.492 us; speedup vs baseline: 2.7188x; 1.2407x over previous
//
#include <hip/hip_runtime.h>
#include <math.h>

constexpr int NN   = 50000;   // nodes
constexpr int NE   = 400000;  // edges
constexpr int INC  = 128;     // in channels
constexpr int NH   = 4;       // heads
constexpr int D1   = 256;     // NH*HIDC
constexpr int NOUT = 10;      // classes
constexpr int NG   = 64;      // graphs
constexpr int NB_SCAN = (NN + 255) / 256;   // 196 scan blocks

typedef __attribute__((ext_vector_type(8))) short bf16x8;   // MFMA A/B frag
typedef __attribute__((ext_vector_type(4))) float f32x4;    // MFMA C/D frag

// ---------- bf16 pack (RNE) ----------
__device__ __forceinline__ short f2b(float f) {
  union { float f; unsigned int i; } v; v.f = f;
  unsigned int x = v.i;
  return (short)((x + 0x7FFFu + ((x >> 16) & 1u)) >> 16);
}

// ---------- fills ----------
__global__ void fill_i(int* __restrict__ p, int v, int n) {
  int i = blockIdx.x * 256 + threadIdx.x;
  if (i < n) p[i] = v;
}
__global__ void fill_f(float* __restrict__ p, float v, int n) {
  int i = blockIdx.x * 256 + threadIdx.x;
  if (i < n) p[i] = v;
}

// ---------- fp32 -> bf16 convert ----------
__global__ void cvt_bf16_k(const float* __restrict__ in, short* __restrict__ out, int n) {
  int i = (blockIdx.x * 256 + threadIdx.x) * 4;
  if (i >= n) return;
  float4 v = *(const float4*)(in + i);
  short4 o; o.x = f2b(v.x); o.y = f2b(v.y); o.z = f2b(v.z); o.w = f2b(v.w);
  *(short4*)(out + i) = o;
}

// ---------- W[K][N] fp32 -> Wt[N][K] bf16 ----------
__global__ void wt_cvt_k(const float* __restrict__ W, short* __restrict__ Wt,
                         int kbits, int N) {
  int i = blockIdx.x * 256 + threadIdx.x;
  int K = 1 << kbits;
  if (i >= N * K) return;
  int n = i >> kbits, k = i & (K - 1);
  Wt[i] = f2b(W[(size_t)k * N + n]);
}

// ---------- CSR build ----------
__global__ void deg_count(const int* __restrict__ dst, int* __restrict__ deg) {
  int e = blockIdx.x * 256 + threadIdx.x;
  if (e < NE) atomicAdd(&deg[dst[e]], 1);
}
__global__ __launch_bounds__(256) void scan1(const int* __restrict__ deg,
                                             int* __restrict__ partial) {
  __shared__ int sh[256];
  int t = threadIdx.x, i = blockIdx.x * 256 + t;
  sh[t] = (i < NN) ? deg[i] : 0;
  __syncthreads();
  for (int off = 128; off > 0; off >>= 1) {
    if (t < off) sh[t] += sh[t + off];
    __syncthreads();
  }
  if (t == 0) partial[blockIdx.x] = sh[0];
}
__global__ __launch_bounds__(256) void scan2(int* __restrict__ partial, int nb) {
  __shared__ int sh[256];
  int t = threadIdx.x;
  int v = (t < nb) ? partial[t] : 0;
  sh[t] = v;
  __syncthreads();
  for (int off = 1; off < 256; off <<= 1) {
    int o = (t >= off) ? sh[t - off] : 0;
    __syncthreads();
    sh[t] += o;
    __syncthreads();
  }
  if (t < nb) partial[t] = sh[t] - v;   // exclusive
}
__global__ __launch_bounds__(256) void scan3(const int* __restrict__ deg,
    const int* __restrict__ partial, int* __restrict__ rowstart,
    int* __restrict__ cursor) {
  __shared__ int sh[256];
  int t = threadIdx.x, i = blockIdx.x * 256 + t;
  int v = (i < NN) ? deg[i] : 0;
  sh[t] = v;
  __syncthreads();
  for (int off = 1; off < 256; off <<= 1) {
    int o = (t >= off) ? sh[t - off] : 0;
    __syncthreads();
    sh[t] += o;
    __syncthreads();
  }
  int excl = sh[t] - v + partial[blockIdx.x];
  if (i <= NN) rowstart[i] = excl;
  if (i < NN)  cursor[i]   = excl;
}
__global__ void scatter_k(const int* __restrict__ src, const int* __restrict__ dst,
    int* __restrict__ cursor, int* __restrict__ esrc, int* __restrict__ edst) {
  int e = blockIdx.x * 256 + threadIdx.x;
  if (e >= NE) return;
  int d = dst[e];
  int pos = atomicAdd(&cursor[d], 1);
  esrc[pos] = src[e];
  edst[pos] = d;
}

// ---------- MFMA GEMM: Y[M,256] = Xb[M,K](bf16) @ Wt[256,K]^T + bias ----------
constexpr int LDP = 56;
template <typename TOUT>
__device__ __forceinline__ void st1(TOUT* p, float v);
template <> __device__ __forceinline__ void st1<float>(float* p, float v) { *p = v; }
template <> __device__ __forceinline__ void st1<short>(short* p, float v) { *p = f2b(v); }

template <typename TOUT>
__global__ __launch_bounds__(256) void gemm_mfma(
    const short* __restrict__ Xb, const short* __restrict__ Wt,
    const float* __restrict__ bias, TOUT* __restrict__ Y, int M, int K) {
  __shared__ short As[128 * LDP];
  __shared__ short Bs[128 * LDP];
  const int t    = threadIdx.x;
  const int m0   = blockIdx.y * 128;
  const int n0   = blockIdx.x * 128;
  const int lane = t & 63;
  const int wv   = t >> 6;
  const int wm   = (wv >> 1) * 64;
  const int wn   = (wv & 1) * 64;
  const int quad = lane >> 4;
  const int l16  = lane & 15;

  f32x4 acc[4][4] = {};
  for (int k0 = 0; k0 < K; k0 += 32) {
#pragma unroll
    for (int it = 0; it < 2; ++it) {
      int c   = t + it * 256;
      int row = c >> 2, seg = c & 3;
      int gm  = m0 + row;
      int4 v  = make_int4(0, 0, 0, 0);
      if (gm < M) v = *(const int4*)(Xb + (size_t)gm * K + k0 + seg * 8);
      *(int4*)(&As[row * LDP + seg * 8]) = v;
      int4 w = *(const int4*)(Wt + (size_t)(n0 + row) * K + k0 + seg * 8);
      *(int4*)(&Bs[row * LDP + seg * 8]) = w;
    }
    __syncthreads();
    bf16x8 a[4], b[4];
#pragma unroll
    for (int mi = 0; mi < 4; mi++)
      a[mi] = *(const bf16x8*)(&As[(wm + mi * 16 + l16) * LDP + quad * 8]);
#pragma unroll
    for (int nj = 0; nj < 4; nj++)
      b[nj] = *(const bf16x8*)(&Bs[(wn + nj * 16 + l16) * LDP + quad * 8]);
#pragma unroll
    for (int mi = 0; mi < 4; mi++)
#pragma unroll
      for (int nj = 0; nj < 4; nj++)
        acc[mi][nj] = __builtin_amdgcn_mfma_f32_16x16x32_bf16(a[mi], b[nj], acc[mi][nj], 0, 0, 0);
    __syncthreads();
  }
#pragma unroll
  for (int mi = 0; mi < 4; mi++) {
#pragma unroll
    for (int r = 0; r < 4; r++) {
      int gm = m0 + wm + mi * 16 + quad * 4 + r;
      if (gm >= M) continue;
#pragma unroll
      for (int nj = 0; nj < 4; nj++) {
        int gn = n0 + wn + nj * 16 + l16;
        st1<TOUT>(Y + (size_t)gm * D1 + gn, acc[mi][nj][r] + bias[gn]);
      }
    }
  }
}

// ---------- per-edge attention logits (CSR order) ----------
__global__ __launch_bounds__(256) void edge_logits(
    const int* __restrict__ esrc, const int* __restrict__ edst,
    const float* __restrict__ Q, const float* __restrict__ Km,
    float* __restrict__ alpha) {
  const int t    = threadIdx.x;
  const int lane = t & 15;
  const int pair = blockIdx.x * 16 + (t >> 4);   // pos*NH + h
  if (pair >= NE * NH) return;
  const int pos = pair >> 2;
  const int h   = pair & 3;
  const int s = esrc[pos], d = edst[pos];
  const float4 qv = *(const float4*)(Q  + (size_t)d * D1 + h * 64 + lane * 4);
  const float4 kv = *(const float4*)(Km + (size_t)s * D1 + h * 64 + lane * 4);
  float dot = qv.x * kv.x + qv.y * kv.y + qv.z * kv.z + qv.w * kv.w;
#pragma unroll
  for (int off = 8; off >= 1; off >>= 1) dot += __shfl_xor(dot, off, 16);
  if (lane == 0) alpha[pair] = dot * 0.125f;    // / sqrt(64)
}

// ---------- fused node softmax + aggregate + skip + ELU (+cast) ----------
template <typename TOUT>
__global__ __launch_bounds__(256) void node_agg(
    const int* __restrict__ rowstart, const int* __restrict__ esrc,
    const float* __restrict__ alpha, const float* __restrict__ V,
    const float* __restrict__ skip, TOUT* __restrict__ out) {
  const int nid = blockIdx.x * 4 + (threadIdx.x >> 6);
  if (nid >= NN) return;
  const int t  = threadIdx.x & 63;
  const int h  = t >> 4;          // head for my 4 channels
  const int c0 = t * 4;
  const int r0 = rowstart[nid], r1 = rowstart[nid + 1];
  float mh = -INFINITY;
  for (int r = r0; r < r1; r++) mh = fmaxf(mh, alpha[r * 4 + h]);
  float4 acc = make_float4(0.f, 0.f, 0.f, 0.f);
  float denom = 0.f;
  for (int r = r0; r < r1; r++) {
    float ex = __expf(alpha[r * 4 + h] - mh);
    denom += ex;
    const float4 v = *(const float4*)(V + (size_t)esrc[r] * D1 + c0);
    acc.x += ex * v.x; acc.y += ex * v.y; acc.z += ex * v.z; acc.w += ex * v.w;
  }
  const float inv = 1.0f / (denom + 1e-16f);
  const float4 sk = *(const float4*)(skip + (size_t)nid * D1 + c0);
  float o0 = acc.x * inv + sk.x;
  float o1 = acc.y * inv + sk.y;
  float o2 = acc.z * inv + sk.z;
  float o3 = acc.w * inv + sk.w;
  o0 = o0 > 0.f ? o0 : expm1f(o0);
  o1 = o1 > 0.f ? o1 : expm1f(o1);
  o2 = o2 > 0.f ? o2 : expm1f(o2);
  o3 = o3 > 0.f ? o3 : expm1f(o3);
  TOUT* p = out + (size_t)nid * D1 + c0;
  st1<TOUT>(p + 0, o0); st1<TOUT>(p + 1, o1);
  st1<TOUT>(p + 2, o2); st1<TOUT>(p + 3, o3);
}

// ---------- graph boundaries via binary search (batch is sorted) ----------
__global__ void bounds_k(const int* __restrict__ batch, int* __restrict__ gb) {
  int g = threadIdx.x;            // 0..NG
  if (g > NG) return;
  int lo = 0, hi = NN;
  while (lo < hi) {               // lower_bound(batch, g)
    int mid = (lo + hi) >> 1;
    if (batch[mid] < g) lo = mid + 1; else hi = mid;
  }
  gb[g] = lo;
}

// ---------- mean-pool partial sums (parallel, run-length atomics) ----------
// block = 64 consecutive nodes; thread = channel. Sorted batch -> <=2-3
// graph switches per block -> few atomics, spread over NG*D1 addresses.
__global__ __launch_bounds__(256) void pool_k(const float* __restrict__ h,
    const int* __restrict__ batch, float* __restrict__ sums) {
  const int c = threadIdx.x;
  const int n0 = blockIdx.x * 64;
  const int n1 = min(n0 + 64, NN);
  float run = 0.f;
  int curg = -1;
  for (int n = n0; n < n1; n++) {
    int g = batch[n];
    if (g != curg) {
      if (curg >= 0) atomicAdd(&sums[(size_t)curg * D1 + c], run);
      run = 0.f; curg = g;
    }
    run += h[(size_t)n * D1 + c];
  }
  if (curg >= 0) atomicAdd(&sums[(size_t)curg * D1 + c], run);
}

// ---------- classifier + log_softmax (counts from gb) ----------
__global__ __launch_bounds__(640) void head_k(const float* __restrict__ sums,
    const int* __restrict__ gb, const float* __restrict__ Wl,
    const float* __restrict__ bl, float* __restrict__ out) {
  __shared__ float logits[NG][NOUT];
  const int t = threadIdx.x;
  if (t < NG * NOUT) {
    int g = t / NOUT, o = t % NOUT;
    float inv = 1.0f / fmaxf((float)(gb[g + 1] - gb[g]), 1.0f);
    float acc = 0.f;
    for (int k = 0; k < D1; k++) acc += sums[(size_t)g * D1 + k] * Wl[k * NOUT + o];
    logits[g][o] = acc * inv + bl[o];
  }
  __syncthreads();
  if (t < NG) {
    float mx = -INFINITY;
#pragma unroll
    for (int o = 0; o < NOUT; o++) mx = fmaxf(mx, logits[t][o]);
    float s = 0.f;
#pragma unroll
    for (int o = 0; o < NOUT; o++) s += __expf(logits[t][o] - mx);
    float lse = mx + logf(s);
#pragma unroll
    for (int o = 0; o < NOUT; o++) out[t * NOUT + o] = logits[t][o] - lse;
  }
}

// ---------------------------------------------------------------------------
extern "C" void kernel_launch(void* const* d_in, const int* in_sizes, int n_in,
                              void* d_out, int out_size, void* d_ws, size_t ws_size,
                              hipStream_t stream) {
  const float* x   = (const float*)d_in[0];
  const int* ei    = (const int*)d_in[1];
  const int* batch = (const int*)d_in[2];
  const float* Wq1 = (const float*)d_in[3];  const float* bq1 = (const float*)d_in[4];
  const float* Wk1 = (const float*)d_in[5];  const float* bk1 = (const float*)d_in[6];
  const float* Wv1 = (const float*)d_in[7];  const float* bv1 = (const float*)d_in[8];
  const float* Ws1 = (const float*)d_in[9];  const float* bs1 = (const float*)d_in[10];
  const float* Wq2 = (const float*)d_in[11]; const float* bq2 = (const float*)d_in[12];
  const float* Wk2 = (const float*)d_in[13]; const float* bk2 = (const float*)d_in[14];
  const float* Wv2 = (const float*)d_in[15]; const float* bv2 = (const float*)d_in[16];
  const float* Ws2 = (const float*)d_in[17]; const float* bs2 = (const float*)d_in[18];
  const float* Wl  = (const float*)d_in[19]; const float* bl  = (const float*)d_in[20];

  const int* srcIdx = ei;          // edge_index[0] (source j)
  const int* dstIdx = ei + NE;     // edge_index[1] (target i)

  // -------- workspace layout --------
  float* ws = (float*)d_ws;
  const size_t SZ_NODE = (size_t)NN * D1;       // 12.8M floats
  float* Qf     = ws;                            // 51.2 MB
  float* Kf     = ws + SZ_NODE;
  float* Vf     = ws + 2 * SZ_NODE;
  float* SKf    = ws + 3 * SZ_NODE;              // skip; layer-2 out in place
  float* alpha  = ws + 4 * SZ_NODE;              // NE*NH (CSR order)
  float* sums   = alpha + (size_t)NE * NH;       // NG*D1
  // bf16 region
  short* Xb   = (short*)(sums + (size_t)NG * D1);  // NN*INC
  short* H1b  = Xb + (size_t)NN * INC;           // NN*D1
  short* Wt1q = H1b + SZ_NODE;
  short* Wt1k = Wt1q + (size_t)D1 * INC;
  short* Wt1v = Wt1k + (size_t)D1 * INC;
  short* Wt1s = Wt1v + (size_t)D1 * INC;
  short* Wt2q = Wt1s + (size_t)D1 * INC;
  short* Wt2k = Wt2q + (size_t)D1 * D1;
  short* Wt2v = Wt2k + (size_t)D1 * D1;
  short* Wt2s = Wt2v + (size_t)D1 * D1;
  // int region (CSR + graph bounds)
  int* ip      = (int*)(Wt2s + (size_t)D1 * D1);
  int* deg     = ip;                 // NN
  int* partial = deg + NN;           // 256
  int* rowstart= partial + 256;      // NN+1
  int* cursor  = rowstart + NN + 1;  // NN
  int* esrc    = cursor + NN;        // NE
  int* edst    = esrc + NE;          // NE
  int* gb      = edst + NE;          // NG+1

  const dim3 gemmGrid(2, (NN + 127) / 128);
  const int pairBlocks = (NE * NH + 15) / 16;
  const int edgeBlocks = (NE + 255) / 256;
  const int nodeBlocks = (NN + 255) / 256;
  const int wt1Blocks  = (D1 * INC + 255) / 256;
  const int wt2Blocks  = (D1 * D1 + 255) / 256;
  const int aggBlocks  = (NN + 3) / 4;

  // ======== Converts (once) ========
  cvt_bf16_k<<<(NN * INC / 4 + 255) / 256, 256, 0, stream>>>(x, Xb, NN * INC);
  wt_cvt_k<<<wt1Blocks, 256, 0, stream>>>(Wq1, Wt1q, 7, D1);
  wt_cvt_k<<<wt1Blocks, 256, 0, stream>>>(Wk1, Wt1k, 7, D1);
  wt_cvt_k<<<wt1Blocks, 256, 0, stream>>>(Wv1, Wt1v, 7, D1);
  wt_cvt_k<<<wt1Blocks, 256, 0, stream>>>(Ws1, Wt1s, 7, D1);
  wt_cvt_k<<<wt2Blocks, 256, 0, stream>>>(Wq2, Wt2q, 8, D1);
  wt_cvt_k<<<wt2Blocks, 256, 0, stream>>>(Wk2, Wt2k, 8, D1);
  wt_cvt_k<<<wt2Blocks, 256, 0, stream>>>(Wv2, Wt2v, 8, D1);
  wt_cvt_k<<<wt2Blocks, 256, 0, stream>>>(Ws2, Wt2s, 8, D1);

  // ======== CSR build + graph bounds (once) ========
  fill_i<<<nodeBlocks, 256, 0, stream>>>(deg, 0, NN);
  deg_count<<<edgeBlocks, 256, 0, stream>>>(dstIdx, deg);
  scan1<<<NB_SCAN, 256, 0, stream>>>(deg, partial);
  scan2<<<1, 256, 0, stream>>>(partial, NB_SCAN);
  scan3<<<NB_SCAN, 256, 0, stream>>>(deg, partial, rowstart, cursor);
  scatter_k<<<edgeBlocks, 256, 0, stream>>>(srcIdx, dstIdx, cursor, esrc, edst);
  bounds_k<<<1, 128, 0, stream>>>(batch, gb);

  // ======== Layer 1 ========  (Xb -> H1b)
  gemm_mfma<float><<<gemmGrid, 256, 0, stream>>>(Xb, Wt1q, bq1, Qf, NN, INC);
  gemm_mfma<float><<<gemmGrid, 256, 0, stream>>>(Xb, Wt1k, bk1, Kf, NN, INC);
  gemm_mfma<float><<<gemmGrid, 256, 0, stream>>>(Xb, Wt1v, bv1, Vf, NN, INC);
  gemm_mfma<float><<<gemmGrid, 256, 0, stream>>>(Xb, Wt1s, bs1, SKf, NN, INC);
  edge_logits<<<pairBlocks, 256, 0, stream>>>(esrc, edst, Qf, Kf, alpha);
  node_agg<short><<<aggBlocks, 256, 0, stream>>>(rowstart, esrc, alpha, Vf, SKf, H1b);

  // ======== Layer 2 ========  (H1b -> H2 in SKf, in place)
  gemm_mfma<float><<<gemmGrid, 256, 0, stream>>>(H1b, Wt2q, bq2, Qf, NN, D1);
  gemm_mfma<float><<<gemmGrid, 256, 0, stream>>>(H1b, Wt2k, bk2, Kf, NN, D1);
  edge_logits<<<pairBlocks, 256, 0, stream>>>(esrc, edst, Qf, Kf, alpha);
  gemm_mfma<float><<<gemmGrid, 256, 0, stream>>>(H1b, Wt2v, bv2, Vf, NN, D1);
  gemm_mfma<float><<<gemmGrid, 256, 0, stream>>>(H1b, Wt2s, bs2, SKf, NN, D1);
  node_agg<float><<<aggBlocks, 256, 0, stream>>>(rowstart, esrc, alpha, Vf, SKf, SKf);

  // ======== Pool + head ========
  fill_f<<<(NG * D1 + 255) / 256, 256, 0, stream>>>(sums, 0.f, NG * D1);
  pool_k<<<(NN + 63) / 64, 256, 0, stream>>>(SKf, batch, sums);
  head_k<<<1, 640, 0, stream>>>(sums, gb, Wl, bl, (float*)d_out);
}

// Round 7
// 568.280 us; speedup vs baseline: 3.5619x; 1.3101x over previous
//
#include <hip/hip_runtime.h>
#include <math.h>

constexpr int NN   = 50000;   // nodes
constexpr int NE   = 400000;  // edges
constexpr int INC  = 128;     // in channels
constexpr int NH   = 4;       // heads
constexpr int D1   = 256;     // NH*HIDC
constexpr int NOUT = 10;      // classes
constexpr int NG   = 64;      // graphs
constexpr int NB_SCAN = (NN + 255) / 256;   // 196 scan blocks

typedef __attribute__((ext_vector_type(8))) short bf16x8;   // MFMA A/B frag
typedef __attribute__((ext_vector_type(4))) float f32x4;    // MFMA C/D frag

// ---------- bf16 helpers ----------
__device__ __forceinline__ short f2b(float f) {
  union { float f; unsigned int i; } v; v.f = f;
  unsigned int x = v.i;
  return (short)((x + 0x7FFFu + ((x >> 16) & 1u)) >> 16);
}
__device__ __forceinline__ float b2f(short u) {
  union { unsigned int i; float f; } v; v.i = ((unsigned int)(unsigned short)u) << 16;
  return v.f;
}
__device__ __forceinline__ float4 ld4b(const short* p) {
  short4 u = *(const short4*)p;
  return make_float4(b2f(u.x), b2f(u.y), b2f(u.z), b2f(u.w));
}

// ---------- fills ----------
__global__ void fill_i(int* __restrict__ p, int v, int n) {
  int i = blockIdx.x * 256 + threadIdx.x;
  if (i < n) p[i] = v;
}
__global__ void fill_f(float* __restrict__ p, float v, int n) {
  int i = blockIdx.x * 256 + threadIdx.x;
  if (i < n) p[i] = v;
}

// ---------- fp32 -> bf16 convert ----------
__global__ void cvt_bf16_k(const float* __restrict__ in, short* __restrict__ out, int n) {
  int i = (blockIdx.x * 256 + threadIdx.x) * 4;
  if (i >= n) return;
  float4 v = *(const float4*)(in + i);
  short4 o; o.x = f2b(v.x); o.y = f2b(v.y); o.z = f2b(v.z); o.w = f2b(v.w);
  *(short4*)(out + i) = o;
}

// ---------- W[K][N] fp32 -> Wt[N][K] bf16 ----------
__global__ void wt_cvt_k(const float* __restrict__ W, short* __restrict__ Wt,
                         int kbits, int N) {
  int i = blockIdx.x * 256 + threadIdx.x;
  int K = 1 << kbits;
  if (i >= N * K) return;
  int n = i >> kbits, k = i & (K - 1);
  Wt[i] = f2b(W[(size_t)k * N + n]);
}

// ---------- CSR build ----------
__global__ void deg_count(const int* __restrict__ dst, int* __restrict__ deg) {
  int e = blockIdx.x * 256 + threadIdx.x;
  if (e < NE) atomicAdd(&deg[dst[e]], 1);
}
__global__ __launch_bounds__(256) void scan1(const int* __restrict__ deg,
                                             int* __restrict__ partial) {
  __shared__ int sh[256];
  int t = threadIdx.x, i = blockIdx.x * 256 + t;
  sh[t] = (i < NN) ? deg[i] : 0;
  __syncthreads();
  for (int off = 128; off > 0; off >>= 1) {
    if (t < off) sh[t] += sh[t + off];
    __syncthreads();
  }
  if (t == 0) partial[blockIdx.x] = sh[0];
}
__global__ __launch_bounds__(256) void scan2(int* __restrict__ partial, int nb) {
  __shared__ int sh[256];
  int t = threadIdx.x;
  int v = (t < nb) ? partial[t] : 0;
  sh[t] = v;
  __syncthreads();
  for (int off = 1; off < 256; off <<= 1) {
    int o = (t >= off) ? sh[t - off] : 0;
    __syncthreads();
    sh[t] += o;
    __syncthreads();
  }
  if (t < nb) partial[t] = sh[t] - v;   // exclusive
}
__global__ __launch_bounds__(256) void scan3(const int* __restrict__ deg,
    const int* __restrict__ partial, int* __restrict__ rowstart,
    int* __restrict__ cursor) {
  __shared__ int sh[256];
  int t = threadIdx.x, i = blockIdx.x * 256 + t;
  int v = (i < NN) ? deg[i] : 0;
  sh[t] = v;
  __syncthreads();
  for (int off = 1; off < 256; off <<= 1) {
    int o = (t >= off) ? sh[t - off] : 0;
    __syncthreads();
    sh[t] += o;
    __syncthreads();
  }
  int excl = sh[t] - v + partial[blockIdx.x];
  if (i <= NN) rowstart[i] = excl;
  if (i < NN)  cursor[i]   = excl;
}
__global__ void scatter_k(const int* __restrict__ src, const int* __restrict__ dst,
    int* __restrict__ cursor, int* __restrict__ esrc) {
  int e = blockIdx.x * 256 + threadIdx.x;
  if (e >= NE) return;
  int d = dst[e];
  int pos = atomicAdd(&cursor[d], 1);
  esrc[pos] = src[e];
}

// ---------- MFMA GEMM: Y[M,256] = Xb[M,K](bf16) @ Wt[256,K]^T + bias ----------
constexpr int LDP = 56;
template <typename TOUT>
__device__ __forceinline__ void st1(TOUT* p, float v);
template <> __device__ __forceinline__ void st1<float>(float* p, float v) { *p = v; }
template <> __device__ __forceinline__ void st1<short>(short* p, float v) { *p = f2b(v); }

template <typename TOUT>
__global__ __launch_bounds__(256) void gemm_mfma(
    const short* __restrict__ Xb, const short* __restrict__ Wt,
    const float* __restrict__ bias, TOUT* __restrict__ Y, int M, int K) {
  __shared__ short As[128 * LDP];
  __shared__ short Bs[128 * LDP];
  const int t    = threadIdx.x;
  const int m0   = blockIdx.y * 128;
  const int n0   = blockIdx.x * 128;
  const int lane = t & 63;
  const int wv   = t >> 6;
  const int wm   = (wv >> 1) * 64;
  const int wn   = (wv & 1) * 64;
  const int quad = lane >> 4;
  const int l16  = lane & 15;

  f32x4 acc[4][4] = {};
  for (int k0 = 0; k0 < K; k0 += 32) {
#pragma unroll
    for (int it = 0; it < 2; ++it) {
      int c   = t + it * 256;
      int row = c >> 2, seg = c & 3;
      int gm  = m0 + row;
      int4 v  = make_int4(0, 0, 0, 0);
      if (gm < M) v = *(const int4*)(Xb + (size_t)gm * K + k0 + seg * 8);
      *(int4*)(&As[row * LDP + seg * 8]) = v;
      int4 w = *(const int4*)(Wt + (size_t)(n0 + row) * K + k0 + seg * 8);
      *(int4*)(&Bs[row * LDP + seg * 8]) = w;
    }
    __syncthreads();
    bf16x8 a[4], b[4];
#pragma unroll
    for (int mi = 0; mi < 4; mi++)
      a[mi] = *(const bf16x8*)(&As[(wm + mi * 16 + l16) * LDP + quad * 8]);
#pragma unroll
    for (int nj = 0; nj < 4; nj++)
      b[nj] = *(const bf16x8*)(&Bs[(wn + nj * 16 + l16) * LDP + quad * 8]);
#pragma unroll
    for (int mi = 0; mi < 4; mi++)
#pragma unroll
      for (int nj = 0; nj < 4; nj++)
        acc[mi][nj] = __builtin_amdgcn_mfma_f32_16x16x32_bf16(a[mi], b[nj], acc[mi][nj], 0, 0, 0);
    __syncthreads();
  }
#pragma unroll
  for (int mi = 0; mi < 4; mi++) {
#pragma unroll
    for (int r = 0; r < 4; r++) {
      int gm = m0 + wm + mi * 16 + quad * 4 + r;
      if (gm >= M) continue;
#pragma unroll
      for (int nj = 0; nj < 4; nj++) {
        int gn = n0 + wn + nj * 16 + l16;
        st1<TOUT>(Y + (size_t)gm * D1 + gn, acc[mi][nj][r] + bias[gn]);
      }
    }
  }
}

// ---------- fused attention: online-softmax QK + aggregate + skip + ELU ----------
// wave per node. 16-lane group per head; lane holds 4 channels.
// Q row held in registers; K,V gathered bf16; single pass over edges.
template <typename TOUT>
__global__ __launch_bounds__(256) void node_attn(
    const int* __restrict__ rowstart, const int* __restrict__ esrc,
    const short* __restrict__ Qb, const short* __restrict__ Kb,
    const short* __restrict__ Vb, const float* __restrict__ skip,
    TOUT* __restrict__ out) {
  const int nid = blockIdx.x * 4 + (threadIdx.x >> 6);
  if (nid >= NN) return;
  const int t  = threadIdx.x & 63;
  const int c0 = t * 4;                 // my 4 channels (head = t>>4)
  const int r0 = rowstart[nid], r1 = rowstart[nid + 1];
  const float4 q = ld4b(Qb + (size_t)nid * D1 + c0);
  float m = -INFINITY, denom = 0.f;
  float4 acc = make_float4(0.f, 0.f, 0.f, 0.f);
  for (int r = r0; r < r1; r++) {
    const int s = esrc[r];
    const float4 kv = ld4b(Kb + (size_t)s * D1 + c0);
    const float4 vv = ld4b(Vb + (size_t)s * D1 + c0);
    float dot = q.x * kv.x + q.y * kv.y + q.z * kv.z + q.w * kv.w;
    dot += __shfl_xor(dot, 1, 16);
    dot += __shfl_xor(dot, 2, 16);
    dot += __shfl_xor(dot, 4, 16);
    dot += __shfl_xor(dot, 8, 16);
    dot *= 0.125f;                      // / sqrt(64)
    const float nm = fmaxf(m, dot);
    const float sc = __expf(m - nm);    // first iter: exp(-inf)=0
    const float ex = __expf(dot - nm);
    denom = denom * sc + ex;
    acc.x = acc.x * sc + ex * vv.x;
    acc.y = acc.y * sc + ex * vv.y;
    acc.z = acc.z * sc + ex * vv.z;
    acc.w = acc.w * sc + ex * vv.w;
    m = nm;
  }
  const float inv = 1.0f / (denom + 1e-16f);
  const float4 sk = *(const float4*)(skip + (size_t)nid * D1 + c0);
  float o0 = acc.x * inv + sk.x;
  float o1 = acc.y * inv + sk.y;
  float o2 = acc.z * inv + sk.z;
  float o3 = acc.w * inv + sk.w;
  o0 = o0 > 0.f ? o0 : expm1f(o0);
  o1 = o1 > 0.f ? o1 : expm1f(o1);
  o2 = o2 > 0.f ? o2 : expm1f(o2);
  o3 = o3 > 0.f ? o3 : expm1f(o3);
  TOUT* p = out + (size_t)nid * D1 + c0;
  st1<TOUT>(p + 0, o0); st1<TOUT>(p + 1, o1);
  st1<TOUT>(p + 2, o2); st1<TOUT>(p + 3, o3);
}

// ---------- graph boundaries via binary search (batch is sorted) ----------
__global__ void bounds_k(const int* __restrict__ batch, int* __restrict__ gb) {
  int g = threadIdx.x;            // 0..NG
  if (g > NG) return;
  int lo = 0, hi = NN;
  while (lo < hi) {
    int mid = (lo + hi) >> 1;
    if (batch[mid] < g) lo = mid + 1; else hi = mid;
  }
  gb[g] = lo;
}

// ---------- mean-pool partial sums (parallel, run-length atomics) ----------
__global__ __launch_bounds__(256) void pool_k(const float* __restrict__ h,
    const int* __restrict__ batch, float* __restrict__ sums) {
  const int c = threadIdx.x;
  const int n0 = blockIdx.x * 64;
  const int n1 = min(n0 + 64, NN);
  float run = 0.f;
  int curg = -1;
  for (int n = n0; n < n1; n++) {
    int g = batch[n];
    if (g != curg) {
      if (curg >= 0) atomicAdd(&sums[(size_t)curg * D1 + c], run);
      run = 0.f; curg = g;
    }
    run += h[(size_t)n * D1 + c];
  }
  if (curg >= 0) atomicAdd(&sums[(size_t)curg * D1 + c], run);
}

// ---------- classifier + log_softmax (counts from gb) ----------
__global__ __launch_bounds__(640) void head_k(const float* __restrict__ sums,
    const int* __restrict__ gb, const float* __restrict__ Wl,
    const float* __restrict__ bl, float* __restrict__ out) {
  __shared__ float logits[NG][NOUT];
  const int t = threadIdx.x;
  if (t < NG * NOUT) {
    int g = t / NOUT, o = t % NOUT;
    float inv = 1.0f / fmaxf((float)(gb[g + 1] - gb[g]), 1.0f);
    float acc = 0.f;
    for (int k = 0; k < D1; k++) acc += sums[(size_t)g * D1 + k] * Wl[k * NOUT + o];
    logits[g][o] = acc * inv + bl[o];
  }
  __syncthreads();
  if (t < NG) {
    float mx = -INFINITY;
#pragma unroll
    for (int o = 0; o < NOUT; o++) mx = fmaxf(mx, logits[t][o]);
    float s = 0.f;
#pragma unroll
    for (int o = 0; o < NOUT; o++) s += __expf(logits[t][o] - mx);
    float lse = mx + logf(s);
#pragma unroll
    for (int o = 0; o < NOUT; o++) out[t * NOUT + o] = logits[t][o] - lse;
  }
}

// ---------------------------------------------------------------------------
extern "C" void kernel_launch(void* const* d_in, const int* in_sizes, int n_in,
                              void* d_out, int out_size, void* d_ws, size_t ws_size,
                              hipStream_t stream) {
  const float* x   = (const float*)d_in[0];
  const int* ei    = (const int*)d_in[1];
  const int* batch = (const int*)d_in[2];
  const float* Wq1 = (const float*)d_in[3];  const float* bq1 = (const float*)d_in[4];
  const float* Wk1 = (const float*)d_in[5];  const float* bk1 = (const float*)d_in[6];
  const float* Wv1 = (const float*)d_in[7];  const float* bv1 = (const float*)d_in[8];
  const float* Ws1 = (const float*)d_in[9];  const float* bs1 = (const float*)d_in[10];
  const float* Wq2 = (const float*)d_in[11]; const float* bq2 = (const float*)d_in[12];
  const float* Wk2 = (const float*)d_in[13]; const float* bk2 = (const float*)d_in[14];
  const float* Wv2 = (const float*)d_in[15]; const float* bv2 = (const float*)d_in[16];
  const float* Ws2 = (const float*)d_in[17]; const float* bs2 = (const float*)d_in[18];
  const float* Wl  = (const float*)d_in[19]; const float* bl  = (const float*)d_in[20];

  const int* srcIdx = ei;          // edge_index[0] (source j)
  const int* dstIdx = ei + NE;     // edge_index[1] (target i)

  // -------- workspace layout --------
  float* ws = (float*)d_ws;
  const size_t SZ_NODE = (size_t)NN * D1;       // 12.8M elems
  float* SKf  = ws;                              // skip (both layers), final H2
  float* sums = ws + SZ_NODE;                    // NG*D1
  // bf16 region
  short* Xb  = (short*)(sums + (size_t)NG * D1); // NN*INC
  short* H1b = Xb + (size_t)NN * INC;            // NN*D1
  short* Qb  = H1b + SZ_NODE;                    // NN*D1
  short* Kb  = Qb + SZ_NODE;                     // NN*D1
  short* Vb  = Kb + SZ_NODE;                     // NN*D1
  short* Wt1q = Vb + SZ_NODE;
  short* Wt1k = Wt1q + (size_t)D1 * INC;
  short* Wt1v = Wt1k + (size_t)D1 * INC;
  short* Wt1s = Wt1v + (size_t)D1 * INC;
  short* Wt2q = Wt1s + (size_t)D1 * INC;
  short* Wt2k = Wt2q + (size_t)D1 * D1;
  short* Wt2v = Wt2k + (size_t)D1 * D1;
  short* Wt2s = Wt2v + (size_t)D1 * D1;
  // int region (CSR + graph bounds)
  int* ip      = (int*)(Wt2s + (size_t)D1 * D1);
  int* deg     = ip;                 // NN
  int* partial = deg + NN;           // 256
  int* rowstart= partial + 256;      // NN+1
  int* cursor  = rowstart + NN + 1;  // NN
  int* esrc    = cursor + NN;        // NE
  int* gb      = esrc + NE;          // NG+1

  const dim3 gemmGrid(2, (NN + 127) / 128);
  const int edgeBlocks = (NE + 255) / 256;
  const int nodeBlocks = (NN + 255) / 256;
  const int wt1Blocks  = (D1 * INC + 255) / 256;
  const int wt2Blocks  = (D1 * D1 + 255) / 256;
  const int aggBlocks  = (NN + 3) / 4;

  // ======== Converts (once) ========
  cvt_bf16_k<<<(NN * INC / 4 + 255) / 256, 256, 0, stream>>>(x, Xb, NN * INC);
  wt_cvt_k<<<wt1Blocks, 256, 0, stream>>>(Wq1, Wt1q, 7, D1);
  wt_cvt_k<<<wt1Blocks, 256, 0, stream>>>(Wk1, Wt1k, 7, D1);
  wt_cvt_k<<<wt1Blocks, 256, 0, stream>>>(Wv1, Wt1v, 7, D1);
  wt_cvt_k<<<wt1Blocks, 256, 0, stream>>>(Ws1, Wt1s, 7, D1);
  wt_cvt_k<<<wt2Blocks, 256, 0, stream>>>(Wq2, Wt2q, 8, D1);
  wt_cvt_k<<<wt2Blocks, 256, 0, stream>>>(Wk2, Wt2k, 8, D1);
  wt_cvt_k<<<wt2Blocks, 256, 0, stream>>>(Wv2, Wt2v, 8, D1);
  wt_cvt_k<<<wt2Blocks, 256, 0, stream>>>(Ws2, Wt2s, 8, D1);

  // ======== CSR build + graph bounds (once) ========
  fill_i<<<nodeBlocks, 256, 0, stream>>>(deg, 0, NN);
  deg_count<<<edgeBlocks, 256, 0, stream>>>(dstIdx, deg);
  scan1<<<NB_SCAN, 256, 0, stream>>>(deg, partial);
  scan2<<<1, 256, 0, stream>>>(partial, NB_SCAN);
  scan3<<<NB_SCAN, 256, 0, stream>>>(deg, partial, rowstart, cursor);
  scatter_k<<<edgeBlocks, 256, 0, stream>>>(srcIdx, dstIdx, cursor, esrc);
  bounds_k<<<1, 128, 0, stream>>>(batch, gb);

  // ======== Layer 1 ========  (Xb -> H1b)
  gemm_mfma<short><<<gemmGrid, 256, 0, stream>>>(Xb, Wt1q, bq1, Qb, NN, INC);
  gemm_mfma<short><<<gemmGrid, 256, 0, stream>>>(Xb, Wt1k, bk1, Kb, NN, INC);
  gemm_mfma<short><<<gemmGrid, 256, 0, stream>>>(Xb, Wt1v, bv1, Vb, NN, INC);
  gemm_mfma<float><<<gemmGrid, 256, 0, stream>>>(Xb, Wt1s, bs1, SKf, NN, INC);
  node_attn<short><<<aggBlocks, 256, 0, stream>>>(rowstart, esrc, Qb, Kb, Vb, SKf, H1b);

  // ======== Layer 2 ========  (H1b -> H2 in SKf, in place)
  gemm_mfma<short><<<gemmGrid, 256, 0, stream>>>(H1b, Wt2q, bq2, Qb, NN, D1);
  gemm_mfma<short><<<gemmGrid, 256, 0, stream>>>(H1b, Wt2k, bk2, Kb, NN, D1);
  gemm_mfma<short><<<gemmGrid, 256, 0, stream>>>(H1b, Wt2v, bv2, Vb, NN, D1);
  gemm_mfma<float><<<gemmGrid, 256, 0, stream>>>(H1b, Wt2s, bs2, SKf, NN, D1);
  node_attn<float><<<aggBlocks, 256, 0, stream>>>(rowstart, esrc, Qb, Kb, Vb, SKf, SKf);

  // ======== Pool + head ========
  fill_f<<<(NG * D1 + 255) / 256, 256, 0, stream>>>(sums, 0.f, NG * D1);
  pool_k<<<(NN + 63) / 64, 256, 0, stream>>>(SKf, batch, sums);
  head_k<<<1, 640, 0, stream>>>(sums, gb, Wl, bl, (float*)d_out);
}

// Round 8
// 485.313 us; speedup vs baseline: 4.1708x; 1.1710x over previous
//
#include <hip/hip_runtime.h>
#include <math.h>

constexpr int NN   = 50000;   // nodes
constexpr int NE   = 400000;  // edges
constexpr int INC  = 128;     // in channels
constexpr int NH   = 4;       // heads
constexpr int D1   = 256;     // NH*HIDC
constexpr int D4   = 1024;    // 4*D1 fused QKVS row
constexpr int NOUT = 10;      // classes
constexpr int NG   = 64;      // graphs
constexpr int NB_SCAN = (NN + 255) / 256;   // 196 scan blocks

typedef __attribute__((ext_vector_type(8))) short bf16x8;   // MFMA A/B frag
typedef __attribute__((ext_vector_type(4))) float f32x4;    // MFMA C/D frag

// ---------- bf16 helpers ----------
__device__ __forceinline__ short f2b(float f) {
  union { float f; unsigned int i; } v; v.f = f;
  unsigned int x = v.i;
  return (short)((x + 0x7FFFu + ((x >> 16) & 1u)) >> 16);
}
__device__ __forceinline__ float b2f(short u) {
  union { unsigned int i; float f; } v; v.i = ((unsigned int)(unsigned short)u) << 16;
  return v.f;
}
__device__ __forceinline__ float4 ld4b(const short* p) {
  short4 u = *(const short4*)p;
  return make_float4(b2f(u.x), b2f(u.y), b2f(u.z), b2f(u.w));
}

// ---------- fills ----------
__global__ void fill_i(int* __restrict__ p, int v, int n) {
  int i = blockIdx.x * 256 + threadIdx.x;
  if (i < n) p[i] = v;
}
__global__ void fill_f(float* __restrict__ p, float v, int n) {
  int i = blockIdx.x * 256 + threadIdx.x;
  if (i < n) p[i] = v;
}

// ---------- fp32 -> bf16 convert ----------
__global__ void cvt_bf16_k(const float* __restrict__ in, short* __restrict__ out, int n) {
  int i = (blockIdx.x * 256 + threadIdx.x) * 4;
  if (i >= n) return;
  float4 v = *(const float4*)(in + i);
  short4 o; o.x = f2b(v.x); o.y = f2b(v.y); o.z = f2b(v.z); o.w = f2b(v.w);
  *(short4*)(out + i) = o;
}

// ---------- W[K][256] fp32 -> Wt[256][K] bf16 (into concat segment) ----------
__global__ void wt_cvt_k(const float* __restrict__ W, short* __restrict__ Wt,
                         int kbits) {
  int i = blockIdx.x * 256 + threadIdx.x;
  int K = 1 << kbits;
  if (i >= D1 * K) return;
  int n = i >> kbits, k = i & (K - 1);
  Wt[i] = f2b(W[(size_t)k * D1 + n]);
}

// ---------- bias concat: [bq | bk | bv | bs] -> bc[1024] fp32 ----------
__global__ void bcat_k(const float* __restrict__ b0, const float* __restrict__ b1,
                       const float* __restrict__ b2, const float* __restrict__ b3,
                       float* __restrict__ out) {
  int i = blockIdx.x * 256 + threadIdx.x;
  if (i >= D4) return;
  const float* src = (i < 256) ? b0 : (i < 512) ? b1 : (i < 768) ? b2 : b3;
  out[i] = src[i & 255];
}

// ---------- CSR build ----------
__global__ void deg_count(const int* __restrict__ dst, int* __restrict__ deg) {
  int e = blockIdx.x * 256 + threadIdx.x;
  if (e < NE) atomicAdd(&deg[dst[e]], 1);
}
__global__ __launch_bounds__(256) void scan1(const int* __restrict__ deg,
                                             int* __restrict__ partial) {
  __shared__ int sh[256];
  int t = threadIdx.x, i = blockIdx.x * 256 + t;
  sh[t] = (i < NN) ? deg[i] : 0;
  __syncthreads();
  for (int off = 128; off > 0; off >>= 1) {
    if (t < off) sh[t] += sh[t + off];
    __syncthreads();
  }
  if (t == 0) partial[blockIdx.x] = sh[0];
}
__global__ __launch_bounds__(256) void scan2(int* __restrict__ partial, int nb) {
  __shared__ int sh[256];
  int t = threadIdx.x;
  int v = (t < nb) ? partial[t] : 0;
  sh[t] = v;
  __syncthreads();
  for (int off = 1; off < 256; off <<= 1) {
    int o = (t >= off) ? sh[t - off] : 0;
    __syncthreads();
    sh[t] += o;
    __syncthreads();
  }
  if (t < nb) partial[t] = sh[t] - v;   // exclusive
}
__global__ __launch_bounds__(256) void scan3(const int* __restrict__ deg,
    const int* __restrict__ partial, int* __restrict__ rowstart,
    int* __restrict__ cursor) {
  __shared__ int sh[256];
  int t = threadIdx.x, i = blockIdx.x * 256 + t;
  int v = (i < NN) ? deg[i] : 0;
  sh[t] = v;
  __syncthreads();
  for (int off = 1; off < 256; off <<= 1) {
    int o = (t >= off) ? sh[t - off] : 0;
    __syncthreads();
    sh[t] += o;
    __syncthreads();
  }
  int excl = sh[t] - v + partial[blockIdx.x];
  if (i <= NN) rowstart[i] = excl;
  if (i < NN)  cursor[i]   = excl;
}
__global__ void scatter_k(const int* __restrict__ src, const int* __restrict__ dst,
    int* __restrict__ cursor, int* __restrict__ esrc) {
  int e = blockIdx.x * 256 + threadIdx.x;
  if (e >= NE) return;
  int d = dst[e];
  int pos = atomicAdd(&cursor[d], 1);
  esrc[pos] = src[e];
}

// ---------- MFMA GEMM: Y[M,Ncols] = Xb[M,K](bf16) @ Wt[Ncols,K]^T + bias ------
constexpr int LDP = 56;
template <typename TOUT>
__device__ __forceinline__ void st1(TOUT* p, float v);
template <> __device__ __forceinline__ void st1<float>(float* p, float v) { *p = v; }
template <> __device__ __forceinline__ void st1<short>(short* p, float v) { *p = f2b(v); }

template <typename TOUT>
__global__ __launch_bounds__(256) void gemm_mfma(
    const short* __restrict__ Xb, const short* __restrict__ Wt,
    const float* __restrict__ bias, TOUT* __restrict__ Y, int M, int K, int Ncols) {
  __shared__ short As[128 * LDP];
  __shared__ short Bs[128 * LDP];
  const int t    = threadIdx.x;
  const int m0   = blockIdx.y * 128;
  const int n0   = blockIdx.x * 128;
  const int lane = t & 63;
  const int wv   = t >> 6;
  const int wm   = (wv >> 1) * 64;
  const int wn   = (wv & 1) * 64;
  const int quad = lane >> 4;
  const int l16  = lane & 15;

  f32x4 acc[4][4] = {};
  for (int k0 = 0; k0 < K; k0 += 32) {
#pragma unroll
    for (int it = 0; it < 2; ++it) {
      int c   = t + it * 256;
      int row = c >> 2, seg = c & 3;
      int gm  = m0 + row;
      int4 v  = make_int4(0, 0, 0, 0);
      if (gm < M) v = *(const int4*)(Xb + (size_t)gm * K + k0 + seg * 8);
      *(int4*)(&As[row * LDP + seg * 8]) = v;
      int4 w = *(const int4*)(Wt + (size_t)(n0 + row) * K + k0 + seg * 8);
      *(int4*)(&Bs[row * LDP + seg * 8]) = w;
    }
    __syncthreads();
    bf16x8 a[4], b[4];
#pragma unroll
    for (int mi = 0; mi < 4; mi++)
      a[mi] = *(const bf16x8*)(&As[(wm + mi * 16 + l16) * LDP + quad * 8]);
#pragma unroll
    for (int nj = 0; nj < 4; nj++)
      b[nj] = *(const bf16x8*)(&Bs[(wn + nj * 16 + l16) * LDP + quad * 8]);
#pragma unroll
    for (int mi = 0; mi < 4; mi++)
#pragma unroll
      for (int nj = 0; nj < 4; nj++)
        acc[mi][nj] = __builtin_amdgcn_mfma_f32_16x16x32_bf16(a[mi], b[nj], acc[mi][nj], 0, 0, 0);
    __syncthreads();
  }
#pragma unroll
  for (int mi = 0; mi < 4; mi++) {
#pragma unroll
    for (int r = 0; r < 4; r++) {
      int gm = m0 + wm + mi * 16 + quad * 4 + r;
      if (gm >= M) continue;
#pragma unroll
      for (int nj = 0; nj < 4; nj++) {
        int gn = n0 + wn + nj * 16 + l16;
        st1<TOUT>(Y + (size_t)gm * Ncols + gn, acc[mi][nj][r] + bias[gn]);
      }
    }
  }
}

// ---------- fused attention on QKVS rows: online softmax, 2-edge unroll --------
// Yb row layout per node: [Q(0:256) | K(256:512) | V(512:768) | S(768:1024)].
// wave per node; 16-lane group per head; lane holds 4 channels.
template <typename TOUT>
__global__ __launch_bounds__(256) void node_attn(
    const int* __restrict__ rowstart, const int* __restrict__ esrc,
    const short* __restrict__ Yb, TOUT* __restrict__ out) {
  const int nid = blockIdx.x * 4 + (threadIdx.x >> 6);
  if (nid >= NN) return;
  const int t  = threadIdx.x & 63;
  const int c0 = t * 4;                 // my 4 channels (head = t>>4)
  const int r0 = rowstart[nid], r1 = rowstart[nid + 1];
  const float4 q = ld4b(Yb + (size_t)nid * D4 + c0);
  float m = -INFINITY, denom = 0.f;
  float4 acc = make_float4(0.f, 0.f, 0.f, 0.f);
  int r = r0;
  for (; r + 1 < r1; r += 2) {
    const int s1 = esrc[r], s2 = esrc[r + 1];
    const short* p1 = Yb + (size_t)s1 * D4 + 256 + c0;
    const short* p2 = Yb + (size_t)s2 * D4 + 256 + c0;
    const float4 k1 = ld4b(p1);
    const float4 k2 = ld4b(p2);
    const float4 v1 = ld4b(p1 + 256);
    const float4 v2 = ld4b(p2 + 256);
    float d1 = q.x * k1.x + q.y * k1.y + q.z * k1.z + q.w * k1.w;
    float d2 = q.x * k2.x + q.y * k2.y + q.z * k2.z + q.w * k2.w;
    d1 += __shfl_xor(d1, 1, 16);  d2 += __shfl_xor(d2, 1, 16);
    d1 += __shfl_xor(d1, 2, 16);  d2 += __shfl_xor(d2, 2, 16);
    d1 += __shfl_xor(d1, 4, 16);  d2 += __shfl_xor(d2, 4, 16);
    d1 += __shfl_xor(d1, 8, 16);  d2 += __shfl_xor(d2, 8, 16);
    d1 *= 0.125f;  d2 *= 0.125f;
    const float nm = fmaxf(m, fmaxf(d1, d2));
    const float sc = __expf(m - nm);
    const float e1 = __expf(d1 - nm);
    const float e2 = __expf(d2 - nm);
    denom = denom * sc + e1 + e2;
    acc.x = acc.x * sc + e1 * v1.x + e2 * v2.x;
    acc.y = acc.y * sc + e1 * v1.y + e2 * v2.y;
    acc.z = acc.z * sc + e1 * v1.z + e2 * v2.z;
    acc.w = acc.w * sc + e1 * v1.w + e2 * v2.w;
    m = nm;
  }
  if (r < r1) {                         // odd-degree tail
    const int s = esrc[r];
    const short* p = Yb + (size_t)s * D4 + 256 + c0;
    const float4 kv = ld4b(p);
    const float4 vv = ld4b(p + 256);
    float dot = q.x * kv.x + q.y * kv.y + q.z * kv.z + q.w * kv.w;
    dot += __shfl_xor(dot, 1, 16);
    dot += __shfl_xor(dot, 2, 16);
    dot += __shfl_xor(dot, 4, 16);
    dot += __shfl_xor(dot, 8, 16);
    dot *= 0.125f;
    const float nm = fmaxf(m, dot);
    const float sc = __expf(m - nm);
    const float ex = __expf(dot - nm);
    denom = denom * sc + ex;
    acc.x = acc.x * sc + ex * vv.x;
    acc.y = acc.y * sc + ex * vv.y;
    acc.z = acc.z * sc + ex * vv.z;
    acc.w = acc.w * sc + ex * vv.w;
  }
  const float inv = 1.0f / (denom + 1e-16f);
  const float4 sk = ld4b(Yb + (size_t)nid * D4 + 768 + c0);
  float o0 = acc.x * inv + sk.x;
  float o1 = acc.y * inv + sk.y;
  float o2 = acc.z * inv + sk.z;
  float o3 = acc.w * inv + sk.w;
  o0 = o0 > 0.f ? o0 : expm1f(o0);
  o1 = o1 > 0.f ? o1 : expm1f(o1);
  o2 = o2 > 0.f ? o2 : expm1f(o2);
  o3 = o3 > 0.f ? o3 : expm1f(o3);
  TOUT* p = out + (size_t)nid * D1 + c0;
  st1<TOUT>(p + 0, o0); st1<TOUT>(p + 1, o1);
  st1<TOUT>(p + 2, o2); st1<TOUT>(p + 3, o3);
}

// ---------- graph boundaries via binary search (batch is sorted) ----------
__global__ void bounds_k(const int* __restrict__ batch, int* __restrict__ gb) {
  int g = threadIdx.x;            // 0..NG
  if (g > NG) return;
  int lo = 0, hi = NN;
  while (lo < hi) {
    int mid = (lo + hi) >> 1;
    if (batch[mid] < g) lo = mid + 1; else hi = mid;
  }
  gb[g] = lo;
}

// ---------- mean-pool partial sums (parallel, run-length atomics) ----------
__global__ __launch_bounds__(256) void pool_k(const float* __restrict__ h,
    const int* __restrict__ batch, float* __restrict__ sums) {
  const int c = threadIdx.x;
  const int n0 = blockIdx.x * 64;
  const int n1 = min(n0 + 64, NN);
  float run = 0.f;
  int curg = -1;
  for (int n = n0; n < n1; n++) {
    int g = batch[n];
    if (g != curg) {
      if (curg >= 0) atomicAdd(&sums[(size_t)curg * D1 + c], run);
      run = 0.f; curg = g;
    }
    run += h[(size_t)n * D1 + c];
  }
  if (curg >= 0) atomicAdd(&sums[(size_t)curg * D1 + c], run);
}

// ---------- classifier + log_softmax (counts from gb) ----------
__global__ __launch_bounds__(640) void head_k(const float* __restrict__ sums,
    const int* __restrict__ gb, const float* __restrict__ Wl,
    const float* __restrict__ bl, float* __restrict__ out) {
  __shared__ float logits[NG][NOUT];
  const int t = threadIdx.x;
  if (t < NG * NOUT) {
    int g = t / NOUT, o = t % NOUT;
    float inv = 1.0f / fmaxf((float)(gb[g + 1] - gb[g]), 1.0f);
    float acc = 0.f;
    for (int k = 0; k < D1; k++) acc += sums[(size_t)g * D1 + k] * Wl[k * NOUT + o];
    logits[g][o] = acc * inv + bl[o];
  }
  __syncthreads();
  if (t < NG) {
    float mx = -INFINITY;
#pragma unroll
    for (int o = 0; o < NOUT; o++) mx = fmaxf(mx, logits[t][o]);
    float s = 0.f;
#pragma unroll
    for (int o = 0; o < NOUT; o++) s += __expf(logits[t][o] - mx);
    float lse = mx + logf(s);
#pragma unroll
    for (int o = 0; o < NOUT; o++) out[t * NOUT + o] = logits[t][o] - lse;
  }
}

// ---------------------------------------------------------------------------
extern "C" void kernel_launch(void* const* d_in, const int* in_sizes, int n_in,
                              void* d_out, int out_size, void* d_ws, size_t ws_size,
                              hipStream_t stream) {
  const float* x   = (const float*)d_in[0];
  const int* ei    = (const int*)d_in[1];
  const int* batch = (const int*)d_in[2];
  const float* Wq1 = (const float*)d_in[3];  const float* bq1 = (const float*)d_in[4];
  const float* Wk1 = (const float*)d_in[5];  const float* bk1 = (const float*)d_in[6];
  const float* Wv1 = (const float*)d_in[7];  const float* bv1 = (const float*)d_in[8];
  const float* Ws1 = (const float*)d_in[9];  const float* bs1 = (const float*)d_in[10];
  const float* Wq2 = (const float*)d_in[11]; const float* bq2 = (const float*)d_in[12];
  const float* Wk2 = (const float*)d_in[13]; const float* bk2 = (const float*)d_in[14];
  const float* Wv2 = (const float*)d_in[15]; const float* bv2 = (const float*)d_in[16];
  const float* Ws2 = (const float*)d_in[17]; const float* bs2 = (const float*)d_in[18];
  const float* Wl  = (const float*)d_in[19]; const float* bl  = (const float*)d_in[20];

  const int* srcIdx = ei;          // edge_index[0] (source j)
  const int* dstIdx = ei + NE;     // edge_index[1] (target i)

  // -------- workspace layout --------
  float* ws = (float*)d_ws;
  const size_t SZ_NODE = (size_t)NN * D1;       // 12.8M elems
  float* H2f  = ws;                              // NN*D1 fp32 (final layer-2 out)
  float* sums = ws + SZ_NODE;                    // NG*D1
  float* bc1  = sums + (size_t)NG * D1;          // 1024
  float* bc2  = bc1 + D4;                        // 1024
  // bf16 region
  short* Xb   = (short*)(bc2 + D4);              // NN*INC
  short* H1b  = Xb + (size_t)NN * INC;           // NN*D1
  short* Yb   = H1b + SZ_NODE;                   // NN*1024 (fused QKVS, both layers)
  short* Wtc1 = Yb + (size_t)NN * D4;            // 1024*128
  short* Wtc2 = Wtc1 + (size_t)D4 * INC;         // 1024*256
  // int region (CSR + graph bounds)
  int* ip      = (int*)(Wtc2 + (size_t)D4 * D1);
  int* deg     = ip;                 // NN
  int* partial = deg + NN;           // 256
  int* rowstart= partial + 256;      // NN+1
  int* cursor  = rowstart + NN + 1;  // NN
  int* esrc    = cursor + NN;        // NE
  int* gb      = esrc + NE;          // NG+1

  const dim3 gemmGrid(D4 / 128, (NN + 127) / 128);   // 8 x 391
  const int edgeBlocks = (NE + 255) / 256;
  const int nodeBlocks = (NN + 255) / 256;
  const int wt1Blocks  = (D1 * INC + 255) / 256;
  const int wt2Blocks  = (D1 * D1 + 255) / 256;
  const int aggBlocks  = (NN + 3) / 4;

  // ======== Converts (once) ========
  cvt_bf16_k<<<(NN * INC / 4 + 255) / 256, 256, 0, stream>>>(x, Xb, NN * INC);
  wt_cvt_k<<<wt1Blocks, 256, 0, stream>>>(Wq1, Wtc1 + (size_t)0 * D1 * INC, 7);
  wt_cvt_k<<<wt1Blocks, 256, 0, stream>>>(Wk1, Wtc1 + (size_t)1 * D1 * INC, 7);
  wt_cvt_k<<<wt1Blocks, 256, 0, stream>>>(Wv1, Wtc1 + (size_t)2 * D1 * INC, 7);
  wt_cvt_k<<<wt1Blocks, 256, 0, stream>>>(Ws1, Wtc1 + (size_t)3 * D1 * INC, 7);
  wt_cvt_k<<<wt2Blocks, 256, 0, stream>>>(Wq2, Wtc2 + (size_t)0 * D1 * D1, 8);
  wt_cvt_k<<<wt2Blocks, 256, 0, stream>>>(Wk2, Wtc2 + (size_t)1 * D1 * D1, 8);
  wt_cvt_k<<<wt2Blocks, 256, 0, stream>>>(Wv2, Wtc2 + (size_t)2 * D1 * D1, 8);
  wt_cvt_k<<<wt2Blocks, 256, 0, stream>>>(Ws2, Wtc2 + (size_t)3 * D1 * D1, 8);
  bcat_k<<<4, 256, 0, stream>>>(bq1, bk1, bv1, bs1, bc1);
  bcat_k<<<4, 256, 0, stream>>>(bq2, bk2, bv2, bs2, bc2);

  // ======== CSR build + graph bounds (once) ========
  fill_i<<<nodeBlocks, 256, 0, stream>>>(deg, 0, NN);
  deg_count<<<edgeBlocks, 256, 0, stream>>>(dstIdx, deg);
  scan1<<<NB_SCAN, 256, 0, stream>>>(deg, partial);
  scan2<<<1, 256, 0, stream>>>(partial, NB_SCAN);
  scan3<<<NB_SCAN, 256, 0, stream>>>(deg, partial, rowstart, cursor);
  scatter_k<<<edgeBlocks, 256, 0, stream>>>(srcIdx, dstIdx, cursor, esrc);
  bounds_k<<<1, 128, 0, stream>>>(batch, gb);

  // ======== Layer 1 ========  (Xb -> fused QKVS -> H1b)
  gemm_mfma<short><<<gemmGrid, 256, 0, stream>>>(Xb, Wtc1, bc1, Yb, NN, INC, D4);
  node_attn<short><<<aggBlocks, 256, 0, stream>>>(rowstart, esrc, Yb, H1b);

  // ======== Layer 2 ========  (H1b -> fused QKVS -> H2f)
  gemm_mfma<short><<<gemmGrid, 256, 0, stream>>>(H1b, Wtc2, bc2, Yb, NN, D1, D4);
  node_attn<float><<<aggBlocks, 256, 0, stream>>>(rowstart, esrc, Yb, H2f);

  // ======== Pool + head ========
  fill_f<<<(NG * D1 + 255) / 256, 256, 0, stream>>>(sums, 0.f, NG * D1);
  pool_k<<<(NN + 63) / 64, 256, 0, stream>>>(H2f, batch, sums);
  head_k<<<1, 640, 0, stream>>>(sums, gb, Wl, bl, (float*)d_out);
}

// Round 9
// 465.345 us; speedup vs baseline: 4.3497x; 1.0429x over previous
//
#include <hip/hip_runtime.h>
#include <math.h>

constexpr int NN   = 50000;   // nodes
constexpr int NE   = 400000;  // edges
constexpr int INC  = 128;     // in channels
constexpr int NH   = 4;       // heads
constexpr int D1   = 256;     // NH*HIDC
constexpr int D4   = 1024;    // 4*D1 fused QKVS row
constexpr int NOUT = 10;      // classes
constexpr int NG   = 64;      // graphs
constexpr int NB_SCAN = (NN + 255) / 256;   // 196 scan blocks

typedef __attribute__((ext_vector_type(8))) short bf16x8;   // MFMA A/B frag
typedef __attribute__((ext_vector_type(4))) float f32x4;    // MFMA C/D frag

// ---------- bf16 helpers ----------
__device__ __forceinline__ short f2b(float f) {
  union { float f; unsigned int i; } v; v.f = f;
  unsigned int x = v.i;
  return (short)((x + 0x7FFFu + ((x >> 16) & 1u)) >> 16);
}
__device__ __forceinline__ float b2f(short u) {
  union { unsigned int i; float f; } v; v.i = ((unsigned int)(unsigned short)u) << 16;
  return v.f;
}
__device__ __forceinline__ float4 ld4b(const short* p) {
  short4 u = *(const short4*)p;
  return make_float4(b2f(u.x), b2f(u.y), b2f(u.z), b2f(u.w));
}

// ---------- async global->LDS 16B (wave-uniform LDS base + lane*16) ----------
__device__ __forceinline__ void gld_lds16(const short* g, short* l) {
  __builtin_amdgcn_global_load_lds(
      (const __attribute__((address_space(1))) unsigned int*)g,
      (__attribute__((address_space(3))) unsigned int*)l, 16, 0, 0);
}

// ---------- fills ----------
__global__ void fill_i(int* __restrict__ p, int v, int n) {
  int i = blockIdx.x * 256 + threadIdx.x;
  if (i < n) p[i] = v;
}
__global__ void fill_f(float* __restrict__ p, float v, int n) {
  int i = blockIdx.x * 256 + threadIdx.x;
  if (i < n) p[i] = v;
}

// ---------- fp32 -> bf16 convert ----------
__global__ void cvt_bf16_k(const float* __restrict__ in, short* __restrict__ out, int n) {
  int i = (blockIdx.x * 256 + threadIdx.x) * 4;
  if (i >= n) return;
  float4 v = *(const float4*)(in + i);
  short4 o; o.x = f2b(v.x); o.y = f2b(v.y); o.z = f2b(v.z); o.w = f2b(v.w);
  *(short4*)(out + i) = o;
}

// ---------- W[K][256] fp32 -> Wt[256][K] bf16 (into concat segment) ----------
__global__ void wt_cvt_k(const float* __restrict__ W, short* __restrict__ Wt,
                         int kbits) {
  int i = blockIdx.x * 256 + threadIdx.x;
  int K = 1 << kbits;
  if (i >= D1 * K) return;
  int n = i >> kbits, k = i & (K - 1);
  Wt[i] = f2b(W[(size_t)k * D1 + n]);
}

// ---------- bias concat: [bq | bk | bv | bs] -> bc[1024] fp32 ----------
__global__ void bcat_k(const float* __restrict__ b0, const float* __restrict__ b1,
                       const float* __restrict__ b2, const float* __restrict__ b3,
                       float* __restrict__ out) {
  int i = blockIdx.x * 256 + threadIdx.x;
  if (i >= D4) return;
  const float* src = (i < 256) ? b0 : (i < 512) ? b1 : (i < 768) ? b2 : b3;
  out[i] = src[i & 255];
}

// ---------- CSR build ----------
__global__ void deg_count(const int* __restrict__ dst, int* __restrict__ deg) {
  int e = blockIdx.x * 256 + threadIdx.x;
  if (e < NE) atomicAdd(&deg[dst[e]], 1);
}
__global__ __launch_bounds__(256) void scan1(const int* __restrict__ deg,
                                             int* __restrict__ partial) {
  __shared__ int sh[256];
  int t = threadIdx.x, i = blockIdx.x * 256 + t;
  sh[t] = (i < NN) ? deg[i] : 0;
  __syncthreads();
  for (int off = 128; off > 0; off >>= 1) {
    if (t < off) sh[t] += sh[t + off];
    __syncthreads();
  }
  if (t == 0) partial[blockIdx.x] = sh[0];
}
__global__ __launch_bounds__(256) void scan2(int* __restrict__ partial, int nb) {
  __shared__ int sh[256];
  int t = threadIdx.x;
  int v = (t < nb) ? partial[t] : 0;
  sh[t] = v;
  __syncthreads();
  for (int off = 1; off < 256; off <<= 1) {
    int o = (t >= off) ? sh[t - off] : 0;
    __syncthreads();
    sh[t] += o;
    __syncthreads();
  }
  if (t < nb) partial[t] = sh[t] - v;   // exclusive
}
__global__ __launch_bounds__(256) void scan3(const int* __restrict__ deg,
    const int* __restrict__ partial, int* __restrict__ rowstart,
    int* __restrict__ cursor) {
  __shared__ int sh[256];
  int t = threadIdx.x, i = blockIdx.x * 256 + t;
  int v = (i < NN) ? deg[i] : 0;
  sh[t] = v;
  __syncthreads();
  for (int off = 1; off < 256; off <<= 1) {
    int o = (t >= off) ? sh[t - off] : 0;
    __syncthreads();
    sh[t] += o;
    __syncthreads();
  }
  int excl = sh[t] - v + partial[blockIdx.x];
  if (i <= NN) rowstart[i] = excl;
  if (i < NN)  cursor[i]   = excl;
}
__global__ void scatter_k(const int* __restrict__ src, const int* __restrict__ dst,
    int* __restrict__ cursor, int* __restrict__ esrc) {
  int e = blockIdx.x * 256 + threadIdx.x;
  if (e >= NE) return;
  int d = dst[e];
  int pos = atomicAdd(&cursor[d], 1);
  esrc[pos] = src[e];
}

// ---------- MFMA GEMM: Y[M,Ncols] = Xb[M,K](bf16) @ Wt[Ncols,K]^T + bias ------
// m97-style: unpadded LDS [128][32], global_load_lds width=16 staging,
// XCD-aware swizzle: the 8 n-tiles of one m-tile share dispatch-id mod 8.
template <typename TOUT>
__device__ __forceinline__ void st1(TOUT* p, float v);
template <> __device__ __forceinline__ void st1<float>(float* p, float v) { *p = v; }
template <> __device__ __forceinline__ void st1<short>(short* p, float v) { *p = f2b(v); }

template <typename TOUT>
__global__ __launch_bounds__(256) void gemm_mfma(
    const short* __restrict__ Xb, const short* __restrict__ Wt,
    const float* __restrict__ bias, TOUT* __restrict__ Y, int M, int K, int Ncols) {
  __shared__ short As[128 * 32];
  __shared__ short Bs[128 * 32];
  // swizzle: grid (64, ceil(mtiles/8)); id%8 == m_tile%8 -> same XCD per m-tile
  const int bx = blockIdx.x;                 // 0..63
  const int by = blockIdx.y;
  const int m_tile = (bx & 7) + (by << 3);
  const int n_tile = bx >> 3;                // 0..7
  const int m0 = m_tile * 128;
  if (m0 >= M) return;
  const int n0 = n_tile * 128;

  const int t    = threadIdx.x;
  const int lane = t & 63;
  const int wv   = t >> 6;
  const int wm   = (wv >> 1) * 64;
  const int wn   = (wv & 1) * 64;
  const int quad = lane >> 4;
  const int l16  = lane & 15;
  const int lrow = lane >> 2;     // 0..15 (staging row within 16-row chunk)
  const int lseg = lane & 3;      // 0..3  (staging 8-bf16 segment)

  f32x4 acc[4][4] = {};
  for (int k0 = 0; k0 < K; k0 += 32) {
    // stage A,B tiles (128x32 bf16 each) via async global->LDS, 16B/lane.
    // wave wv, chunk j covers rows rb..rb+15; LDS base wave-uniform.
#pragma unroll
    for (int j = 0; j < 2; ++j) {
      const int rb = wv * 32 + j * 16;
      int gm = m0 + rb + lrow;
      gm = gm < M ? gm : M - 1;                         // clamp (stores guarded)
      gld_lds16(Xb + (size_t)gm * K + k0 + lseg * 8, &As[rb * 32]);
      gld_lds16(Wt + (size_t)(n0 + rb + lrow) * K + k0 + lseg * 8, &Bs[rb * 32]);
    }
    __syncthreads();
    bf16x8 a[4], b[4];
#pragma unroll
    for (int mi = 0; mi < 4; mi++)
      a[mi] = *(const bf16x8*)(&As[(wm + mi * 16 + l16) * 32 + quad * 8]);
#pragma unroll
    for (int nj = 0; nj < 4; nj++)
      b[nj] = *(const bf16x8*)(&Bs[(wn + nj * 16 + l16) * 32 + quad * 8]);
#pragma unroll
    for (int mi = 0; mi < 4; mi++)
#pragma unroll
      for (int nj = 0; nj < 4; nj++)
        acc[mi][nj] = __builtin_amdgcn_mfma_f32_16x16x32_bf16(a[mi], b[nj], acc[mi][nj], 0, 0, 0);
    __syncthreads();
  }
#pragma unroll
  for (int mi = 0; mi < 4; mi++) {
#pragma unroll
    for (int r = 0; r < 4; r++) {
      int gm = m0 + wm + mi * 16 + quad * 4 + r;
      if (gm >= M) continue;
#pragma unroll
      for (int nj = 0; nj < 4; nj++) {
        int gn = n0 + wn + nj * 16 + l16;
        st1<TOUT>(Y + (size_t)gm * Ncols + gn, acc[mi][nj][r] + bias[gn]);
      }
    }
  }
}

// ---------- fused attention on QKVS rows: online softmax, 2-edge unroll --------
// Yb row layout per node: [Q(0:256) | K(256:512) | V(512:768) | S(768:1024)].
// wave per node; 16-lane group per head; lane holds 4 channels.
template <typename TOUT>
__global__ __launch_bounds__(256) void node_attn(
    const int* __restrict__ rowstart, const int* __restrict__ esrc,
    const short* __restrict__ Yb, TOUT* __restrict__ out) {
  const int nid = blockIdx.x * 4 + (threadIdx.x >> 6);
  if (nid >= NN) return;
  const int t  = threadIdx.x & 63;
  const int c0 = t * 4;                 // my 4 channels (head = t>>4)
  const int r0 = rowstart[nid], r1 = rowstart[nid + 1];
  const float4 q = ld4b(Yb + (size_t)nid * D4 + c0);
  float m = -INFINITY, denom = 0.f;
  float4 acc = make_float4(0.f, 0.f, 0.f, 0.f);
  int r = r0;
  for (; r + 1 < r1; r += 2) {
    const int s1 = esrc[r], s2 = esrc[r + 1];
    const short* p1 = Yb + (size_t)s1 * D4 + 256 + c0;
    const short* p2 = Yb + (size_t)s2 * D4 + 256 + c0;
    const float4 k1 = ld4b(p1);
    const float4 k2 = ld4b(p2);
    const float4 v1 = ld4b(p1 + 256);
    const float4 v2 = ld4b(p2 + 256);
    float d1 = q.x * k1.x + q.y * k1.y + q.z * k1.z + q.w * k1.w;
    float d2 = q.x * k2.x + q.y * k2.y + q.z * k2.z + q.w * k2.w;
    d1 += __shfl_xor(d1, 1, 16);  d2 += __shfl_xor(d2, 1, 16);
    d1 += __shfl_xor(d1, 2, 16);  d2 += __shfl_xor(d2, 2, 16);
    d1 += __shfl_xor(d1, 4, 16);  d2 += __shfl_xor(d2, 4, 16);
    d1 += __shfl_xor(d1, 8, 16);  d2 += __shfl_xor(d2, 8, 16);
    d1 *= 0.125f;  d2 *= 0.125f;
    const float nm = fmaxf(m, fmaxf(d1, d2));
    const float sc = __expf(m - nm);
    const float e1 = __expf(d1 - nm);
    const float e2 = __expf(d2 - nm);
    denom = denom * sc + e1 + e2;
    acc.x = acc.x * sc + e1 * v1.x + e2 * v2.x;
    acc.y = acc.y * sc + e1 * v1.y + e2 * v2.y;
    acc.z = acc.z * sc + e1 * v1.z + e2 * v2.z;
    acc.w = acc.w * sc + e1 * v1.w + e2 * v2.w;
    m = nm;
  }
  if (r < r1) {                         // odd-degree tail
    const int s = esrc[r];
    const short* p = Yb + (size_t)s * D4 + 256 + c0;
    const float4 kv = ld4b(p);
    const float4 vv = ld4b(p + 256);
    float dot = q.x * kv.x + q.y * kv.y + q.z * kv.z + q.w * kv.w;
    dot += __shfl_xor(dot, 1, 16);
    dot += __shfl_xor(dot, 2, 16);
    dot += __shfl_xor(dot, 4, 16);
    dot += __shfl_xor(dot, 8, 16);
    dot *= 0.125f;
    const float nm = fmaxf(m, dot);
    const float sc = __expf(m - nm);
    const float ex = __expf(dot - nm);
    denom = denom * sc + ex;
    acc.x = acc.x * sc + ex * vv.x;
    acc.y = acc.y * sc + ex * vv.y;
    acc.z = acc.z * sc + ex * vv.z;
    acc.w = acc.w * sc + ex * vv.w;
  }
  const float inv = 1.0f / (denom + 1e-16f);
  const float4 sk = ld4b(Yb + (size_t)nid * D4 + 768 + c0);
  float o0 = acc.x * inv + sk.x;
  float o1 = acc.y * inv + sk.y;
  float o2 = acc.z * inv + sk.z;
  float o3 = acc.w * inv + sk.w;
  o0 = o0 > 0.f ? o0 : expm1f(o0);
  o1 = o1 > 0.f ? o1 : expm1f(o1);
  o2 = o2 > 0.f ? o2 : expm1f(o2);
  o3 = o3 > 0.f ? o3 : expm1f(o3);
  TOUT* p = out + (size_t)nid * D1 + c0;
  st1<TOUT>(p + 0, o0); st1<TOUT>(p + 1, o1);
  st1<TOUT>(p + 2, o2); st1<TOUT>(p + 3, o3);
}

// ---------- graph boundaries via binary search (batch is sorted) ----------
__global__ void bounds_k(const int* __restrict__ batch, int* __restrict__ gb) {
  int g = threadIdx.x;            // 0..NG
  if (g > NG) return;
  int lo = 0, hi = NN;
  while (lo < hi) {
    int mid = (lo + hi) >> 1;
    if (batch[mid] < g) lo = mid + 1; else hi = mid;
  }
  gb[g] = lo;
}

// ---------- mean-pool partial sums (parallel, run-length atomics) ----------
__global__ __launch_bounds__(256) void pool_k(const float* __restrict__ h,
    const int* __restrict__ batch, float* __restrict__ sums) {
  const int c = threadIdx.x;
  const int n0 = blockIdx.x * 64;
  const int n1 = min(n0 + 64, NN);
  float run = 0.f;
  int curg = -1;
  for (int n = n0; n < n1; n++) {
    int g = batch[n];
    if (g != curg) {
      if (curg >= 0) atomicAdd(&sums[(size_t)curg * D1 + c], run);
      run = 0.f; curg = g;
    }
    run += h[(size_t)n * D1 + c];
  }
  if (curg >= 0) atomicAdd(&sums[(size_t)curg * D1 + c], run);
}

// ---------- classifier + log_softmax (counts from gb) ----------
__global__ __launch_bounds__(640) void head_k(const float* __restrict__ sums,
    const int* __restrict__ gb, const float* __restrict__ Wl,
    const float* __restrict__ bl, float* __restrict__ out) {
  __shared__ float logits[NG][NOUT];
  const int t = threadIdx.x;
  if (t < NG * NOUT) {
    int g = t / NOUT, o = t % NOUT;
    float inv = 1.0f / fmaxf((float)(gb[g + 1] - gb[g]), 1.0f);
    float acc = 0.f;
    for (int k = 0; k < D1; k++) acc += sums[(size_t)g * D1 + k] * Wl[k * NOUT + o];
    logits[g][o] = acc * inv + bl[o];
  }
  __syncthreads();
  if (t < NG) {
    float mx = -INFINITY;
#pragma unroll
    for (int o = 0; o < NOUT; o++) mx = fmaxf(mx, logits[t][o]);
    float s = 0.f;
#pragma unroll
    for (int o = 0; o < NOUT; o++) s += __expf(logits[t][o] - mx);
    float lse = mx + logf(s);
#pragma unroll
    for (int o = 0; o < NOUT; o++) out[t * NOUT + o] = logits[t][o] - lse;
  }
}

// ---------------------------------------------------------------------------
extern "C" void kernel_launch(void* const* d_in, const int* in_sizes, int n_in,
                              void* d_out, int out_size, void* d_ws, size_t ws_size,
                              hipStream_t stream) {
  const float* x   = (const float*)d_in[0];
  const int* ei    = (const int*)d_in[1];
  const int* batch = (const int*)d_in[2];
  const float* Wq1 = (const float*)d_in[3];  const float* bq1 = (const float*)d_in[4];
  const float* Wk1 = (const float*)d_in[5];  const float* bk1 = (const float*)d_in[6];
  const float* Wv1 = (const float*)d_in[7];  const float* bv1 = (const float*)d_in[8];
  const float* Ws1 = (const float*)d_in[9];  const float* bs1 = (const float*)d_in[10];
  const float* Wq2 = (const float*)d_in[11]; const float* bq2 = (const float*)d_in[12];
  const float* Wk2 = (const float*)d_in[13]; const float* bk2 = (const float*)d_in[14];
  const float* Wv2 = (const float*)d_in[15]; const float* bv2 = (const float*)d_in[16];
  const float* Ws2 = (const float*)d_in[17]; const float* bs2 = (const float*)d_in[18];
  const float* Wl  = (const float*)d_in[19]; const float* bl  = (const float*)d_in[20];

  const int* srcIdx = ei;          // edge_index[0] (source j)
  const int* dstIdx = ei + NE;     // edge_index[1] (target i)

  // -------- workspace layout --------
  float* ws = (float*)d_ws;
  const size_t SZ_NODE = (size_t)NN * D1;       // 12.8M elems
  float* H2f  = ws;                              // NN*D1 fp32 (final layer-2 out)
  float* sums = ws + SZ_NODE;                    // NG*D1
  float* bc1  = sums + (size_t)NG * D1;          // 1024
  float* bc2  = bc1 + D4;                        // 1024
  // bf16 region
  short* Xb   = (short*)(bc2 + D4);              // NN*INC
  short* H1b  = Xb + (size_t)NN * INC;           // NN*D1
  short* Yb   = H1b + SZ_NODE;                   // NN*1024 (fused QKVS, both layers)
  short* Wtc1 = Yb + (size_t)NN * D4;            // 1024*128
  short* Wtc2 = Wtc1 + (size_t)D4 * INC;         // 1024*256
  // int region (CSR + graph bounds)
  int* ip      = (int*)(Wtc2 + (size_t)D4 * D1);
  int* deg     = ip;                 // NN
  int* partial = deg + NN;           // 256
  int* rowstart= partial + 256;      // NN+1
  int* cursor  = rowstart + NN + 1;  // NN
  int* esrc    = cursor + NN;        // NE
  int* gb      = esrc + NE;          // NG+1

  // swizzled GEMM grid: 64 x ceil(391/8)
  const int mtiles = (NN + 127) / 128;           // 391
  const dim3 gemmGrid(64, (mtiles + 7) / 8);     // 64 x 49
  const int edgeBlocks = (NE + 255) / 256;
  const int nodeBlocks = (NN + 255) / 256;
  const int wt1Blocks  = (D1 * INC + 255) / 256;
  const int wt2Blocks  = (D1 * D1 + 255) / 256;
  const int aggBlocks  = (NN + 3) / 4;

  // ======== Converts (once) ========
  cvt_bf16_k<<<(NN * INC / 4 + 255) / 256, 256, 0, stream>>>(x, Xb, NN * INC);
  wt_cvt_k<<<wt1Blocks, 256, 0, stream>>>(Wq1, Wtc1 + (size_t)0 * D1 * INC, 7);
  wt_cvt_k<<<wt1Blocks, 256, 0, stream>>>(Wk1, Wtc1 + (size_t)1 * D1 * INC, 7);
  wt_cvt_k<<<wt1Blocks, 256, 0, stream>>>(Wv1, Wtc1 + (size_t)2 * D1 * INC, 7);
  wt_cvt_k<<<wt1Blocks, 256, 0, stream>>>(Ws1, Wtc1 + (size_t)3 * D1 * INC, 7);
  wt_cvt_k<<<wt2Blocks, 256, 0, stream>>>(Wq2, Wtc2 + (size_t)0 * D1 * D1, 8);
  wt_cvt_k<<<wt2Blocks, 256, 0, stream>>>(Wk2, Wtc2 + (size_t)1 * D1 * D1, 8);
  wt_cvt_k<<<wt2Blocks, 256, 0, stream>>>(Wv2, Wtc2 + (size_t)2 * D1 * D1, 8);
  wt_cvt_k<<<wt2Blocks, 256, 0, stream>>>(Ws2, Wtc2 + (size_t)3 * D1 * D1, 8);
  bcat_k<<<4, 256, 0, stream>>>(bq1, bk1, bv1, bs1, bc1);
  bcat_k<<<4, 256, 0, stream>>>(bq2, bk2, bv2, bs2, bc2);

  // ======== CSR build + graph bounds (once) ========
  fill_i<<<nodeBlocks, 256, 0, stream>>>(deg, 0, NN);
  deg_count<<<edgeBlocks, 256, 0, stream>>>(dstIdx, deg);
  scan1<<<NB_SCAN, 256, 0, stream>>>(deg, partial);
  scan2<<<1, 256, 0, stream>>>(partial, NB_SCAN);
  scan3<<<NB_SCAN, 256, 0, stream>>>(deg, partial, rowstart, cursor);
  scatter_k<<<edgeBlocks, 256, 0, stream>>>(srcIdx, dstIdx, cursor, esrc);
  bounds_k<<<1, 128, 0, stream>>>(batch, gb);

  // ======== Layer 1 ========  (Xb -> fused QKVS -> H1b)
  gemm_mfma<short><<<gemmGrid, 256, 0, stream>>>(Xb, Wtc1, bc1, Yb, NN, INC, D4);
  node_attn<short><<<aggBlocks, 256, 0, stream>>>(rowstart, esrc, Yb, H1b);

  // ======== Layer 2 ========  (H1b -> fused QKVS -> H2f)
  gemm_mfma<short><<<gemmGrid, 256, 0, stream>>>(H1b, Wtc2, bc2, Yb, NN, D1, D4);
  node_attn<float><<<aggBlocks, 256, 0, stream>>>(rowstart, esrc, Yb, H2f);

  // ======== Pool + head ========
  fill_f<<<(NG * D1 + 255) / 256, 256, 0, stream>>>(sums, 0.f, NG * D1);
  pool_k<<<(NN + 63) / 64, 256, 0, stream>>>(H2f, batch, sums);
  head_k<<<1, 640, 0, stream>>>(sums, gb, Wl, bl, (float*)d_out);
}

// Round 10
// 451.329 us; speedup vs baseline: 4.4848x; 1.0311x over previous
//
#include <hip/hip_runtime.h>
#include <math.h>

constexpr int NN   = 50000;   // nodes
constexpr int NE   = 400000;  // edges
constexpr int INC  = 128;     // in channels
constexpr int NH   = 4;       // heads
constexpr int D1   = 256;     // NH*HIDC
constexpr int D4   = 1024;    // 4*D1 fused QKVS row
constexpr int NOUT = 10;      // classes
constexpr int NG   = 64;      // graphs
constexpr int NB_SCAN = (NN + 255) / 256;   // 196 scan blocks

// Yb row layout per node (columns):
//   [0:256)    Q  (channel-ordered)
//   [256:768)  KV interleaved: group g (0..63) -> cols 256+8g..256+8g+3 = K ch 4g..4g+3,
//                                               cols 256+8g+4..+7      = V ch 4g..4g+3
//   [768:1024) S  (channel-ordered)
// Lane t of node_attn reads 16B at row+256+t*8 = [K c0..c0+3 | V c0..c0+3], c0 = 4t.

typedef __attribute__((ext_vector_type(8))) short bf16x8;   // MFMA A/B frag
typedef __attribute__((ext_vector_type(4))) float f32x4;    // MFMA C/D frag

// ---------- bf16 helpers ----------
__device__ __forceinline__ short f2b(float f) {
  union { float f; unsigned int i; } v; v.f = f;
  unsigned int x = v.i;
  return (short)((x + 0x7FFFu + ((x >> 16) & 1u)) >> 16);
}
__device__ __forceinline__ float b2f(short u) {
  union { unsigned int i; float f; } v; v.i = ((unsigned int)(unsigned short)u) << 16;
  return v.f;
}
__device__ __forceinline__ float4 ld4b(const short* p) {
  short4 u = *(const short4*)p;
  return make_float4(b2f(u.x), b2f(u.y), b2f(u.z), b2f(u.w));
}
// unpack int4 (8 bf16) -> 8 floats: f[0..3]=K, f[4..7]=V (interleaved layout)
__device__ __forceinline__ void unpack8(const int4 v, float* f) {
  union { unsigned int u; float x; } a;
  a.u = (unsigned int)v.x << 16;         f[0] = a.x;
  a.u = (unsigned int)v.x & 0xffff0000u; f[1] = a.x;
  a.u = (unsigned int)v.y << 16;         f[2] = a.x;
  a.u = (unsigned int)v.y & 0xffff0000u; f[3] = a.x;
  a.u = (unsigned int)v.z << 16;         f[4] = a.x;
  a.u = (unsigned int)v.z & 0xffff0000u; f[5] = a.x;
  a.u = (unsigned int)v.w << 16;         f[6] = a.x;
  a.u = (unsigned int)v.w & 0xffff0000u; f[7] = a.x;
}

// ---------- async global->LDS 16B ----------
__device__ __forceinline__ void gld_lds16(const short* g, short* l) {
  __builtin_amdgcn_global_load_lds(
      (const __attribute__((address_space(1))) unsigned int*)g,
      (__attribute__((address_space(3))) unsigned int*)l, 16, 0, 0);
}

// ---------- fills ----------
__global__ void fill_i(int* __restrict__ p, int v, int n) {
  int i = blockIdx.x * 256 + threadIdx.x;
  if (i < n) p[i] = v;
}
__global__ void fill_f(float* __restrict__ p, float v, int n) {
  int i = blockIdx.x * 256 + threadIdx.x;
  if (i < n) p[i] = v;
}

// ---------- fp32 -> bf16 convert ----------
__global__ void cvt_bf16_k(const float* __restrict__ in, short* __restrict__ out, int n) {
  int i = (blockIdx.x * 256 + threadIdx.x) * 4;
  if (i >= n) return;
  float4 v = *(const float4*)(in + i);
  short4 o; o.x = f2b(v.x); o.y = f2b(v.y); o.z = f2b(v.z); o.w = f2b(v.w);
  *(short4*)(out + i) = o;
}

// ---------- fused weight convert+transpose+permute for one layer ----------
// W*[K][256] fp32 -> Wt[1024][K] bf16 with KV-interleaved row mapping.
__global__ void wt_cvt_all(const float* __restrict__ Wq, const float* __restrict__ Wk,
                           const float* __restrict__ Wv, const float* __restrict__ Ws,
                           short* __restrict__ Wt, int kbits) {
  int i = blockIdx.x * 256 + threadIdx.x;
  int K = 1 << kbits;
  if (i >= 4 * D1 * K) return;
  int seg = i >> (kbits + 8);               // 0=Q 1=K 2=V 3=S
  int idx = i & ((D1 << kbits) - 1);
  int n = idx >> kbits, k = idx & (K - 1);
  const float* W = (seg == 0) ? Wq : (seg == 1) ? Wk : (seg == 2) ? Wv : Ws;
  int row;
  if (seg == 0)      row = n;
  else if (seg == 3) row = 768 + n;
  else               row = 256 + (n >> 2) * 8 + ((seg == 2) ? 4 : 0) + (n & 3);
  Wt[(size_t)row * K + k] = f2b(W[(size_t)k * D1 + n]);
}

// ---------- bias concat (both layers, permuted rows) ----------
__global__ void bcat_k(const float* __restrict__ q1, const float* __restrict__ k1,
                       const float* __restrict__ v1, const float* __restrict__ s1,
                       const float* __restrict__ q2, const float* __restrict__ k2,
                       const float* __restrict__ v2, const float* __restrict__ s2,
                       float* __restrict__ bc1, float* __restrict__ bc2) {
  int i = blockIdx.x * 256 + threadIdx.x;
  if (i >= 2 * D4) return;
  int row = i & (D4 - 1);
  const float* bq = (i < D4) ? q1 : q2;
  const float* bk = (i < D4) ? k1 : k2;
  const float* bv = (i < D4) ? v1 : v2;
  const float* bs = (i < D4) ? s1 : s2;
  float v;
  if (row < 256) v = bq[row];
  else if (row < 768) {
    int j = row - 256, grp = j >> 3, off = j & 7;
    int ch = grp * 4 + (off & 3);
    v = (off < 4) ? bk[ch] : bv[ch];
  } else v = bs[row - 768];
  float* out = (i < D4) ? bc1 : bc2;
  out[row] = v;
}

// ---------- CSR build ----------
__global__ void deg_count(const int* __restrict__ dst, int* __restrict__ deg) {
  int e = blockIdx.x * 256 + threadIdx.x;
  if (e < NE) atomicAdd(&deg[dst[e]], 1);
}
__global__ __launch_bounds__(256) void scan1(const int* __restrict__ deg,
                                             int* __restrict__ partial) {
  __shared__ int sh[256];
  int t = threadIdx.x, i = blockIdx.x * 256 + t;
  sh[t] = (i < NN) ? deg[i] : 0;
  __syncthreads();
  for (int off = 128; off > 0; off >>= 1) {
    if (t < off) sh[t] += sh[t + off];
    __syncthreads();
  }
  if (t == 0) partial[blockIdx.x] = sh[0];
}
__global__ __launch_bounds__(256) void scan2(int* __restrict__ partial, int nb) {
  __shared__ int sh[256];
  int t = threadIdx.x;
  int v = (t < nb) ? partial[t] : 0;
  sh[t] = v;
  __syncthreads();
  for (int off = 1; off < 256; off <<= 1) {
    int o = (t >= off) ? sh[t - off] : 0;
    __syncthreads();
    sh[t] += o;
    __syncthreads();
  }
  if (t < nb) partial[t] = sh[t] - v;   // exclusive
}
__global__ __launch_bounds__(256) void scan3(const int* __restrict__ deg,
    const int* __restrict__ partial, int* __restrict__ rowstart,
    int* __restrict__ cursor) {
  __shared__ int sh[256];
  int t = threadIdx.x, i = blockIdx.x * 256 + t;
  int v = (i < NN) ? deg[i] : 0;
  sh[t] = v;
  __syncthreads();
  for (int off = 1; off < 256; off <<= 1) {
    int o = (t >= off) ? sh[t - off] : 0;
    __syncthreads();
    sh[t] += o;
    __syncthreads();
  }
  int excl = sh[t] - v + partial[blockIdx.x];
  if (i <= NN) rowstart[i] = excl;
  if (i < NN)  cursor[i]   = excl;
}
__global__ void scatter_k(const int* __restrict__ src, const int* __restrict__ dst,
    int* __restrict__ cursor, int* __restrict__ esrc) {
  int e = blockIdx.x * 256 + threadIdx.x;
  if (e >= NE) return;
  int d = dst[e];
  int pos = atomicAdd(&cursor[d], 1);
  esrc[pos] = src[e];
}

// ---------- MFMA GEMM: Y[M,Ncols] = Xb[M,K](bf16) @ Wt[Ncols,K]^T + bias ------
template <typename TOUT>
__device__ __forceinline__ void st1(TOUT* p, float v);
template <> __device__ __forceinline__ void st1<float>(float* p, float v) { *p = v; }
template <> __device__ __forceinline__ void st1<short>(short* p, float v) { *p = f2b(v); }

template <typename TOUT>
__global__ __launch_bounds__(256) void gemm_mfma(
    const short* __restrict__ Xb, const short* __restrict__ Wt,
    const float* __restrict__ bias, TOUT* __restrict__ Y, int M, int K, int Ncols) {
  __shared__ short As[128 * 32];
  __shared__ short Bs[128 * 32];
  const int bx = blockIdx.x;                 // 0..63
  const int by = blockIdx.y;
  const int m_tile = (bx & 7) + (by << 3);   // XCD swizzle: m-tile pinned per XCD
  const int n_tile = bx >> 3;                // 0..7
  const int m0 = m_tile * 128;
  if (m0 >= M) return;
  const int n0 = n_tile * 128;

  const int t    = threadIdx.x;
  const int lane = t & 63;
  const int wv   = t >> 6;
  const int wm   = (wv >> 1) * 64;
  const int wn   = (wv & 1) * 64;
  const int quad = lane >> 4;
  const int l16  = lane & 15;
  const int lrow = lane >> 2;
  const int lseg = lane & 3;

  f32x4 acc[4][4] = {};
  for (int k0 = 0; k0 < K; k0 += 32) {
#pragma unroll
    for (int j = 0; j < 2; ++j) {
      const int rb = wv * 32 + j * 16;
      int gm = m0 + rb + lrow;
      gm = gm < M ? gm : M - 1;                         // clamp (stores guarded)
      gld_lds16(Xb + (size_t)gm * K + k0 + lseg * 8, &As[rb * 32]);
      gld_lds16(Wt + (size_t)(n0 + rb + lrow) * K + k0 + lseg * 8, &Bs[rb * 32]);
    }
    __syncthreads();
    bf16x8 a[4], b[4];
#pragma unroll
    for (int mi = 0; mi < 4; mi++)
      a[mi] = *(const bf16x8*)(&As[(wm + mi * 16 + l16) * 32 + quad * 8]);
#pragma unroll
    for (int nj = 0; nj < 4; nj++)
      b[nj] = *(const bf16x8*)(&Bs[(wn + nj * 16 + l16) * 32 + quad * 8]);
#pragma unroll
    for (int mi = 0; mi < 4; mi++)
#pragma unroll
      for (int nj = 0; nj < 4; nj++)
        acc[mi][nj] = __builtin_amdgcn_mfma_f32_16x16x32_bf16(a[mi], b[nj], acc[mi][nj], 0, 0, 0);
    __syncthreads();
  }
#pragma unroll
  for (int mi = 0; mi < 4; mi++) {
#pragma unroll
    for (int r = 0; r < 4; r++) {
      int gm = m0 + wm + mi * 16 + quad * 4 + r;
      if (gm >= M) continue;
#pragma unroll
      for (int nj = 0; nj < 4; nj++) {
        int gn = n0 + wn + nj * 16 + l16;
        st1<TOUT>(Y + (size_t)gm * Ncols + gn, acc[mi][nj][r] + bias[gn]);
      }
    }
  }
}

// ---------- fused attention: online softmax, KV-interleaved, 4-edge unroll ----
// wave per node; 16-lane group per head; lane owns 4 channels (c0 = 4t).
// Per edge per lane: ONE 16B load = [K c0..c0+3 | V c0..c0+3].
template <typename TOUT>
__global__ __launch_bounds__(256) void node_attn(
    const int* __restrict__ rowstart, const int* __restrict__ esrc,
    const short* __restrict__ Yb, TOUT* __restrict__ out) {
  const int nid = blockIdx.x * 4 + (threadIdx.x >> 6);
  if (nid >= NN) return;
  const int t  = threadIdx.x & 63;
  const int c0 = t * 4;
  const int r0 = rowstart[nid], r1 = rowstart[nid + 1];
  const float4 q = ld4b(Yb + (size_t)nid * D4 + c0);
  const short* kvb = Yb + 256 + t * 8;     // lane-fixed offset into KV region
  float m = -INFINITY, denom = 0.f;
  float4 acc = make_float4(0.f, 0.f, 0.f, 0.f);
  int r = r0;
  for (; r + 3 < r1; r += 4) {
    const int4 x0 = *(const int4*)(kvb + (size_t)esrc[r + 0] * D4);
    const int4 x1 = *(const int4*)(kvb + (size_t)esrc[r + 1] * D4);
    const int4 x2 = *(const int4*)(kvb + (size_t)esrc[r + 2] * D4);
    const int4 x3 = *(const int4*)(kvb + (size_t)esrc[r + 3] * D4);
    float f0[8], f1[8], f2[8], f3[8];
    unpack8(x0, f0); unpack8(x1, f1); unpack8(x2, f2); unpack8(x3, f3);
    float d0 = q.x * f0[0] + q.y * f0[1] + q.z * f0[2] + q.w * f0[3];
    float d1 = q.x * f1[0] + q.y * f1[1] + q.z * f1[2] + q.w * f1[3];
    float d2 = q.x * f2[0] + q.y * f2[1] + q.z * f2[2] + q.w * f2[3];
    float d3 = q.x * f3[0] + q.y * f3[1] + q.z * f3[2] + q.w * f3[3];
#pragma unroll
    for (int off = 1; off <= 8; off <<= 1) {
      d0 += __shfl_xor(d0, off, 16);
      d1 += __shfl_xor(d1, off, 16);
      d2 += __shfl_xor(d2, off, 16);
      d3 += __shfl_xor(d3, off, 16);
    }
    d0 *= 0.125f; d1 *= 0.125f; d2 *= 0.125f; d3 *= 0.125f;
    const float nm = fmaxf(fmaxf(m, fmaxf(d0, d1)), fmaxf(d2, d3));
    const float sc = __expf(m - nm);
    const float e0 = __expf(d0 - nm);
    const float e1 = __expf(d1 - nm);
    const float e2 = __expf(d2 - nm);
    const float e3 = __expf(d3 - nm);
    denom = denom * sc + e0 + e1 + e2 + e3;
    acc.x = acc.x * sc + e0 * f0[4] + e1 * f1[4] + e2 * f2[4] + e3 * f3[4];
    acc.y = acc.y * sc + e0 * f0[5] + e1 * f1[5] + e2 * f2[5] + e3 * f3[5];
    acc.z = acc.z * sc + e0 * f0[6] + e1 * f1[6] + e2 * f2[6] + e3 * f3[6];
    acc.w = acc.w * sc + e0 * f0[7] + e1 * f1[7] + e2 * f2[7] + e3 * f3[7];
    m = nm;
  }
  for (; r < r1; r++) {                     // tail (<=3 edges)
    const int4 x0 = *(const int4*)(kvb + (size_t)esrc[r] * D4);
    float f0[8];
    unpack8(x0, f0);
    float d0 = q.x * f0[0] + q.y * f0[1] + q.z * f0[2] + q.w * f0[3];
#pragma unroll
    for (int off = 1; off <= 8; off <<= 1) d0 += __shfl_xor(d0, off, 16);
    d0 *= 0.125f;
    const float nm = fmaxf(m, d0);
    const float sc = __expf(m - nm);
    const float e0 = __expf(d0 - nm);
    denom = denom * sc + e0;
    acc.x = acc.x * sc + e0 * f0[4];
    acc.y = acc.y * sc + e0 * f0[5];
    acc.z = acc.z * sc + e0 * f0[6];
    acc.w = acc.w * sc + e0 * f0[7];
    m = nm;
  }
  const float inv = 1.0f / (denom + 1e-16f);
  const float4 sk = ld4b(Yb + (size_t)nid * D4 + 768 + c0);
  float o0 = acc.x * inv + sk.x;
  float o1 = acc.y * inv + sk.y;
  float o2 = acc.z * inv + sk.z;
  float o3 = acc.w * inv + sk.w;
  o0 = o0 > 0.f ? o0 : expm1f(o0);
  o1 = o1 > 0.f ? o1 : expm1f(o1);
  o2 = o2 > 0.f ? o2 : expm1f(o2);
  o3 = o3 > 0.f ? o3 : expm1f(o3);
  TOUT* p = out + (size_t)nid * D1 + c0;
  st1<TOUT>(p + 0, o0); st1<TOUT>(p + 1, o1);
  st1<TOUT>(p + 2, o2); st1<TOUT>(p + 3, o3);
}

// ---------- graph boundaries via binary search (batch is sorted) ----------
__global__ void bounds_k(const int* __restrict__ batch, int* __restrict__ gb) {
  int g = threadIdx.x;            // 0..NG
  if (g > NG) return;
  int lo = 0, hi = NN;
  while (lo < hi) {
    int mid = (lo + hi) >> 1;
    if (batch[mid] < g) lo = mid + 1; else hi = mid;
  }
  gb[g] = lo;
}

// ---------- mean-pool partial sums (parallel, run-length atomics) ----------
__global__ __launch_bounds__(256) void pool_k(const float* __restrict__ h,
    const int* __restrict__ batch, float* __restrict__ sums) {
  const int c = threadIdx.x;
  const int n0 = blockIdx.x * 64;
  const int n1 = min(n0 + 64, NN);
  float run = 0.f;
  int curg = -1;
  for (int n = n0; n < n1; n++) {
    int g = batch[n];
    if (g != curg) {
      if (curg >= 0) atomicAdd(&sums[(size_t)curg * D1 + c], run);
      run = 0.f; curg = g;
    }
    run += h[(size_t)n * D1 + c];
  }
  if (curg >= 0) atomicAdd(&sums[(size_t)curg * D1 + c], run);
}

// ---------- classifier + log_softmax (counts from gb) ----------
__global__ __launch_bounds__(640) void head_k(const float* __restrict__ sums,
    const int* __restrict__ gb, const float* __restrict__ Wl,
    const float* __restrict__ bl, float* __restrict__ out) {
  __shared__ float logits[NG][NOUT];
  const int t = threadIdx.x;
  if (t < NG * NOUT) {
    int g = t / NOUT, o = t % NOUT;
    float inv = 1.0f / fmaxf((float)(gb[g + 1] - gb[g]), 1.0f);
    float acc = 0.f;
    for (int k = 0; k < D1; k++) acc += sums[(size_t)g * D1 + k] * Wl[k * NOUT + o];
    logits[g][o] = acc * inv + bl[o];
  }
  __syncthreads();
  if (t < NG) {
    float mx = -INFINITY;
#pragma unroll
    for (int o = 0; o < NOUT; o++) mx = fmaxf(mx, logits[t][o]);
    float s = 0.f;
#pragma unroll
    for (int o = 0; o < NOUT; o++) s += __expf(logits[t][o] - mx);
    float lse = mx + logf(s);
#pragma unroll
    for (int o = 0; o < NOUT; o++) out[t * NOUT + o] = logits[t][o] - lse;
  }
}

// ---------------------------------------------------------------------------
extern "C" void kernel_launch(void* const* d_in, const int* in_sizes, int n_in,
                              void* d_out, int out_size, void* d_ws, size_t ws_size,
                              hipStream_t stream) {
  const float* x   = (const float*)d_in[0];
  const int* ei    = (const int*)d_in[1];
  const int* batch = (const int*)d_in[2];
  const float* Wq1 = (const float*)d_in[3];  const float* bq1 = (const float*)d_in[4];
  const float* Wk1 = (const float*)d_in[5];  const float* bk1 = (const float*)d_in[6];
  const float* Wv1 = (const float*)d_in[7];  const float* bv1 = (const float*)d_in[8];
  const float* Ws1 = (const float*)d_in[9];  const float* bs1 = (const float*)d_in[10];
  const float* Wq2 = (const float*)d_in[11]; const float* bq2 = (const float*)d_in[12];
  const float* Wk2 = (const float*)d_in[13]; const float* bk2 = (const float*)d_in[14];
  const float* Wv2 = (const float*)d_in[15]; const float* bv2 = (const float*)d_in[16];
  const float* Ws2 = (const float*)d_in[17]; const float* bs2 = (const float*)d_in[18];
  const float* Wl  = (const float*)d_in[19]; const float* bl  = (const float*)d_in[20];

  const int* srcIdx = ei;          // edge_index[0] (source j)
  const int* dstIdx = ei + NE;     // edge_index[1] (target i)

  // -------- workspace layout --------
  float* ws = (float*)d_ws;
  const size_t SZ_NODE = (size_t)NN * D1;       // 12.8M elems
  float* H2f  = ws;                              // NN*D1 fp32 (final layer-2 out)
  float* sums = ws + SZ_NODE;                    // NG*D1
  float* bc1  = sums + (size_t)NG * D1;          // 1024
  float* bc2  = bc1 + D4;                        // 1024
  // bf16 region
  short* Xb   = (short*)(bc2 + D4);              // NN*INC
  short* H1b  = Xb + (size_t)NN * INC;           // NN*D1
  short* Yb   = H1b + SZ_NODE;                   // NN*1024 (fused QKVS, both layers)
  short* Wtc1 = Yb + (size_t)NN * D4;            // 1024*128
  short* Wtc2 = Wtc1 + (size_t)D4 * INC;         // 1024*256
  // int region (CSR + graph bounds)
  int* ip      = (int*)(Wtc2 + (size_t)D4 * D1);
  int* deg     = ip;                 // NN
  int* partial = deg + NN;           // 256
  int* rowstart= partial + 256;      // NN+1
  int* cursor  = rowstart + NN + 1;  // NN
  int* esrc    = cursor + NN;        // NE
  int* gb      = esrc + NE;          // NG+1

  const int mtiles = (NN + 127) / 128;           // 391
  const dim3 gemmGrid(64, (mtiles + 7) / 8);     // 64 x 49 swizzled
  const int edgeBlocks = (NE + 255) / 256;
  const int nodeBlocks = (NN + 255) / 256;
  const int aggBlocks  = (NN + 3) / 4;

  // ======== Converts (once) ========
  cvt_bf16_k<<<(NN * INC / 4 + 255) / 256, 256, 0, stream>>>(x, Xb, NN * INC);
  wt_cvt_all<<<(4 * D1 * INC + 255) / 256, 256, 0, stream>>>(Wq1, Wk1, Wv1, Ws1, Wtc1, 7);
  wt_cvt_all<<<(4 * D1 * D1 + 255) / 256, 256, 0, stream>>>(Wq2, Wk2, Wv2, Ws2, Wtc2, 8);
  bcat_k<<<8, 256, 0, stream>>>(bq1, bk1, bv1, bs1, bq2, bk2, bv2, bs2, bc1, bc2);

  // ======== CSR build + graph bounds (once) ========
  fill_i<<<nodeBlocks, 256, 0, stream>>>(deg, 0, NN);
  deg_count<<<edgeBlocks, 256, 0, stream>>>(dstIdx, deg);
  scan1<<<NB_SCAN, 256, 0, stream>>>(deg, partial);
  scan2<<<1, 256, 0, stream>>>(partial, NB_SCAN);
  scan3<<<NB_SCAN, 256, 0, stream>>>(deg, partial, rowstart, cursor);
  scatter_k<<<edgeBlocks, 256, 0, stream>>>(srcIdx, dstIdx, cursor, esrc);
  bounds_k<<<1, 128, 0, stream>>>(batch, gb);

  // ======== Layer 1 ========  (Xb -> fused QKVS -> H1b)
  gemm_mfma<short><<<gemmGrid, 256, 0, stream>>>(Xb, Wtc1, bc1, Yb, NN, INC, D4);
  node_attn<short><<<aggBlocks, 256, 0, stream>>>(rowstart, esrc, Yb, H1b);

  // ======== Layer 2 ========  (H1b -> fused QKVS -> H2f)
  gemm_mfma<short><<<gemmGrid, 256, 0, stream>>>(H1b, Wtc2, bc2, Yb, NN, D1, D4);
  node_attn<float><<<aggBlocks, 256, 0, stream>>>(rowstart, esrc, Yb, H2f);

  // ======== Pool + head ========
  fill_f<<<(NG * D1 + 255) / 256, 256, 0, stream>>>(sums, 0.f, NG * D1);
  pool_k<<<(NN + 63) / 64, 256, 0, stream>>>(H2f, batch, sums);
  head_k<<<1, 640, 0, stream>>>(sums, gb, Wl, bl, (float*)d_out);
}

// Round 11
// 433.588 us; speedup vs baseline: 4.6683x; 1.0409x over previous
//
#include <hip/hip_runtime.h>
#include <math.h>

constexpr int NN   = 50000;   // nodes
constexpr int NE   = 400000;  // edges
constexpr int INC  = 128;     // in channels
constexpr int NH   = 4;       // heads
constexpr int D1   = 256;     // NH*HIDC
constexpr int D4   = 1024;    // 4*D1 fused QKVS row
constexpr int NOUT = 10;      // classes
constexpr int NG   = 64;      // graphs
constexpr int NB_SCAN = (NN + 255) / 256;   // 196 scan blocks

// Yb row layout per node (columns):
//   [0:256)    Q  (channel-ordered)
//   [256:768)  KV interleaved: group g (0..63): cols 256+8g..+3 = K ch 4g..4g+3,
//                                               cols 256+8g+4..+7 = V ch 4g..4g+3
//   [768:1024) S  (channel-ordered)

typedef __attribute__((ext_vector_type(8))) short bf16x8;   // MFMA A/B frag
typedef __attribute__((ext_vector_type(4))) float f32x4;    // MFMA C/D frag

// ---------- bf16 helpers ----------
__device__ __forceinline__ short f2b(float f) {
  union { float f; unsigned int i; } v; v.f = f;
  unsigned int x = v.i;
  return (short)((x + 0x7FFFu + ((x >> 16) & 1u)) >> 16);
}
__device__ __forceinline__ float b2f(short u) {
  union { unsigned int i; float f; } v; v.i = ((unsigned int)(unsigned short)u) << 16;
  return v.f;
}
__device__ __forceinline__ float4 ld4b(const short* p) {
  short4 u = *(const short4*)p;
  return make_float4(b2f(u.x), b2f(u.y), b2f(u.z), b2f(u.w));
}
__device__ __forceinline__ void unpack8(const int4 v, float* f) {
  union { unsigned int u; float x; } a;
  a.u = (unsigned int)v.x << 16;         f[0] = a.x;
  a.u = (unsigned int)v.x & 0xffff0000u; f[1] = a.x;
  a.u = (unsigned int)v.y << 16;         f[2] = a.x;
  a.u = (unsigned int)v.y & 0xffff0000u; f[3] = a.x;
  a.u = (unsigned int)v.z << 16;         f[4] = a.x;
  a.u = (unsigned int)v.z & 0xffff0000u; f[5] = a.x;
  a.u = (unsigned int)v.w << 16;         f[6] = a.x;
  a.u = (unsigned int)v.w & 0xffff0000u; f[7] = a.x;
}

// ---------- async global->LDS 16B ----------
__device__ __forceinline__ void gld_lds16(const short* g, short* l) {
  __builtin_amdgcn_global_load_lds(
      (const __attribute__((address_space(1))) unsigned int*)g,
      (__attribute__((address_space(3))) unsigned int*)l, 16, 0, 0);
}

// ---------- fills ----------
__global__ void fill_i(int* __restrict__ p, int v, int n) {
  int i = blockIdx.x * 256 + threadIdx.x;
  if (i < n) p[i] = v;
}
__global__ void fill_f(float* __restrict__ p, float v, int n) {
  int i = blockIdx.x * 256 + threadIdx.x;
  if (i < n) p[i] = v;
}

// ---------- fused converts: x->bf16, W->Wt (transpose+permute), bias concat ---
constexpr int CVT_XB  = (NN * INC / 4 + 255) / 256;   // 6250 blocks
constexpr int CVT_W1B = (4 * D1 * INC + 255) / 256;   // 512
constexpr int CVT_W2B = (4 * D1 * D1 + 255) / 256;    // 1024

__device__ __forceinline__ void wt_one(const float* Wq, const float* Wk,
    const float* Wv, const float* Ws, short* Wt, int kbits, int i) {
  int K = 1 << kbits;
  int seg = i >> (kbits + 8);               // 0=Q 1=K 2=V 3=S
  int idx = i & ((D1 << kbits) - 1);
  int n = idx >> kbits, k = idx & (K - 1);
  const float* W = (seg == 0) ? Wq : (seg == 1) ? Wk : (seg == 2) ? Wv : Ws;
  int row;
  if (seg == 0)      row = n;
  else if (seg == 3) row = 768 + n;
  else               row = 256 + (n >> 2) * 8 + ((seg == 2) ? 4 : 0) + (n & 3);
  Wt[(size_t)row * K + k] = f2b(W[(size_t)k * D1 + n]);
}

__global__ void cvt_all_k(const float* __restrict__ x, short* __restrict__ Xb,
    const float* __restrict__ Wq1, const float* __restrict__ Wk1,
    const float* __restrict__ Wv1, const float* __restrict__ Ws1,
    const float* __restrict__ Wq2, const float* __restrict__ Wk2,
    const float* __restrict__ Wv2, const float* __restrict__ Ws2,
    short* __restrict__ Wtc1, short* __restrict__ Wtc2,
    const float* __restrict__ bq1, const float* __restrict__ bk1,
    const float* __restrict__ bv1, const float* __restrict__ bs1,
    const float* __restrict__ bq2, const float* __restrict__ bk2,
    const float* __restrict__ bv2, const float* __restrict__ bs2,
    float* __restrict__ bc1, float* __restrict__ bc2) {
  const int b = blockIdx.x;
  const int t = threadIdx.x;
  if (b < CVT_XB) {                               // x -> bf16 (4/thread)
    int i = (b * 256 + t) * 4;
    if (i >= NN * INC) return;
    float4 v = *(const float4*)(x + i);
    short4 o; o.x = f2b(v.x); o.y = f2b(v.y); o.z = f2b(v.z); o.w = f2b(v.w);
    *(short4*)(Xb + i) = o;
  } else if (b < CVT_XB + CVT_W1B) {              // layer-1 weights
    int i = (b - CVT_XB) * 256 + t;
    if (i < 4 * D1 * INC) wt_one(Wq1, Wk1, Wv1, Ws1, Wtc1, 7, i);
  } else if (b < CVT_XB + CVT_W1B + CVT_W2B) {    // layer-2 weights
    int i = (b - CVT_XB - CVT_W1B) * 256 + t;
    if (i < 4 * D1 * D1) wt_one(Wq2, Wk2, Wv2, Ws2, Wtc2, 8, i);
  } else {                                        // bias concat (8 blocks)
    int i = (b - CVT_XB - CVT_W1B - CVT_W2B) * 256 + t;
    if (i >= 2 * D4) return;
    int row = i & (D4 - 1);
    const float* bq = (i < D4) ? bq1 : bq2;
    const float* bk = (i < D4) ? bk1 : bk2;
    const float* bv = (i < D4) ? bv1 : bv2;
    const float* bs = (i < D4) ? bs1 : bs2;
    float v;
    if (row < 256) v = bq[row];
    else if (row < 768) {
      int j = row - 256, grp = j >> 3, off = j & 7;
      int ch = grp * 4 + (off & 3);
      v = (off < 4) ? bk[ch] : bv[ch];
    } else v = bs[row - 768];
    ((i < D4) ? bc1 : bc2)[row] = v;
  }
}

// ---------- CSR build ----------
__global__ void deg_count(const int* __restrict__ dst, int* __restrict__ deg) {
  int e = blockIdx.x * 256 + threadIdx.x;
  if (e < NE) atomicAdd(&deg[dst[e]], 1);
}
// block partial sums; extra block NB_SCAN does graph bounds (binary search)
__global__ __launch_bounds__(256) void scan1(const int* __restrict__ deg,
    int* __restrict__ partial, const int* __restrict__ batch, int* __restrict__ gb) {
  if (blockIdx.x == NB_SCAN) {
    int g = threadIdx.x;
    if (g > NG) return;
    int lo = 0, hi = NN;
    while (lo < hi) {
      int mid = (lo + hi) >> 1;
      if (batch[mid] < g) lo = mid + 1; else hi = mid;
    }
    gb[g] = lo;
    return;
  }
  __shared__ int sh[256];
  int t = threadIdx.x, i = blockIdx.x * 256 + t;
  sh[t] = (i < NN) ? deg[i] : 0;
  __syncthreads();
  for (int off = 128; off > 0; off >>= 1) {
    if (t < off) sh[t] += sh[t + off];
    __syncthreads();
  }
  if (t == 0) partial[blockIdx.x] = sh[0];
}
// per-block: redundant self-scan of partials + local exclusive scan of deg
__global__ __launch_bounds__(256) void scan3(const int* __restrict__ deg,
    const int* __restrict__ partial, int* __restrict__ rowstart,
    int* __restrict__ cursor) {
  __shared__ int sh[256];
  __shared__ int base_s;
  const int t = threadIdx.x;
  // phase 1: inclusive scan of the 196 partials (all blocks redundantly)
  int pv = (t < NB_SCAN) ? partial[t] : 0;
  sh[t] = pv;
  __syncthreads();
  for (int off = 1; off < 256; off <<= 1) {
    int o = (t >= off) ? sh[t - off] : 0;
    __syncthreads();
    sh[t] += o;
    __syncthreads();
  }
  if (t == 0) base_s = (blockIdx.x == 0) ? 0 : sh[blockIdx.x - 1];
  __syncthreads();
  const int base = base_s;
  __syncthreads();
  // phase 2: local exclusive scan of deg
  int i = blockIdx.x * 256 + t;
  int v = (i < NN) ? deg[i] : 0;
  sh[t] = v;
  __syncthreads();
  for (int off = 1; off < 256; off <<= 1) {
    int o = (t >= off) ? sh[t - off] : 0;
    __syncthreads();
    sh[t] += o;
    __syncthreads();
  }
  int excl = sh[t] - v + base;
  if (i <= NN) rowstart[i] = excl;
  if (i < NN)  cursor[i]   = excl;
}
__global__ void scatter_k(const int* __restrict__ src, const int* __restrict__ dst,
    int* __restrict__ cursor, int* __restrict__ esrc) {
  int e = blockIdx.x * 256 + threadIdx.x;
  if (e >= NE) return;
  int d = dst[e];
  int pos = atomicAdd(&cursor[d], 1);
  esrc[pos] = src[e];
}

// ---------- MFMA GEMM: Y[M,Ncols] = Xb[M,K] @ Wt[Ncols,K]^T + bias ----------
// 64 K-cols per barrier-pair via two [128][32] buffer pairs (proven layout);
// global_load_lds width=16; XCD swizzle pins each m-tile's 8 n-tiles together.
template <typename TOUT>
__device__ __forceinline__ void st1(TOUT* p, float v);
template <> __device__ __forceinline__ void st1<float>(float* p, float v) { *p = v; }
template <> __device__ __forceinline__ void st1<short>(short* p, float v) { *p = f2b(v); }

template <typename TOUT>
__global__ __launch_bounds__(256) void gemm_mfma(
    const short* __restrict__ Xb, const short* __restrict__ Wt,
    const float* __restrict__ bias, TOUT* __restrict__ Y, int M, int K, int Ncols) {
  __shared__ short As0[128 * 32];
  __shared__ short As1[128 * 32];
  __shared__ short Bs0[128 * 32];
  __shared__ short Bs1[128 * 32];
  const int bx = blockIdx.x;                 // 0..63
  const int by = blockIdx.y;
  const int m_tile = (bx & 7) + (by << 3);
  const int n_tile = bx >> 3;                // 0..7
  const int m0 = m_tile * 128;
  if (m0 >= M) return;
  const int n0 = n_tile * 128;

  const int t    = threadIdx.x;
  const int lane = t & 63;
  const int wv   = t >> 6;
  const int wm   = (wv >> 1) * 64;
  const int wn   = (wv & 1) * 64;
  const int quad = lane >> 4;
  const int l16  = lane & 15;
  const int lrow = lane >> 2;     // 0..15
  const int lseg = lane & 3;      // 0..3

  f32x4 acc[4][4] = {};
  for (int k0 = 0; k0 < K; k0 += 64) {
#pragma unroll
    for (int j = 0; j < 2; ++j) {
      const int rb = wv * 32 + j * 16;
      int gm = m0 + rb + lrow;
      gm = gm < M ? gm : M - 1;                        // clamp (stores guarded)
      const size_t ga = (size_t)gm * K + k0 + lseg * 8;
      gld_lds16(Xb + ga,      &As0[rb * 32]);
      gld_lds16(Xb + ga + 32, &As1[rb * 32]);
      const size_t gw = (size_t)(n0 + rb + lrow) * K + k0 + lseg * 8;
      gld_lds16(Wt + gw,      &Bs0[rb * 32]);
      gld_lds16(Wt + gw + 32, &Bs1[rb * 32]);
    }
    __syncthreads();
    {
      bf16x8 a[4], b[4];
#pragma unroll
      for (int mi = 0; mi < 4; mi++)
        a[mi] = *(const bf16x8*)(&As0[(wm + mi * 16 + l16) * 32 + quad * 8]);
#pragma unroll
      for (int nj = 0; nj < 4; nj++)
        b[nj] = *(const bf16x8*)(&Bs0[(wn + nj * 16 + l16) * 32 + quad * 8]);
#pragma unroll
      for (int mi = 0; mi < 4; mi++)
#pragma unroll
        for (int nj = 0; nj < 4; nj++)
          acc[mi][nj] = __builtin_amdgcn_mfma_f32_16x16x32_bf16(a[mi], b[nj], acc[mi][nj], 0, 0, 0);
#pragma unroll
      for (int mi = 0; mi < 4; mi++)
        a[mi] = *(const bf16x8*)(&As1[(wm + mi * 16 + l16) * 32 + quad * 8]);
#pragma unroll
      for (int nj = 0; nj < 4; nj++)
        b[nj] = *(const bf16x8*)(&Bs1[(wn + nj * 16 + l16) * 32 + quad * 8]);
#pragma unroll
      for (int mi = 0; mi < 4; mi++)
#pragma unroll
        for (int nj = 0; nj < 4; nj++)
          acc[mi][nj] = __builtin_amdgcn_mfma_f32_16x16x32_bf16(a[mi], b[nj], acc[mi][nj], 0, 0, 0);
    }
    __syncthreads();
  }
#pragma unroll
  for (int mi = 0; mi < 4; mi++) {
#pragma unroll
    for (int r = 0; r < 4; r++) {
      int gm = m0 + wm + mi * 16 + quad * 4 + r;
      if (gm >= M) continue;
#pragma unroll
      for (int nj = 0; nj < 4; nj++) {
        int gn = n0 + wn + nj * 16 + l16;
        st1<TOUT>(Y + (size_t)gm * Ncols + gn, acc[mi][nj][r] + bias[gn]);
      }
    }
  }
}

// ---------- fused attention: online softmax, KV-interleaved, 4-edge unroll ----
template <typename TOUT>
__global__ __launch_bounds__(256) void node_attn(
    const int* __restrict__ rowstart, const int* __restrict__ esrc,
    const short* __restrict__ Yb, TOUT* __restrict__ out) {
  const int nid = blockIdx.x * 4 + (threadIdx.x >> 6);
  if (nid >= NN) return;
  const int t  = threadIdx.x & 63;
  const int c0 = t * 4;
  const int r0 = rowstart[nid], r1 = rowstart[nid + 1];
  const float4 q = ld4b(Yb + (size_t)nid * D4 + c0);
  const short* kvb = Yb + 256 + t * 8;
  float m = -INFINITY, denom = 0.f;
  float4 acc = make_float4(0.f, 0.f, 0.f, 0.f);
  int r = r0;
  for (; r + 3 < r1; r += 4) {
    const int4 x0 = *(const int4*)(kvb + (size_t)esrc[r + 0] * D4);
    const int4 x1 = *(const int4*)(kvb + (size_t)esrc[r + 1] * D4);
    const int4 x2 = *(const int4*)(kvb + (size_t)esrc[r + 2] * D4);
    const int4 x3 = *(const int4*)(kvb + (size_t)esrc[r + 3] * D4);
    float f0[8], f1[8], f2[8], f3[8];
    unpack8(x0, f0); unpack8(x1, f1); unpack8(x2, f2); unpack8(x3, f3);
    float d0 = q.x * f0[0] + q.y * f0[1] + q.z * f0[2] + q.w * f0[3];
    float d1 = q.x * f1[0] + q.y * f1[1] + q.z * f1[2] + q.w * f1[3];
    float d2 = q.x * f2[0] + q.y * f2[1] + q.z * f2[2] + q.w * f2[3];
    float d3 = q.x * f3[0] + q.y * f3[1] + q.z * f3[2] + q.w * f3[3];
#pragma unroll
    for (int off = 1; off <= 8; off <<= 1) {
      d0 += __shfl_xor(d0, off, 16);
      d1 += __shfl_xor(d1, off, 16);
      d2 += __shfl_xor(d2, off, 16);
      d3 += __shfl_xor(d3, off, 16);
    }
    d0 *= 0.125f; d1 *= 0.125f; d2 *= 0.125f; d3 *= 0.125f;
    const float nm = fmaxf(fmaxf(m, fmaxf(d0, d1)), fmaxf(d2, d3));
    const float sc = __expf(m - nm);
    const float e0 = __expf(d0 - nm);
    const float e1 = __expf(d1 - nm);
    const float e2 = __expf(d2 - nm);
    const float e3 = __expf(d3 - nm);
    denom = denom * sc + e0 + e1 + e2 + e3;
    acc.x = acc.x * sc + e0 * f0[4] + e1 * f1[4] + e2 * f2[4] + e3 * f3[4];
    acc.y = acc.y * sc + e0 * f0[5] + e1 * f1[5] + e2 * f2[5] + e3 * f3[5];
    acc.z = acc.z * sc + e0 * f0[6] + e1 * f1[6] + e2 * f2[6] + e3 * f3[6];
    acc.w = acc.w * sc + e0 * f0[7] + e1 * f1[7] + e2 * f2[7] + e3 * f3[7];
    m = nm;
  }
  for (; r < r1; r++) {
    const int4 x0 = *(const int4*)(kvb + (size_t)esrc[r] * D4);
    float f0[8];
    unpack8(x0, f0);
    float d0 = q.x * f0[0] + q.y * f0[1] + q.z * f0[2] + q.w * f0[3];
#pragma unroll
    for (int off = 1; off <= 8; off <<= 1) d0 += __shfl_xor(d0, off, 16);
    d0 *= 0.125f;
    const float nm = fmaxf(m, d0);
    const float sc = __expf(m - nm);
    const float e0 = __expf(d0 - nm);
    denom = denom * sc + e0;
    acc.x = acc.x * sc + e0 * f0[4];
    acc.y = acc.y * sc + e0 * f0[5];
    acc.z = acc.z * sc + e0 * f0[6];
    acc.w = acc.w * sc + e0 * f0[7];
    m = nm;
  }
  const float inv = 1.0f / (denom + 1e-16f);
  const float4 sk = ld4b(Yb + (size_t)nid * D4 + 768 + c0);
  float o0 = acc.x * inv + sk.x;
  float o1 = acc.y * inv + sk.y;
  float o2 = acc.z * inv + sk.z;
  float o3 = acc.w * inv + sk.w;
  o0 = o0 > 0.f ? o0 : expm1f(o0);
  o1 = o1 > 0.f ? o1 : expm1f(o1);
  o2 = o2 > 0.f ? o2 : expm1f(o2);
  o3 = o3 > 0.f ? o3 : expm1f(o3);
  TOUT* p = out + (size_t)nid * D1 + c0;
  st1<TOUT>(p + 0, o0); st1<TOUT>(p + 1, o1);
  st1<TOUT>(p + 2, o2); st1<TOUT>(p + 3, o3);
}

// ---------- mean-pool partial sums (parallel, run-length atomics) ----------
__global__ __launch_bounds__(256) void pool_k(const float* __restrict__ h,
    const int* __restrict__ batch, float* __restrict__ sums) {
  const int c = threadIdx.x;
  const int n0 = blockIdx.x * 64;
  const int n1 = min(n0 + 64, NN);
  float run = 0.f;
  int curg = -1;
  for (int n = n0; n < n1; n++) {
    int g = batch[n];
    if (g != curg) {
      if (curg >= 0) atomicAdd(&sums[(size_t)curg * D1 + c], run);
      run = 0.f; curg = g;
    }
    run += h[(size_t)n * D1 + c];
  }
  if (curg >= 0) atomicAdd(&sums[(size_t)curg * D1 + c], run);
}

// ---------- classifier + log_softmax (counts from gb) ----------
__global__ __launch_bounds__(640) void head_k(const float* __restrict__ sums,
    const int* __restrict__ gb, const float* __restrict__ Wl,
    const float* __restrict__ bl, float* __restrict__ out) {
  __shared__ float logits[NG][NOUT];
  const int t = threadIdx.x;
  if (t < NG * NOUT) {
    int g = t / NOUT, o = t % NOUT;
    float inv = 1.0f / fmaxf((float)(gb[g + 1] - gb[g]), 1.0f);
    float acc = 0.f;
    for (int k = 0; k < D1; k++) acc += sums[(size_t)g * D1 + k] * Wl[k * NOUT + o];
    logits[g][o] = acc * inv + bl[o];
  }
  __syncthreads();
  if (t < NG) {
    float mx = -INFINITY;
#pragma unroll
    for (int o = 0; o < NOUT; o++) mx = fmaxf(mx, logits[t][o]);
    float s = 0.f;
#pragma unroll
    for (int o = 0; o < NOUT; o++) s += __expf(logits[t][o] - mx);
    float lse = mx + logf(s);
#pragma unroll
    for (int o = 0; o < NOUT; o++) out[t * NOUT + o] = logits[t][o] - lse;
  }
}

// ---------------------------------------------------------------------------
extern "C" void kernel_launch(void* const* d_in, const int* in_sizes, int n_in,
                              void* d_out, int out_size, void* d_ws, size_t ws_size,
                              hipStream_t stream) {
  const float* x   = (const float*)d_in[0];
  const int* ei    = (const int*)d_in[1];
  const int* batch = (const int*)d_in[2];
  const float* Wq1 = (const float*)d_in[3];  const float* bq1 = (const float*)d_in[4];
  const float* Wk1 = (const float*)d_in[5];  const float* bk1 = (const float*)d_in[6];
  const float* Wv1 = (const float*)d_in[7];  const float* bv1 = (const float*)d_in[8];
  const float* Ws1 = (const float*)d_in[9];  const float* bs1 = (const float*)d_in[10];
  const float* Wq2 = (const float*)d_in[11]; const float* bq2 = (const float*)d_in[12];
  const float* Wk2 = (const float*)d_in[13]; const float* bk2 = (const float*)d_in[14];
  const float* Wv2 = (const float*)d_in[15]; const float* bv2 = (const float*)d_in[16];
  const float* Ws2 = (const float*)d_in[17]; const float* bs2 = (const float*)d_in[18];
  const float* Wl  = (const float*)d_in[19]; const float* bl  = (const float*)d_in[20];

  const int* srcIdx = ei;          // edge_index[0] (source j)
  const int* dstIdx = ei + NE;     // edge_index[1] (target i)

  // -------- workspace layout --------
  float* ws = (float*)d_ws;
  const size_t SZ_NODE = (size_t)NN * D1;       // 12.8M elems
  float* H2f  = ws;                              // NN*D1 fp32
  float* sums = ws + SZ_NODE;                    // NG*D1
  float* bc1  = sums + (size_t)NG * D1;          // 1024
  float* bc2  = bc1 + D4;                        // 1024
  short* Xb   = (short*)(bc2 + D4);              // NN*INC
  short* H1b  = Xb + (size_t)NN * INC;           // NN*D1
  short* Yb   = H1b + SZ_NODE;                   // NN*1024
  short* Wtc1 = Yb + (size_t)NN * D4;            // 1024*128
  short* Wtc2 = Wtc1 + (size_t)D4 * INC;         // 1024*256
  int* ip      = (int*)(Wtc2 + (size_t)D4 * D1);
  int* deg     = ip;                 // NN
  int* partial = deg + NN;           // 256
  int* rowstart= partial + 256;      // NN+1
  int* cursor  = rowstart + NN + 1;  // NN
  int* esrc    = cursor + NN;        // NE
  int* gb      = esrc + NE;          // NG+1

  const int mtiles = (NN + 127) / 128;           // 391
  const dim3 gemmGrid(64, (mtiles + 7) / 8);     // 64 x 49 swizzled
  const int edgeBlocks = (NE + 255) / 256;
  const int nodeBlocks = (NN + 255) / 256;
  const int aggBlocks  = (NN + 3) / 4;
  const int cvtBlocks  = CVT_XB + CVT_W1B + CVT_W2B + 8;

  // ======== Converts (one kernel) ========
  cvt_all_k<<<cvtBlocks, 256, 0, stream>>>(x, Xb,
      Wq1, Wk1, Wv1, Ws1, Wq2, Wk2, Wv2, Ws2, Wtc1, Wtc2,
      bq1, bk1, bv1, bs1, bq2, bk2, bv2, bs2, bc1, bc2);

  // ======== CSR build + graph bounds ========
  fill_i<<<nodeBlocks, 256, 0, stream>>>(deg, 0, NN);
  deg_count<<<edgeBlocks, 256, 0, stream>>>(dstIdx, deg);
  scan1<<<NB_SCAN + 1, 256, 0, stream>>>(deg, partial, batch, gb);
  scan3<<<NB_SCAN, 256, 0, stream>>>(deg, partial, rowstart, cursor);
  scatter_k<<<edgeBlocks, 256, 0, stream>>>(srcIdx, dstIdx, cursor, esrc);

  // ======== Layer 1 ========
  gemm_mfma<short><<<gemmGrid, 256, 0, stream>>>(Xb, Wtc1, bc1, Yb, NN, INC, D4);
  node_attn<short><<<aggBlocks, 256, 0, stream>>>(rowstart, esrc, Yb, H1b);

  // ======== Layer 2 ========
  gemm_mfma<short><<<gemmGrid, 256, 0, stream>>>(H1b, Wtc2, bc2, Yb, NN, D1, D4);
  node_attn<float><<<aggBlocks, 256, 0, stream>>>(rowstart, esrc, Yb, H2f);

  // ======== Pool + head ========
  fill_f<<<(NG * D1 + 255) / 256, 256, 0, stream>>>(sums, 0.f, NG * D1);
  pool_k<<<(NN + 63) / 64, 256, 0, stream>>>(H2f, batch, sums);
  head_k<<<1, 640, 0, stream>>>(sums, gb, Wl, bl, (float*)d_out);
}